// Round 3
// baseline (882.322 us; speedup 1.0000x reference)
//
#include <hip/hip_runtime.h>
#include <hip/hip_bf16.h>

// PolicyNet, MFMA split-bf16, pipelined (T3+T4):
//   c    = b1 + W1[:, :D] @ hist                       (fp32, once)
//   qw1t = W1[:, D:] @ Q^T  (fp32 gemm, [j][n]) -> split -> QWt_hi/lo bf16
//   W2   -> transpose-split -> W2T_hi/lo [j][k] bf16
//   A    -> rowwise split -> A_hi/A_lo bf16, ab2[m] = A[m]·b2;  Q -> Q_hi/Q_lo
//   s_attn (MFMA): S = A@Q^T, fused row-softmax -> attn_hi/lo bf16
//   fused (MFMA, 3-product, counted-vmcnt pipeline):
//       z = attn @ QWt (K=128); h = relu(z+c) [fp32 regs]
//       G = A @ W2t    (K=2048)
//       partial = sum_j h*G
//   semantic = sum partial + ab2 -> softmax over M -> out

typedef unsigned short ushort_t;
typedef __attribute__((ext_vector_type(8))) short short8;
typedef __attribute__((ext_vector_type(4))) float f32x4;

#define GLL(gp, lp)                                                              \
  __builtin_amdgcn_global_load_lds(                                              \
      (const __attribute__((address_space(1))) void*)(gp),                       \
      (__attribute__((address_space(3))) void*)(lp), 16, 0, 0)

#define WAIT4 asm volatile("s_waitcnt vmcnt(4)" ::: "memory")
#define WAIT0 asm volatile("s_waitcnt vmcnt(0)" ::: "memory")
#define BAR __builtin_amdgcn_s_barrier()

__device__ __forceinline__ void split_bf16(float x, ushort_t& hi, ushort_t& lo) {
  unsigned u = __float_as_uint(x);
  unsigned r = u + 0x7fffu + ((u >> 16) & 1u);
  hi = (ushort_t)(r >> 16);
  float fh = __uint_as_float(r & 0xffff0000u);
  float xl = x - fh;
  unsigned ul = __float_as_uint(xl);
  unsigned rl = ul + 0x7fffu + ((ul >> 16) & 1u);
  lo = (ushort_t)(rl >> 16);
}

// ---------------- shared K-loop (3-product split-bf16, pipelined) ----------------
// BM=BN=128, BK=32, 4 waves (2m x 2n), per-wave 64x64 (4x4 frags of 16x16x32).
// A-fragments: direct global->reg (ping-pong, depth-1 prefetch).
// B-tiles: LDS, 3 buffers of [hi 8KB][lo 8KB], GLL-staged, depth-2 prefetch,
// XOR swizzle slot = kk ^ ((row>>1)&3) -> conflict-free ds_read_b128.
template <int NT, int LDA, int LDB>
__device__ __forceinline__ void kloop(const ushort_t* __restrict__ Ah,
                                      const ushort_t* __restrict__ Al,
                                      const ushort_t* __restrict__ Bh,
                                      const ushort_t* __restrict__ Bl,
                                      short* __restrict__ SB,
                                      f32x4 (&acc)[4][4],
                                      int lane, int wv, int wm, int wn) {
  const int f = lane & 15, kk = lane >> 4;
  const ushort_t* arow_h = Ah + (size_t)(wm + f) * LDA + kk * 8;
  const ushort_t* arow_l = Al + (size_t)(wm + f) * LDA + kk * 8;
  int boff[4];
  #pragma unroll
  for (int nf = 0; nf < 4; ++nf) {
    const int row = wn + nf * 16 + f;
    boff[nf] = row * 32 + ((kk ^ ((row >> 1) & 3)) * 8);
  }

  auto LOADA = [&](short8 (&dst)[8], int kt) {
    #pragma unroll
    for (int mf = 0; mf < 4; ++mf) {
      dst[mf]     = *(const short8*)&arow_h[(size_t)mf * 16 * LDA + kt];
      dst[mf + 4] = *(const short8*)&arow_l[(size_t)mf * 16 * LDA + kt];
    }
  };
  auto STAGEB = [&](short* dst, int kt) {
    #pragma unroll
    for (int i = 0; i < 2; ++i) {
      const int seg = wv * 2 + i;
      const int row = seg * 16 + (lane >> 2);
      const int chunk = (lane & 3) ^ ((row >> 1) & 3);
      const size_t go = (size_t)row * LDB + kt + chunk * 8;
      GLL(Bh + go, dst + seg * 512);
      GLL(Bl + go, dst + 4096 + seg * 512);
    }
  };
  auto COMPUTE = [&](const short* p, const short8 (&a)[8]) {
    short8 bh[4], bl[4];
    #pragma unroll
    for (int nf = 0; nf < 4; ++nf) {
      bh[nf] = *(const short8*)&p[boff[nf]];
      bl[nf] = *(const short8*)&p[4096 + boff[nf]];
    }
    #pragma unroll
    for (int mf = 0; mf < 4; ++mf)
      #pragma unroll
      for (int nf = 0; nf < 4; ++nf) {
        acc[mf][nf] = __builtin_amdgcn_mfma_f32_16x16x32_bf16(a[mf], bh[nf], acc[mf][nf], 0, 0, 0);
        acc[mf][nf] = __builtin_amdgcn_mfma_f32_16x16x32_bf16(a[mf], bl[nf], acc[mf][nf], 0, 0, 0);
        acc[mf][nf] = __builtin_amdgcn_mfma_f32_16x16x32_bf16(a[mf + 4], bh[nf], acc[mf][nf], 0, 0, 0);
      }
  };

  short* p0 = SB;
  short* p1 = SB + 8192;
  short* p2 = SB + 16384;
  short8 a0[8], a1[8];
  LOADA(a0, 0);
  STAGEB(p0, 0);
  STAGEB(p1, 32);

  #pragma unroll 1
  for (int t = 0; t < NT - 2; t += 2) {
    WAIT4; BAR;
    LOADA(a1, (t + 1) * 32);
    STAGEB(p2, (t + 2) * 32);
    COMPUTE(p0, a0);
    { short* tp = p0; p0 = p1; p1 = p2; p2 = tp; }
    WAIT4; BAR;
    LOADA(a0, (t + 2) * 32);
    STAGEB(p2, (t + 3) * 32);
    COMPUTE(p0, a1);
    { short* tp = p0; p0 = p1; p1 = p2; p2 = tp; }
  }
  // peel t = NT-2, NT-1
  WAIT4; BAR;
  LOADA(a1, (NT - 1) * 32);
  COMPUTE(p0, a0);
  { short* tp = p0; p0 = p1; p1 = p2; p2 = tp; }
  WAIT0; BAR;
  COMPUTE(p0, a1);
  BAR;
}

// ---------------- prep kernels ----------------

__global__ __launch_bounds__(256) void c_kernel(const float* __restrict__ W1,
                                                const float* __restrict__ b1,
                                                const float* __restrict__ hist,
                                                float* __restrict__ c) {
  const int wave = threadIdx.x >> 6, lane = threadIdx.x & 63;
  const int j = blockIdx.x * 4 + wave;
  const float* row = W1 + (size_t)j * 4096;
  float s = 0.f;
  #pragma unroll 2
  for (int kq = lane; kq < 512; kq += 64) {
    const float4 w = *(const float4*)&row[kq * 4];
    const float4 h = *(const float4*)&hist[kq * 4];
    s += w.x * h.x + w.y * h.y + w.z * h.z + w.w * h.w;
  }
  #pragma unroll
  for (int mask = 1; mask < 64; mask <<= 1) s += __shfl_xor(s, mask);
  if (lane == 0) c[j] = s + b1[j];
}

__global__ __launch_bounds__(256) void prep_A(const float* __restrict__ A,
                                              const float* __restrict__ b2,
                                              ushort_t* __restrict__ Ahi,
                                              ushort_t* __restrict__ Alo,
                                              float* __restrict__ ab2) {
  const int wv = threadIdx.x >> 6, lane = threadIdx.x & 63;
  const size_t row = (size_t)blockIdx.x * 4 + wv;
  const float* ar = A + row * 2048;
  float dot = 0.f;
  #pragma unroll 2
  for (int c0 = 0; c0 < 2048; c0 += 256) {
    const int col = c0 + lane * 4;
    const float4 v = *(const float4*)&ar[col];
    const float4 bb = *(const float4*)&b2[col];
    dot += v.x * bb.x + v.y * bb.y + v.z * bb.z + v.w * bb.w;
    ushort4 h, l;
    split_bf16(v.x, h.x, l.x); split_bf16(v.y, h.y, l.y);
    split_bf16(v.z, h.z, l.z); split_bf16(v.w, h.w, l.w);
    *(ushort4*)&Ahi[row * 2048 + col] = h;
    *(ushort4*)&Alo[row * 2048 + col] = l;
  }
  #pragma unroll
  for (int mask = 1; mask < 64; mask <<= 1) dot += __shfl_xor(dot, mask);
  if (lane == 0) ab2[row] = dot;
}

__global__ __launch_bounds__(256) void prep_Q(const float* __restrict__ Q,
                                              ushort_t* __restrict__ Qhi,
                                              ushort_t* __restrict__ Qlo) {
  const int wv = threadIdx.x >> 6, lane = threadIdx.x & 63;
  const size_t row = (size_t)blockIdx.x * 4 + wv;  // grid 32 -> 128 rows
  const float* qr = Q + row * 2048;
  #pragma unroll 2
  for (int c0 = 0; c0 < 2048; c0 += 256) {
    const int col = c0 + lane * 4;
    const float4 v = *(const float4*)&qr[col];
    ushort4 h, l;
    split_bf16(v.x, h.x, l.x); split_bf16(v.y, h.y, l.y);
    split_bf16(v.z, h.z, l.z); split_bf16(v.w, h.w, l.w);
    *(ushort4*)&Qhi[row * 2048 + col] = h;
    *(ushort4*)&Qlo[row * 2048 + col] = l;
  }
}

// dst_hi/lo[c*ldR + r] = split(src[r*C + c])
__global__ __launch_bounds__(256) void transpose_split(const float* __restrict__ src,
                                                       int R, int C,
                                                       ushort_t* __restrict__ dhi,
                                                       ushort_t* __restrict__ dlo) {
  __shared__ float T[64][65];
  const int c0 = blockIdx.x * 64, r0 = blockIdx.y * 64;
  const int t = threadIdx.x;
  {
    const int rl = t >> 4, cl = (t & 15) * 4;
    #pragma unroll
    for (int ii = 0; ii < 4; ++ii) {
      const float4 v = *(const float4*)&src[(size_t)(r0 + rl + ii * 16) * C + c0 + cl];
      T[rl + ii * 16][cl + 0] = v.x; T[rl + ii * 16][cl + 1] = v.y;
      T[rl + ii * 16][cl + 2] = v.z; T[rl + ii * 16][cl + 3] = v.w;
    }
  }
  __syncthreads();
  const int cc = t >> 2, rr0 = (t & 3) * 16;
  union { ushort_t u[16]; ushort4 v[4]; } H, L;
  #pragma unroll
  for (int k = 0; k < 16; ++k) split_bf16(T[rr0 + k][cc], H.u[k], L.u[k]);
  ushort_t* ph = dhi + (size_t)(c0 + cc) * R + r0 + rr0;
  ushort_t* pl = dlo + (size_t)(c0 + cc) * R + r0 + rr0;
  #pragma unroll
  for (int k4 = 0; k4 < 4; ++k4) {
    *(ushort4*)&ph[k4 * 4] = H.v[k4];
    *(ushort4*)&pl[k4 * 4] = L.v[k4];
  }
}

__global__ __launch_bounds__(256) void split_plain(const float* __restrict__ src,
                                                   ushort_t* __restrict__ dhi,
                                                   ushort_t* __restrict__ dlo) {
  const size_t i = ((size_t)blockIdx.x * 256 + threadIdx.x) * 4;
  const float4 v = *(const float4*)&src[i];
  ushort4 h, l;
  split_bf16(v.x, h.x, l.x); split_bf16(v.y, h.y, l.y);
  split_bf16(v.z, h.z, l.z); split_bf16(v.w, h.w, l.w);
  *(ushort4*)&dhi[i] = h;
  *(ushort4*)&dlo[i] = l;
}

// fp32 tiled GEMM (B^T layout): C[m][n] = sum_k A[m*lda+k]*B[n*ldb+k]
template <int BM, int TM>
__global__ __launch_bounds__(256) void gemm_bt(const float* __restrict__ A,
                                               const float* __restrict__ B,
                                               float* __restrict__ C,
                                               int K, int lda, int ldb, int ldc) {
  constexpr int BN = 64, BK = 32;
  constexpr int ASTR = BM + 12, BSTR = BN + 4;
  __shared__ float As[BK][ASTR];
  __shared__ float Bs[BK][BSTR];
  const int tid = threadIdx.x;
  const int tx = tid & 15, ty = tid >> 4;
  const int m0 = ty * TM, n0 = tx * 4;
  const size_t bm = (size_t)blockIdx.x * BM, bn = (size_t)blockIdx.y * BN;
  const float* Ab = A + bm * lda;
  const float* Bb = B + bn * ldb;
  float acc[TM][4];
  #pragma unroll
  for (int i = 0; i < TM; ++i)
    #pragma unroll
    for (int j = 0; j < 4; ++j) acc[i][j] = 0.f;
  for (int kt = 0; kt < K; kt += BK) {
    #pragma unroll
    for (int it = 0; it < BM * BK / 4 / 256; ++it) {
      const int idx = it * 256 + tid;
      const int row = idx >> 3, kq = idx & 7;
      const float4 v = *(const float4*)&Ab[(size_t)row * lda + kt + kq * 4];
      As[kq * 4 + 0][row] = v.x; As[kq * 4 + 1][row] = v.y;
      As[kq * 4 + 2][row] = v.z; As[kq * 4 + 3][row] = v.w;
    }
    #pragma unroll
    for (int it = 0; it < BN * BK / 4 / 256; ++it) {
      const int idx = it * 256 + tid;
      const int row = idx >> 3, kq = idx & 7;
      const float4 v = *(const float4*)&Bb[(size_t)row * ldb + kt + kq * 4];
      Bs[kq * 4 + 0][row] = v.x; Bs[kq * 4 + 1][row] = v.y;
      Bs[kq * 4 + 2][row] = v.z; Bs[kq * 4 + 3][row] = v.w;
    }
    __syncthreads();
    #pragma unroll
    for (int k = 0; k < BK; ++k) {
      float av[TM];
      #pragma unroll
      for (int i = 0; i < TM; ++i) av[i] = As[k][m0 + i];
      const float4 b = *(const float4*)&Bs[k][n0];
      const float bv[4] = {b.x, b.y, b.z, b.w};
      #pragma unroll
      for (int i = 0; i < TM; ++i)
        #pragma unroll
        for (int j = 0; j < 4; ++j) acc[i][j] = fmaf(av[i], bv[j], acc[i][j]);
    }
    __syncthreads();
  }
  #pragma unroll
  for (int i = 0; i < TM; ++i) {
    float* crow = C + (bm + m0 + i) * (size_t)ldc + bn + n0;
    #pragma unroll
    for (int j = 0; j < 4; ++j) crow[j] = acc[i][j];
  }
}

// ---------------- S = A@Q^T + fused row softmax -> attn hi/lo ----------------
__global__ __launch_bounds__(256, 2) void s_attn(const ushort_t* __restrict__ Ahi,
                                                 const ushort_t* __restrict__ Alo,
                                                 const ushort_t* __restrict__ Qhi,
                                                 const ushort_t* __restrict__ Qlo,
                                                 ushort_t* __restrict__ at_hi,
                                                 ushort_t* __restrict__ at_lo) {
  __shared__ short SB[24576];  // 48 KB
  const int tid = threadIdx.x, lane = tid & 63, wv = tid >> 6;
  const int wm = (wv >> 1) * 64, wn = (wv & 1) * 64;
  const int f = lane & 15, kk = lane >> 4;
  const size_t bm = (size_t)blockIdx.x * 128;

  f32x4 acc[4][4];
  #pragma unroll
  for (int mf = 0; mf < 4; ++mf)
    #pragma unroll
    for (int nf = 0; nf < 4; ++nf) acc[mf][nf] = 0.f;

  kloop<64, 2048, 2048>(Ahi + bm * 2048, Alo + bm * 2048, Qhi, Qlo,
                        SB, acc, lane, wv, wm, wn);

  // fused softmax over full rows (128 cols; wave-pair shares rows)
  float* sred = (float*)SB;        // [128][2] row-max
  float* ssum = sred + 256;        // [128][2] row-sum
  const int rowbase = wm + kk * 4;
  float rmax[4][4];
  #pragma unroll
  for (int mf = 0; mf < 4; ++mf)
    #pragma unroll
    for (int r = 0; r < 4; ++r) {
      float m4 = fmaxf(fmaxf(acc[mf][0][r], acc[mf][1][r]),
                       fmaxf(acc[mf][2][r], acc[mf][3][r]));
      m4 = fmaxf(m4, __shfl_xor(m4, 1));
      m4 = fmaxf(m4, __shfl_xor(m4, 2));
      m4 = fmaxf(m4, __shfl_xor(m4, 4));
      m4 = fmaxf(m4, __shfl_xor(m4, 8));
      rmax[mf][r] = m4;
    }
  if (f == 0) {
    #pragma unroll
    for (int mf = 0; mf < 4; ++mf)
      #pragma unroll
      for (int r = 0; r < 4; ++r)
        sred[(rowbase + mf * 16 + r) * 2 + (wv & 1)] = rmax[mf][r];
  }
  __syncthreads();
  #pragma unroll
  for (int mf = 0; mf < 4; ++mf)
    #pragma unroll
    for (int r = 0; r < 4; ++r) {
      const int row = rowbase + mf * 16 + r;
      rmax[mf][r] = fmaxf(sred[row * 2], sred[row * 2 + 1]);
    }
  float rsum[4][4];
  #pragma unroll
  for (int mf = 0; mf < 4; ++mf)
    #pragma unroll
    for (int r = 0; r < 4; ++r) {
      float s = 0.f;
      #pragma unroll
      for (int nf = 0; nf < 4; ++nf) {
        acc[mf][nf][r] = __expf(acc[mf][nf][r] - rmax[mf][r]);
        s += acc[mf][nf][r];
      }
      s += __shfl_xor(s, 1);
      s += __shfl_xor(s, 2);
      s += __shfl_xor(s, 4);
      s += __shfl_xor(s, 8);
      rsum[mf][r] = s;
    }
  if (f == 0) {
    #pragma unroll
    for (int mf = 0; mf < 4; ++mf)
      #pragma unroll
      for (int r = 0; r < 4; ++r)
        ssum[(rowbase + mf * 16 + r) * 2 + (wv & 1)] = rsum[mf][r];
  }
  __syncthreads();
  #pragma unroll
  for (int mf = 0; mf < 4; ++mf)
    #pragma unroll
    for (int r = 0; r < 4; ++r) {
      const int row = rowbase + mf * 16 + r;
      const float inv = 1.0f / (ssum[row * 2] + ssum[row * 2 + 1]);
      const size_t orow = (bm + row) * 128;
      #pragma unroll
      for (int nf = 0; nf < 4; ++nf) {
        ushort_t hi, lo;
        split_bf16(acc[mf][nf][r] * inv, hi, lo);
        const size_t idx = orow + wn + nf * 16 + f;
        at_hi[idx] = hi;
        at_lo[idx] = lo;
      }
    }
}

// ---------------- fused z/h/G/dot ----------------
__global__ __launch_bounds__(256, 2) void fused_zg_mfma(
    const ushort_t* __restrict__ Ahi, const ushort_t* __restrict__ Alo,
    const ushort_t* __restrict__ at_hi, const ushort_t* __restrict__ at_lo,
    const ushort_t* __restrict__ QWt_hi, const ushort_t* __restrict__ QWt_lo,
    const ushort_t* __restrict__ W2t_hi, const ushort_t* __restrict__ W2t_lo,
    const float* __restrict__ cvec, float* __restrict__ partial) {
  __shared__ short SB[24576];  // 48 KB
  const int tid = threadIdx.x, lane = tid & 63, wv = tid >> 6;
  const int wm = (wv >> 1) * 64, wn = (wv & 1) * 64;
  const int f = lane & 15, kk = lane >> 4;
  const size_t bm = (size_t)blockIdx.x * 128;
  const size_t bn = (size_t)blockIdx.y * 128;

  f32x4 acc[4][4];
  #pragma unroll
  for (int mf = 0; mf < 4; ++mf)
    #pragma unroll
    for (int nf = 0; nf < 4; ++nf) acc[mf][nf] = 0.f;

  // phase Z: z = attn @ QWt, K = 128
  kloop<4, 128, 128>(at_hi + bm * 128, at_lo + bm * 128,
                     QWt_hi + bn * 128, QWt_lo + bn * 128,
                     SB, acc, lane, wv, wm, wn);

  // h = relu(z + c)
  float hreg[4][4][4];
  {
    float ccv[4];
    #pragma unroll
    for (int nf = 0; nf < 4; ++nf) ccv[nf] = cvec[bn + wn + nf * 16 + f];
    #pragma unroll
    for (int mf = 0; mf < 4; ++mf)
      #pragma unroll
      for (int nf = 0; nf < 4; ++nf)
        #pragma unroll
        for (int r = 0; r < 4; ++r) {
          hreg[mf][nf][r] = fmaxf(acc[mf][nf][r] + ccv[nf], 0.f);
          acc[mf][nf][r] = 0.f;
        }
  }

  // phase G: G = A @ W2t, K = 2048
  kloop<64, 2048, 2048>(Ahi + bm * 2048, Alo + bm * 2048,
                        W2t_hi + bn * 2048, W2t_lo + bn * 2048,
                        SB, acc, lane, wv, wm, wn);

  // epilogue: partial = sum over this block's 128 j of h*G
  float part[4][4];
  #pragma unroll
  for (int mf = 0; mf < 4; ++mf)
    #pragma unroll
    for (int r = 0; r < 4; ++r) {
      float s = 0.f;
      #pragma unroll
      for (int nf = 0; nf < 4; ++nf) s += hreg[mf][nf][r] * acc[mf][nf][r];
      part[mf][r] = s;
    }
  #pragma unroll
  for (int mf = 0; mf < 4; ++mf)
    #pragma unroll
    for (int r = 0; r < 4; ++r) {
      part[mf][r] += __shfl_xor(part[mf][r], 1);
      part[mf][r] += __shfl_xor(part[mf][r], 2);
      part[mf][r] += __shfl_xor(part[mf][r], 4);
      part[mf][r] += __shfl_xor(part[mf][r], 8);
    }
  if (f == 0) {
    const size_t slab = (size_t)(blockIdx.y * 2 + (wv & 1)) * 16384;
    #pragma unroll
    for (int mf = 0; mf < 4; ++mf)
      #pragma unroll
      for (int r = 0; r < 4; ++r)
        partial[slab + bm + wm + mf * 16 + kk * 4 + r] = part[mf][r];
  }
}

// ---------------- final reduction + softmax over M ----------------

__global__ __launch_bounds__(256) void k_sem(const float* __restrict__ partial,
                                             const float* __restrict__ ab2,
                                             float* __restrict__ semantic,
                                             float* __restrict__ bstats) {
  const int m = blockIdx.x * 256 + threadIdx.x;
  float s = ab2[m];
  #pragma unroll
  for (int nb = 0; nb < 32; ++nb) s += partial[(size_t)nb * 16384 + m];
  semantic[m] = s;
  float mx = s;
  #pragma unroll
  for (int mask = 1; mask < 64; mask <<= 1) mx = fmaxf(mx, __shfl_xor(mx, mask));
  __shared__ float wmax[4], wsum[4];
  const int wave = threadIdx.x >> 6, lane = threadIdx.x & 63;
  if (lane == 0) wmax[wave] = mx;
  __syncthreads();
  const float bmax = fmaxf(fmaxf(wmax[0], wmax[1]), fmaxf(wmax[2], wmax[3]));
  float e = expf(s - bmax);
  #pragma unroll
  for (int mask = 1; mask < 64; mask <<= 1) e += __shfl_xor(e, mask);
  if (lane == 0) wsum[wave] = e;
  __syncthreads();
  if (threadIdx.x == 0) {
    bstats[blockIdx.x * 2] = bmax;
    bstats[blockIdx.x * 2 + 1] = wsum[0] + wsum[1] + wsum[2] + wsum[3];
  }
}

__global__ void k_combine(const float* __restrict__ bstats, float* __restrict__ gstats) {
  const int t = threadIdx.x;
  const float bm = bstats[t * 2], bs = bstats[t * 2 + 1];
  float gm = bm;
  #pragma unroll
  for (int mask = 1; mask < 64; mask <<= 1) gm = fmaxf(gm, __shfl_xor(gm, mask));
  float gs = bs * expf(bm - gm);
  #pragma unroll
  for (int mask = 1; mask < 64; mask <<= 1) gs += __shfl_xor(gs, mask);
  if (t == 0) { gstats[0] = gm; gstats[1] = gs; }
}

__global__ __launch_bounds__(256) void k_out(const float* __restrict__ semantic,
                                             const float* __restrict__ gstats,
                                             float* __restrict__ out) {
  const int m = blockIdx.x * 256 + threadIdx.x;
  out[m] = expf(semantic[m] - gstats[0]) / gstats[1];
}

// ---------------- launch ----------------

extern "C" void kernel_launch(void* const* d_in, const int* in_sizes, int n_in,
                              void* d_out, int out_size, void* d_ws, size_t ws_size,
                              hipStream_t stream) {
  (void)in_sizes; (void)n_in; (void)out_size; (void)ws_size;
  const float* A    = (const float*)d_in[0];  // [16384][2048]
  const float* Q    = (const float*)d_in[1];  // [128][2048]
  const float* hist = (const float*)d_in[2];  // [2048]
  const float* W1   = (const float*)d_in[3];  // [2048][4096]
  const float* b1   = (const float*)d_in[4];  // [2048]
  const float* W2   = (const float*)d_in[5];  // [2048][2048]
  const float* b2   = (const float*)d_in[6];  // [2048]
  float* out = (float*)d_out;                 // [16384]

  char* ws = (char*)d_ws;
  ushort_t* A_hi   = (ushort_t*)ws;  ws += (size_t)16384 * 2048 * 2;  // 64 MB
  ushort_t* A_lo   = (ushort_t*)ws;  ws += (size_t)16384 * 2048 * 2;  // 64 MB
  ushort_t* W2t_hi = (ushort_t*)ws;  ws += (size_t)2048 * 2048 * 2;   // 8 MB
  ushort_t* W2t_lo = (ushort_t*)ws;  ws += (size_t)2048 * 2048 * 2;   // 8 MB
  ushort_t* Q_hi   = (ushort_t*)ws;  ws += (size_t)128 * 2048 * 2;
  ushort_t* Q_lo   = (ushort_t*)ws;  ws += (size_t)128 * 2048 * 2;
  ushort_t* QWt_hi = (ushort_t*)ws;  ws += (size_t)2048 * 128 * 2;
  ushort_t* QWt_lo = (ushort_t*)ws;  ws += (size_t)2048 * 128 * 2;
  ushort_t* at_hi  = (ushort_t*)ws;  ws += (size_t)16384 * 128 * 2;   // 4 MB
  ushort_t* at_lo  = (ushort_t*)ws;  ws += (size_t)16384 * 128 * 2;   // 4 MB
  float* qw1t      = (float*)ws;     ws += (size_t)2048 * 128 * 4;    // 1 MB
  float* c_vec     = (float*)ws;     ws += 2048 * 4;
  float* ab2       = (float*)ws;     ws += 16384 * 4;
  float* partial   = (float*)ws;     ws += (size_t)32 * 16384 * 4;    // 2 MB
  float* semantic  = (float*)ws;     ws += 16384 * 4;
  float* bstats    = (float*)ws;     ws += 128 * 4;
  float* gstats    = (float*)ws;     ws += 2 * 4;

  // prep
  c_kernel<<<512, 256, 0, stream>>>(W1, b1, hist, c_vec);
  // qw1t[j][n] = sum_k W1q[j][k] * Q[n][k]
  gemm_bt<32, 2><<<dim3(64, 2), 256, 0, stream>>>(W1 + 2048, Q, qw1t,
                                                  2048, 4096, 2048, 128);
  split_plain<<<256, 256, 0, stream>>>(qw1t, QWt_hi, QWt_lo);
  transpose_split<<<dim3(32, 32), 256, 0, stream>>>(W2, 2048, 2048, W2t_hi, W2t_lo);
  prep_Q<<<32, 256, 0, stream>>>(Q, Q_hi, Q_lo);
  prep_A<<<4096, 256, 0, stream>>>(A, b2, A_hi, A_lo, ab2);
  // S = A@Q^T + softmax (MFMA, fused)
  s_attn<<<128, 256, 0, stream>>>(A_hi, A_lo, Q_hi, Q_lo, at_hi, at_lo);
  // fused z/h/G/dot (MFMA split-3, pipelined)
  fused_zg_mfma<<<dim3(128, 16), 256, 0, stream>>>(A_hi, A_lo, at_hi, at_lo,
                                                   QWt_hi, QWt_lo, W2t_hi, W2t_lo,
                                                   c_vec, partial);
  // semantic + softmax over M
  k_sem<<<64, 256, 0, stream>>>(partial, ab2, semantic, bstats);
  k_combine<<<1, 64, 0, stream>>>(bstats, gstats);
  k_out<<<64, 256, 0, stream>>>(semantic, gstats, out);
}

// Round 4
// 588.964 us; speedup vs baseline: 1.4981x; 1.4981x over previous
//
#include <hip/hip_runtime.h>
#include <hip/hip_bf16.h>

// PolicyNet, MFMA split-bf16, counted-vmcnt double-buffered LDS (T3+T4):
//   c    = b1 + W1[:, :D] @ hist                       (fp32, once)
//   qw1t = W1[:, D:] @ Q^T  (fp32 gemm, [j][n]) -> split -> QWt_hi/lo bf16
//   W2   -> transpose-split -> W2T_hi/lo [j][k] bf16
//   A    -> rowwise split -> A_hi/A_lo bf16, ab2[m] = A[m]·b2;  Q -> Q_hi/Q_lo
//   s_attn (MFMA): S = A@Q^T, fused row-softmax -> attn_hi/lo bf16
//   fused (MFMA, 3-product):
//       z = attn @ QWt (K=128); h = relu(z+c) [fp32 regs]
//       G = A @ W2t    (K=2048)
//       partial = sum_j h*G
//   semantic = sum partial + ab2 -> softmax over M -> out

typedef unsigned short ushort_t;
typedef __attribute__((ext_vector_type(8))) short short8;
typedef __attribute__((ext_vector_type(4))) float f32x4;

#define GLL(gp, lp)                                                              \
  __builtin_amdgcn_global_load_lds(                                              \
      (const __attribute__((address_space(1))) void*)(gp),                       \
      (__attribute__((address_space(3))) void*)(lp), 16, 0, 0)

__device__ __forceinline__ void split_bf16(float x, ushort_t& hi, ushort_t& lo) {
  unsigned u = __float_as_uint(x);
  unsigned r = u + 0x7fffu + ((u >> 16) & 1u);
  hi = (ushort_t)(r >> 16);
  float fh = __uint_as_float(r & 0xffff0000u);
  float xl = x - fh;
  unsigned ul = __float_as_uint(xl);
  unsigned rl = ul + 0x7fffu + ((ul >> 16) & 1u);
  lo = (ushort_t)(rl >> 16);
}

// ---------------- shared K-loop (3-product split-bf16, dbuf + counted vmcnt) ----
// BM=BN=128, BK=32, 4 waves (2m x 2n), per-wave 64x64 (4x4 frags of 16x16x32).
// LDS: 2 sets x {Ah,Al,Bh,Bl} x 8KB = 64KB. GLL-staged, depth-1 prefetch,
// wait vmcnt(8) per step (never 0 in steady state), raw s_barrier.
// Swizzle: within each 128B line, 16B-chunk index c' = c ^ (line&7);
// GLL source is pre-inverse-swizzled, reads apply the same XOR (involution).
template <int NT, int LDA, int LDB>
__device__ __forceinline__ void kloop(const ushort_t* __restrict__ Ah,
                                      const ushort_t* __restrict__ Al,
                                      const ushort_t* __restrict__ Bh,
                                      const ushort_t* __restrict__ Bl,
                                      short* __restrict__ SM,
                                      f32x4 (&acc)[4][4],
                                      int lane, int wv, int wm, int wn) {
  const int f = lane & 15, kk = lane >> 4;
  // staging geometry: lane l of GLL inst L writes LDS bytes [L*1024 + 16l).
  // stored chunk c_s = l&7, line = 8L + (l>>3); logical chunk c = c_s ^ (line&7)
  //  = (l&7) ^ (l>>3);  row = 2*line + (c>>2) = 16L + 2*(l>>3) + (c>>2);
  //  col-chunk kk = c&3 -> elems kk*8..+8.
  const int cS = (lane & 7) ^ (lane >> 3);
  const int kkS = (cS & 3) * 8;
  const int rS = 2 * (lane >> 3) + (cS >> 2);
  const size_t offA0 = (size_t)(16 * (wv * 2 + 0) + rS) * LDA + kkS;
  const size_t offA1 = (size_t)(16 * (wv * 2 + 1) + rS) * LDA + kkS;
  const size_t offB0 = (size_t)(16 * (wv * 2 + 0) + rS) * LDB + kkS;
  const size_t offB1 = (size_t)(16 * (wv * 2 + 1) + rS) * LDB + kkS;
  const int Ld0 = (wv * 2 + 0) * 512, Ld1 = (wv * 2 + 1) * 512;

  // read offsets (shorts within a 4096-short tile): logical (row R, chunk kk):
  // line = R>>1, c = ((R&1)<<2)|kk, c' = c ^ (line&7), off = line*64 + c'*8.
  int aoff[4], boff[4];
  #pragma unroll
  for (int mf = 0; mf < 4; ++mf) {
    const int R = wm + mf * 16 + f;
    const int c2 = (((R & 1) << 2) | kk) ^ ((R >> 1) & 7);
    aoff[mf] = (R >> 1) * 64 + c2 * 8;
  }
  #pragma unroll
  for (int nf = 0; nf < 4; ++nf) {
    const int R = wn + nf * 16 + f;
    const int c2 = (((R & 1) << 2) | kk) ^ ((R >> 1) & 7);
    boff[nf] = (R >> 1) * 64 + c2 * 8;
  }

  auto STAGE = [&](int set, int kt) {
    short* base = SM + set * 16384;
    GLL(Ah + offA0 + kt, base + Ld0);
    GLL(Ah + offA1 + kt, base + Ld1);
    GLL(Al + offA0 + kt, base + 4096 + Ld0);
    GLL(Al + offA1 + kt, base + 4096 + Ld1);
    GLL(Bh + offB0 + kt, base + 8192 + Ld0);
    GLL(Bh + offB1 + kt, base + 8192 + Ld1);
    GLL(Bl + offB0 + kt, base + 12288 + Ld0);
    GLL(Bl + offB1 + kt, base + 12288 + Ld1);
  };
  auto COMPUTE = [&](int set) {
    const short* p = SM + set * 16384;
    short8 ah[4], al[4], bh[4], bl[4];
    #pragma unroll
    for (int mf = 0; mf < 4; ++mf) {
      ah[mf] = *(const short8*)&p[aoff[mf]];
      al[mf] = *(const short8*)&p[4096 + aoff[mf]];
    }
    #pragma unroll
    for (int nf = 0; nf < 4; ++nf) {
      bh[nf] = *(const short8*)&p[8192 + boff[nf]];
      bl[nf] = *(const short8*)&p[12288 + boff[nf]];
    }
    #pragma unroll
    for (int mf = 0; mf < 4; ++mf)
      #pragma unroll
      for (int nf = 0; nf < 4; ++nf) {
        acc[mf][nf] = __builtin_amdgcn_mfma_f32_16x16x32_bf16(ah[mf], bh[nf], acc[mf][nf], 0, 0, 0);
        acc[mf][nf] = __builtin_amdgcn_mfma_f32_16x16x32_bf16(ah[mf], bl[nf], acc[mf][nf], 0, 0, 0);
        acc[mf][nf] = __builtin_amdgcn_mfma_f32_16x16x32_bf16(al[mf], bh[nf], acc[mf][nf], 0, 0, 0);
      }
  };

  STAGE(0, 0);
  #pragma unroll 1
  for (int t = 0; t < NT - 1; ++t) {
    STAGE((t + 1) & 1, (t + 1) * 32);
    asm volatile("s_waitcnt vmcnt(8)" ::: "memory");
    __builtin_amdgcn_sched_barrier(0);
    __builtin_amdgcn_s_barrier();
    COMPUTE(t & 1);
    __builtin_amdgcn_s_barrier();
  }
  asm volatile("s_waitcnt vmcnt(0)" ::: "memory");
  __builtin_amdgcn_sched_barrier(0);
  __builtin_amdgcn_s_barrier();
  COMPUTE((NT - 1) & 1);
  __builtin_amdgcn_s_barrier();
}

// ---------------- prep kernels ----------------

__global__ __launch_bounds__(256) void c_kernel(const float* __restrict__ W1,
                                                const float* __restrict__ b1,
                                                const float* __restrict__ hist,
                                                float* __restrict__ c) {
  const int wave = threadIdx.x >> 6, lane = threadIdx.x & 63;
  const int j = blockIdx.x * 4 + wave;
  const float* row = W1 + (size_t)j * 4096;
  float s = 0.f;
  #pragma unroll 2
  for (int kq = lane; kq < 512; kq += 64) {
    const float4 w = *(const float4*)&row[kq * 4];
    const float4 h = *(const float4*)&hist[kq * 4];
    s += w.x * h.x + w.y * h.y + w.z * h.z + w.w * h.w;
  }
  #pragma unroll
  for (int mask = 1; mask < 64; mask <<= 1) s += __shfl_xor(s, mask);
  if (lane == 0) c[j] = s + b1[j];
}

__global__ __launch_bounds__(256) void prep_A(const float* __restrict__ A,
                                              const float* __restrict__ b2,
                                              ushort_t* __restrict__ Ahi,
                                              ushort_t* __restrict__ Alo,
                                              float* __restrict__ ab2) {
  const int wv = threadIdx.x >> 6, lane = threadIdx.x & 63;
  const size_t row = (size_t)blockIdx.x * 4 + wv;
  const float* ar = A + row * 2048;
  float dot = 0.f;
  #pragma unroll 2
  for (int c0 = 0; c0 < 2048; c0 += 256) {
    const int col = c0 + lane * 4;
    const float4 v = *(const float4*)&ar[col];
    const float4 bb = *(const float4*)&b2[col];
    dot += v.x * bb.x + v.y * bb.y + v.z * bb.z + v.w * bb.w;
    ushort4 h, l;
    split_bf16(v.x, h.x, l.x); split_bf16(v.y, h.y, l.y);
    split_bf16(v.z, h.z, l.z); split_bf16(v.w, h.w, l.w);
    *(ushort4*)&Ahi[row * 2048 + col] = h;
    *(ushort4*)&Alo[row * 2048 + col] = l;
  }
  #pragma unroll
  for (int mask = 1; mask < 64; mask <<= 1) dot += __shfl_xor(dot, mask);
  if (lane == 0) ab2[row] = dot;
}

__global__ __launch_bounds__(256) void prep_Q(const float* __restrict__ Q,
                                              ushort_t* __restrict__ Qhi,
                                              ushort_t* __restrict__ Qlo) {
  const int wv = threadIdx.x >> 6, lane = threadIdx.x & 63;
  const size_t row = (size_t)blockIdx.x * 4 + wv;  // grid 32 -> 128 rows
  const float* qr = Q + row * 2048;
  #pragma unroll 2
  for (int c0 = 0; c0 < 2048; c0 += 256) {
    const int col = c0 + lane * 4;
    const float4 v = *(const float4*)&qr[col];
    ushort4 h, l;
    split_bf16(v.x, h.x, l.x); split_bf16(v.y, h.y, l.y);
    split_bf16(v.z, h.z, l.z); split_bf16(v.w, h.w, l.w);
    *(ushort4*)&Qhi[row * 2048 + col] = h;
    *(ushort4*)&Qlo[row * 2048 + col] = l;
  }
}

// dst_hi/lo[c*ldR + r] = split(src[r*C + c])
__global__ __launch_bounds__(256) void transpose_split(const float* __restrict__ src,
                                                       int R, int C,
                                                       ushort_t* __restrict__ dhi,
                                                       ushort_t* __restrict__ dlo) {
  __shared__ float T[64][65];
  const int c0 = blockIdx.x * 64, r0 = blockIdx.y * 64;
  const int t = threadIdx.x;
  {
    const int rl = t >> 4, cl = (t & 15) * 4;
    #pragma unroll
    for (int ii = 0; ii < 4; ++ii) {
      const float4 v = *(const float4*)&src[(size_t)(r0 + rl + ii * 16) * C + c0 + cl];
      T[rl + ii * 16][cl + 0] = v.x; T[rl + ii * 16][cl + 1] = v.y;
      T[rl + ii * 16][cl + 2] = v.z; T[rl + ii * 16][cl + 3] = v.w;
    }
  }
  __syncthreads();
  const int cc = t >> 2, rr0 = (t & 3) * 16;
  union { ushort_t u[16]; ushort4 v[4]; } H, L;
  #pragma unroll
  for (int k = 0; k < 16; ++k) split_bf16(T[rr0 + k][cc], H.u[k], L.u[k]);
  ushort_t* ph = dhi + (size_t)(c0 + cc) * R + r0 + rr0;
  ushort_t* pl = dlo + (size_t)(c0 + cc) * R + r0 + rr0;
  #pragma unroll
  for (int k4 = 0; k4 < 4; ++k4) {
    *(ushort4*)&ph[k4 * 4] = H.v[k4];
    *(ushort4*)&pl[k4 * 4] = L.v[k4];
  }
}

__global__ __launch_bounds__(256) void split_plain(const float* __restrict__ src,
                                                   ushort_t* __restrict__ dhi,
                                                   ushort_t* __restrict__ dlo) {
  const size_t i = ((size_t)blockIdx.x * 256 + threadIdx.x) * 4;
  const float4 v = *(const float4*)&src[i];
  ushort4 h, l;
  split_bf16(v.x, h.x, l.x); split_bf16(v.y, h.y, l.y);
  split_bf16(v.z, h.z, l.z); split_bf16(v.w, h.w, l.w);
  *(ushort4*)&dhi[i] = h;
  *(ushort4*)&dlo[i] = l;
}

// fp32 tiled GEMM (B^T layout): C[m][n] = sum_k A[m*lda+k]*B[n*ldb+k]
template <int BM, int TM>
__global__ __launch_bounds__(256) void gemm_bt(const float* __restrict__ A,
                                               const float* __restrict__ B,
                                               float* __restrict__ C,
                                               int K, int lda, int ldb, int ldc) {
  constexpr int BN = 64, BK = 32;
  constexpr int ASTR = BM + 12, BSTR = BN + 4;
  __shared__ float As[BK][ASTR];
  __shared__ float Bs[BK][BSTR];
  const int tid = threadIdx.x;
  const int tx = tid & 15, ty = tid >> 4;
  const int m0 = ty * TM, n0 = tx * 4;
  const size_t bm = (size_t)blockIdx.x * BM, bn = (size_t)blockIdx.y * BN;
  const float* Ab = A + bm * lda;
  const float* Bb = B + bn * ldb;
  float acc[TM][4];
  #pragma unroll
  for (int i = 0; i < TM; ++i)
    #pragma unroll
    for (int j = 0; j < 4; ++j) acc[i][j] = 0.f;
  for (int kt = 0; kt < K; kt += BK) {
    #pragma unroll
    for (int it = 0; it < BM * BK / 4 / 256; ++it) {
      const int idx = it * 256 + tid;
      const int row = idx >> 3, kq = idx & 7;
      const float4 v = *(const float4*)&Ab[(size_t)row * lda + kt + kq * 4];
      As[kq * 4 + 0][row] = v.x; As[kq * 4 + 1][row] = v.y;
      As[kq * 4 + 2][row] = v.z; As[kq * 4 + 3][row] = v.w;
    }
    #pragma unroll
    for (int it = 0; it < BN * BK / 4 / 256; ++it) {
      const int idx = it * 256 + tid;
      const int row = idx >> 3, kq = idx & 7;
      const float4 v = *(const float4*)&Bb[(size_t)row * ldb + kt + kq * 4];
      Bs[kq * 4 + 0][row] = v.x; Bs[kq * 4 + 1][row] = v.y;
      Bs[kq * 4 + 2][row] = v.z; Bs[kq * 4 + 3][row] = v.w;
    }
    __syncthreads();
    #pragma unroll
    for (int k = 0; k < BK; ++k) {
      float av[TM];
      #pragma unroll
      for (int i = 0; i < TM; ++i) av[i] = As[k][m0 + i];
      const float4 b = *(const float4*)&Bs[k][n0];
      const float bv[4] = {b.x, b.y, b.z, b.w};
      #pragma unroll
      for (int i = 0; i < TM; ++i)
        #pragma unroll
        for (int j = 0; j < 4; ++j) acc[i][j] = fmaf(av[i], bv[j], acc[i][j]);
    }
    __syncthreads();
  }
  #pragma unroll
  for (int i = 0; i < TM; ++i) {
    float* crow = C + (bm + m0 + i) * (size_t)ldc + bn + n0;
    #pragma unroll
    for (int j = 0; j < 4; ++j) crow[j] = acc[i][j];
  }
}

// ---------------- S = A@Q^T + fused row softmax -> attn hi/lo ----------------
__global__ __launch_bounds__(256, 2) void s_attn(const ushort_t* __restrict__ Ahi,
                                                 const ushort_t* __restrict__ Alo,
                                                 const ushort_t* __restrict__ Qhi,
                                                 const ushort_t* __restrict__ Qlo,
                                                 ushort_t* __restrict__ at_hi,
                                                 ushort_t* __restrict__ at_lo) {
  __shared__ short SM[32768];  // 64 KB
  const int tid = threadIdx.x, lane = tid & 63, wv = tid >> 6;
  const int wm = (wv >> 1) * 64, wn = (wv & 1) * 64;
  const int f = lane & 15, kk = lane >> 4;
  const size_t bm = (size_t)blockIdx.x * 128;

  f32x4 acc[4][4];
  #pragma unroll
  for (int mf = 0; mf < 4; ++mf)
    #pragma unroll
    for (int nf = 0; nf < 4; ++nf) acc[mf][nf] = 0.f;

  kloop<64, 2048, 2048>(Ahi + bm * 2048, Alo + bm * 2048, Qhi, Qlo,
                        SM, acc, lane, wv, wm, wn);

  // fused softmax over full rows (128 cols; wave-pair shares rows)
  float* sred = (float*)SM;        // [128][2] row-max
  float* ssum = sred + 256;        // [128][2] row-sum
  const int rowbase = wm + kk * 4;
  float rmax[4][4];
  #pragma unroll
  for (int mf = 0; mf < 4; ++mf)
    #pragma unroll
    for (int r = 0; r < 4; ++r) {
      float m4 = fmaxf(fmaxf(acc[mf][0][r], acc[mf][1][r]),
                       fmaxf(acc[mf][2][r], acc[mf][3][r]));
      m4 = fmaxf(m4, __shfl_xor(m4, 1));
      m4 = fmaxf(m4, __shfl_xor(m4, 2));
      m4 = fmaxf(m4, __shfl_xor(m4, 4));
      m4 = fmaxf(m4, __shfl_xor(m4, 8));
      rmax[mf][r] = m4;
    }
  if (f == 0) {
    #pragma unroll
    for (int mf = 0; mf < 4; ++mf)
      #pragma unroll
      for (int r = 0; r < 4; ++r)
        sred[(rowbase + mf * 16 + r) * 2 + (wv & 1)] = rmax[mf][r];
  }
  __syncthreads();
  #pragma unroll
  for (int mf = 0; mf < 4; ++mf)
    #pragma unroll
    for (int r = 0; r < 4; ++r) {
      const int row = rowbase + mf * 16 + r;
      rmax[mf][r] = fmaxf(sred[row * 2], sred[row * 2 + 1]);
    }
  float rsum[4][4];
  #pragma unroll
  for (int mf = 0; mf < 4; ++mf)
    #pragma unroll
    for (int r = 0; r < 4; ++r) {
      float s = 0.f;
      #pragma unroll
      for (int nf = 0; nf < 4; ++nf) {
        acc[mf][nf][r] = __expf(acc[mf][nf][r] - rmax[mf][r]);
        s += acc[mf][nf][r];
      }
      s += __shfl_xor(s, 1);
      s += __shfl_xor(s, 2);
      s += __shfl_xor(s, 4);
      s += __shfl_xor(s, 8);
      rsum[mf][r] = s;
    }
  if (f == 0) {
    #pragma unroll
    for (int mf = 0; mf < 4; ++mf)
      #pragma unroll
      for (int r = 0; r < 4; ++r)
        ssum[(rowbase + mf * 16 + r) * 2 + (wv & 1)] = rsum[mf][r];
  }
  __syncthreads();
  #pragma unroll
  for (int mf = 0; mf < 4; ++mf)
    #pragma unroll
    for (int r = 0; r < 4; ++r) {
      const int row = rowbase + mf * 16 + r;
      const float inv = 1.0f / (ssum[row * 2] + ssum[row * 2 + 1]);
      const size_t orow = (bm + row) * 128;
      #pragma unroll
      for (int nf = 0; nf < 4; ++nf) {
        ushort_t hi, lo;
        split_bf16(acc[mf][nf][r] * inv, hi, lo);
        const size_t idx = orow + wn + nf * 16 + f;
        at_hi[idx] = hi;
        at_lo[idx] = lo;
      }
    }
}

// ---------------- fused z/h/G/dot ----------------
__global__ __launch_bounds__(256, 2) void fused_zg_mfma(
    const ushort_t* __restrict__ Ahi, const ushort_t* __restrict__ Alo,
    const ushort_t* __restrict__ at_hi, const ushort_t* __restrict__ at_lo,
    const ushort_t* __restrict__ QWt_hi, const ushort_t* __restrict__ QWt_lo,
    const ushort_t* __restrict__ W2t_hi, const ushort_t* __restrict__ W2t_lo,
    const float* __restrict__ cvec, float* __restrict__ partial) {
  __shared__ short SM[32768];  // 64 KB
  const int tid = threadIdx.x, lane = tid & 63, wv = tid >> 6;
  const int wm = (wv >> 1) * 64, wn = (wv & 1) * 64;
  const int f = lane & 15, kk = lane >> 4;
  const size_t bm = (size_t)blockIdx.x * 128;
  const size_t bn = (size_t)blockIdx.y * 128;

  f32x4 acc[4][4];
  #pragma unroll
  for (int mf = 0; mf < 4; ++mf)
    #pragma unroll
    for (int nf = 0; nf < 4; ++nf) acc[mf][nf] = 0.f;

  // phase Z: z = attn @ QWt, K = 128
  kloop<4, 128, 128>(at_hi + bm * 128, at_lo + bm * 128,
                     QWt_hi + bn * 128, QWt_lo + bn * 128,
                     SM, acc, lane, wv, wm, wn);

  // h = relu(z + c)
  float hreg[4][4][4];
  {
    float ccv[4];
    #pragma unroll
    for (int nf = 0; nf < 4; ++nf) ccv[nf] = cvec[bn + wn + nf * 16 + f];
    #pragma unroll
    for (int mf = 0; mf < 4; ++mf)
      #pragma unroll
      for (int nf = 0; nf < 4; ++nf)
        #pragma unroll
        for (int r = 0; r < 4; ++r) {
          hreg[mf][nf][r] = fmaxf(acc[mf][nf][r] + ccv[nf], 0.f);
          acc[mf][nf][r] = 0.f;
        }
  }

  // phase G: G = A @ W2t, K = 2048
  kloop<64, 2048, 2048>(Ahi + bm * 2048, Alo + bm * 2048,
                        W2t_hi + bn * 2048, W2t_lo + bn * 2048,
                        SM, acc, lane, wv, wm, wn);

  // epilogue: partial = sum over this block's 128 j of h*G
  float part[4][4];
  #pragma unroll
  for (int mf = 0; mf < 4; ++mf)
    #pragma unroll
    for (int r = 0; r < 4; ++r) {
      float s = 0.f;
      #pragma unroll
      for (int nf = 0; nf < 4; ++nf) s += hreg[mf][nf][r] * acc[mf][nf][r];
      part[mf][r] = s;
    }
  #pragma unroll
  for (int mf = 0; mf < 4; ++mf)
    #pragma unroll
    for (int r = 0; r < 4; ++r) {
      part[mf][r] += __shfl_xor(part[mf][r], 1);
      part[mf][r] += __shfl_xor(part[mf][r], 2);
      part[mf][r] += __shfl_xor(part[mf][r], 4);
      part[mf][r] += __shfl_xor(part[mf][r], 8);
    }
  if (f == 0) {
    const size_t slab = (size_t)(blockIdx.y * 2 + (wv & 1)) * 16384;
    #pragma unroll
    for (int mf = 0; mf < 4; ++mf)
      #pragma unroll
      for (int r = 0; r < 4; ++r)
        partial[slab + bm + wm + mf * 16 + kk * 4 + r] = part[mf][r];
  }
}

// ---------------- final reduction + softmax over M ----------------

__global__ __launch_bounds__(256) void k_sem(const float* __restrict__ partial,
                                             const float* __restrict__ ab2,
                                             float* __restrict__ semantic,
                                             float* __restrict__ bstats) {
  const int m = blockIdx.x * 256 + threadIdx.x;
  float s = ab2[m];
  #pragma unroll
  for (int nb = 0; nb < 32; ++nb) s += partial[(size_t)nb * 16384 + m];
  semantic[m] = s;
  float mx = s;
  #pragma unroll
  for (int mask = 1; mask < 64; mask <<= 1) mx = fmaxf(mx, __shfl_xor(mx, mask));
  __shared__ float wmax[4], wsum[4];
  const int wave = threadIdx.x >> 6, lane = threadIdx.x & 63;
  if (lane == 0) wmax[wave] = mx;
  __syncthreads();
  const float bmax = fmaxf(fmaxf(wmax[0], wmax[1]), fmaxf(wmax[2], wmax[3]));
  float e = expf(s - bmax);
  #pragma unroll
  for (int mask = 1; mask < 64; mask <<= 1) e += __shfl_xor(e, mask);
  if (lane == 0) wsum[wave] = e;
  __syncthreads();
  if (threadIdx.x == 0) {
    bstats[blockIdx.x * 2] = bmax;
    bstats[blockIdx.x * 2 + 1] = wsum[0] + wsum[1] + wsum[2] + wsum[3];
  }
}

__global__ void k_combine(const float* __restrict__ bstats, float* __restrict__ gstats) {
  const int t = threadIdx.x;
  const float bm = bstats[t * 2], bs = bstats[t * 2 + 1];
  float gm = bm;
  #pragma unroll
  for (int mask = 1; mask < 64; mask <<= 1) gm = fmaxf(gm, __shfl_xor(gm, mask));
  float gs = bs * expf(bm - gm);
  #pragma unroll
  for (int mask = 1; mask < 64; mask <<= 1) gs += __shfl_xor(gs, mask);
  if (t == 0) { gstats[0] = gm; gstats[1] = gs; }
}

__global__ __launch_bounds__(256) void k_out(const float* __restrict__ semantic,
                                             const float* __restrict__ gstats,
                                             float* __restrict__ out) {
  const int m = blockIdx.x * 256 + threadIdx.x;
  out[m] = expf(semantic[m] - gstats[0]) / gstats[1];
}

// ---------------- launch ----------------

extern "C" void kernel_launch(void* const* d_in, const int* in_sizes, int n_in,
                              void* d_out, int out_size, void* d_ws, size_t ws_size,
                              hipStream_t stream) {
  (void)in_sizes; (void)n_in; (void)out_size; (void)ws_size;
  const float* A    = (const float*)d_in[0];  // [16384][2048]
  const float* Q    = (const float*)d_in[1];  // [128][2048]
  const float* hist = (const float*)d_in[2];  // [2048]
  const float* W1   = (const float*)d_in[3];  // [2048][4096]
  const float* b1   = (const float*)d_in[4];  // [2048]
  const float* W2   = (const float*)d_in[5];  // [2048][2048]
  const float* b2   = (const float*)d_in[6];  // [2048]
  float* out = (float*)d_out;                 // [16384]

  char* ws = (char*)d_ws;
  ushort_t* A_hi   = (ushort_t*)ws;  ws += (size_t)16384 * 2048 * 2;  // 64 MB
  ushort_t* A_lo   = (ushort_t*)ws;  ws += (size_t)16384 * 2048 * 2;  // 64 MB
  ushort_t* W2t_hi = (ushort_t*)ws;  ws += (size_t)2048 * 2048 * 2;   // 8 MB
  ushort_t* W2t_lo = (ushort_t*)ws;  ws += (size_t)2048 * 2048 * 2;   // 8 MB
  ushort_t* Q_hi   = (ushort_t*)ws;  ws += (size_t)128 * 2048 * 2;
  ushort_t* Q_lo   = (ushort_t*)ws;  ws += (size_t)128 * 2048 * 2;
  ushort_t* QWt_hi = (ushort_t*)ws;  ws += (size_t)2048 * 128 * 2;
  ushort_t* QWt_lo = (ushort_t*)ws;  ws += (size_t)2048 * 128 * 2;
  ushort_t* at_hi  = (ushort_t*)ws;  ws += (size_t)16384 * 128 * 2;   // 4 MB
  ushort_t* at_lo  = (ushort_t*)ws;  ws += (size_t)16384 * 128 * 2;   // 4 MB
  float* qw1t      = (float*)ws;     ws += (size_t)2048 * 128 * 4;    // 1 MB
  float* c_vec     = (float*)ws;     ws += 2048 * 4;
  float* ab2       = (float*)ws;     ws += 16384 * 4;
  float* partial   = (float*)ws;     ws += (size_t)32 * 16384 * 4;    // 2 MB
  float* semantic  = (float*)ws;     ws += 16384 * 4;
  float* bstats    = (float*)ws;     ws += 128 * 4;
  float* gstats    = (float*)ws;     ws += 2 * 4;

  // prep
  c_kernel<<<512, 256, 0, stream>>>(W1, b1, hist, c_vec);
  // qw1t[j][n] = sum_k W1q[j][k] * Q[n][k]
  gemm_bt<32, 2><<<dim3(64, 2), 256, 0, stream>>>(W1 + 2048, Q, qw1t,
                                                  2048, 4096, 2048, 128);
  split_plain<<<256, 256, 0, stream>>>(qw1t, QWt_hi, QWt_lo);
  transpose_split<<<dim3(32, 32), 256, 0, stream>>>(W2, 2048, 2048, W2t_hi, W2t_lo);
  prep_Q<<<32, 256, 0, stream>>>(Q, Q_hi, Q_lo);
  prep_A<<<4096, 256, 0, stream>>>(A, b2, A_hi, A_lo, ab2);
  // S = A@Q^T + softmax (MFMA, fused)
  s_attn<<<128, 256, 0, stream>>>(A_hi, A_lo, Q_hi, Q_lo, at_hi, at_lo);
  // fused z/h/G/dot (MFMA split-3, dbuf pipelined)
  fused_zg_mfma<<<dim3(128, 16), 256, 0, stream>>>(A_hi, A_lo, at_hi, at_lo,
                                                   QWt_hi, QWt_lo, W2t_hi, W2t_lo,
                                                   c_vec, partial);
  // semantic + softmax over M
  k_sem<<<64, 256, 0, stream>>>(partial, ab2, semantic, bstats);
  k_combine<<<1, 64, 0, stream>>>(bstats, gstats);
  k_out<<<64, 256, 0, stream>>>(semantic, gstats, out);
}

// Round 6
// 392.553 us; speedup vs baseline: 2.2476x; 1.5003x over previous
//
#include <hip/hip_runtime.h>
#include <hip/hip_bf16.h>

// PolicyNet, fp16 MFMA version:
//   A -> Af + Al (fp16 + fp16 residual), ab2[m] = A[m]·b2;  Q -> Qf + Ql
//   c    = b1 + W1[:, :D] @ hist                  (fp32)
//   qw1t = W1[:, D:] @ Q^T (fp32 gemm) -> QWt f16
//   W2   -> transpose -> W2t f16 [j][k]
//   s_attn: S = A@Q^T via split-3 fp16 MFMA (Af·Qf + Af·Ql + Al·Qf),
//           fused row-softmax -> at f16
//   fused: z = at @ QWt (K=128, fp16 single); h = relu(z+c) fp32 regs
//          G = Af @ W2t (K=2048, fp16 single); partial = sum_j h*G
//   semantic = sum partial + ab2 -> softmax over M -> out

typedef _Float16 f16;
typedef __attribute__((ext_vector_type(8))) _Float16 half8;
typedef __attribute__((ext_vector_type(4))) _Float16 half4_t;
typedef __attribute__((ext_vector_type(4))) float f32x4;

#define GLL(gp, lp)                                                              \
  __builtin_amdgcn_global_load_lds(                                              \
      (const __attribute__((address_space(1))) void*)(gp),                       \
      (__attribute__((address_space(3))) void*)(lp), 16, 0, 0)

// ---------------- single-product fp16 K-loop ----------------
// BM=BN=128, BK=32, 4 waves (2m x 2n), wave tile 64x64 (4x4 of 16x16x32).
// LDS: 2 sets x {A,B} x 8KB = 32KB. GLL-staged, depth-1 prefetch,
// s_waitcnt vmcnt(4) steady state, raw s_barrier.
// Tile = 128 rows x 32 halves (64B/row); 128B line = 2 rows.
// Swizzle: 16B-chunk c' = c ^ (line&7); source pre-inverse-swizzled.
template <int NT, int LDA, int LDB>
__device__ __forceinline__ void kloop1(const f16* __restrict__ A,
                                       const f16* __restrict__ B,
                                       f16* __restrict__ SM,
                                       f32x4 (&acc)[4][4],
                                       int lane, int wv, int wm, int wn) {
  const int f = lane & 15, kk = lane >> 4;
  const int cS = (lane & 7) ^ (lane >> 3);
  const int kkS = (cS & 3) * 8;
  const int rS = 2 * (lane >> 3) + (cS >> 2);
  const size_t offA0 = (size_t)(16 * (wv * 2 + 0) + rS) * LDA + kkS;
  const size_t offA1 = (size_t)(16 * (wv * 2 + 1) + rS) * LDA + kkS;
  const size_t offB0 = (size_t)(16 * (wv * 2 + 0) + rS) * LDB + kkS;
  const size_t offB1 = (size_t)(16 * (wv * 2 + 1) + rS) * LDB + kkS;
  const int Ld0 = (wv * 2 + 0) * 512, Ld1 = (wv * 2 + 1) * 512;

  int aoff[4], boff[4];
  #pragma unroll
  for (int mf = 0; mf < 4; ++mf) {
    const int R = wm + mf * 16 + f;
    const int c2 = (((R & 1) << 2) | kk) ^ ((R >> 1) & 7);
    aoff[mf] = (R >> 1) * 64 + c2 * 8;
  }
  #pragma unroll
  for (int nf = 0; nf < 4; ++nf) {
    const int R = wn + nf * 16 + f;
    const int c2 = (((R & 1) << 2) | kk) ^ ((R >> 1) & 7);
    boff[nf] = (R >> 1) * 64 + c2 * 8;
  }

  auto STAGE = [&](int set, int kt) {
    f16* base = SM + set * 8192;
    GLL(A + offA0 + kt, base + Ld0);
    GLL(A + offA1 + kt, base + Ld1);
    GLL(B + offB0 + kt, base + 4096 + Ld0);
    GLL(B + offB1 + kt, base + 4096 + Ld1);
  };
  auto COMPUTE = [&](int set) {
    const f16* p = SM + set * 8192;
    half8 a[4], b[4];
    #pragma unroll
    for (int mf = 0; mf < 4; ++mf) a[mf] = *(const half8*)&p[aoff[mf]];
    #pragma unroll
    for (int nf = 0; nf < 4; ++nf) b[nf] = *(const half8*)&p[4096 + boff[nf]];
    #pragma unroll
    for (int mf = 0; mf < 4; ++mf)
      #pragma unroll
      for (int nf = 0; nf < 4; ++nf)
        acc[mf][nf] = __builtin_amdgcn_mfma_f32_16x16x32_f16(a[mf], b[nf], acc[mf][nf], 0, 0, 0);
  };

  STAGE(0, 0);
  #pragma unroll 1
  for (int t = 0; t < NT - 1; ++t) {
    STAGE((t + 1) & 1, (t + 1) * 32);
    asm volatile("s_waitcnt vmcnt(4)" ::: "memory");
    __builtin_amdgcn_sched_barrier(0);
    __builtin_amdgcn_s_barrier();
    COMPUTE(t & 1);
    __builtin_amdgcn_s_barrier();
  }
  asm volatile("s_waitcnt vmcnt(0)" ::: "memory");
  __builtin_amdgcn_sched_barrier(0);
  __builtin_amdgcn_s_barrier();
  COMPUTE((NT - 1) & 1);
  __builtin_amdgcn_s_barrier();
}

// ---------------- split-3 fp16 K-loop (score path) ----------------
// Same geometry, 4 tiles {Ah,Al,Bh,Bl} x 8KB x 2 sets = 64KB, vmcnt(8).
template <int NT, int LDA, int LDB>
__device__ __forceinline__ void kloop3(const f16* __restrict__ Ah,
                                       const f16* __restrict__ Al,
                                       const f16* __restrict__ Bh,
                                       const f16* __restrict__ Bl,
                                       f16* __restrict__ SM,
                                       f32x4 (&acc)[4][4],
                                       int lane, int wv, int wm, int wn) {
  const int f = lane & 15, kk = lane >> 4;
  const int cS = (lane & 7) ^ (lane >> 3);
  const int kkS = (cS & 3) * 8;
  const int rS = 2 * (lane >> 3) + (cS >> 2);
  const size_t offA0 = (size_t)(16 * (wv * 2 + 0) + rS) * LDA + kkS;
  const size_t offA1 = (size_t)(16 * (wv * 2 + 1) + rS) * LDA + kkS;
  const size_t offB0 = (size_t)(16 * (wv * 2 + 0) + rS) * LDB + kkS;
  const size_t offB1 = (size_t)(16 * (wv * 2 + 1) + rS) * LDB + kkS;
  const int Ld0 = (wv * 2 + 0) * 512, Ld1 = (wv * 2 + 1) * 512;

  int aoff[4], boff[4];
  #pragma unroll
  for (int mf = 0; mf < 4; ++mf) {
    const int R = wm + mf * 16 + f;
    const int c2 = (((R & 1) << 2) | kk) ^ ((R >> 1) & 7);
    aoff[mf] = (R >> 1) * 64 + c2 * 8;
  }
  #pragma unroll
  for (int nf = 0; nf < 4; ++nf) {
    const int R = wn + nf * 16 + f;
    const int c2 = (((R & 1) << 2) | kk) ^ ((R >> 1) & 7);
    boff[nf] = (R >> 1) * 64 + c2 * 8;
  }

  auto STAGE = [&](int set, int kt) {
    f16* base = SM + set * 16384;
    GLL(Ah + offA0 + kt, base + Ld0);
    GLL(Ah + offA1 + kt, base + Ld1);
    GLL(Al + offA0 + kt, base + 4096 + Ld0);
    GLL(Al + offA1 + kt, base + 4096 + Ld1);
    GLL(Bh + offB0 + kt, base + 8192 + Ld0);
    GLL(Bh + offB1 + kt, base + 8192 + Ld1);
    GLL(Bl + offB0 + kt, base + 12288 + Ld0);
    GLL(Bl + offB1 + kt, base + 12288 + Ld1);
  };
  auto COMPUTE = [&](int set) {
    const f16* p = SM + set * 16384;
    half8 ah[4], al[4], bh[4], bl[4];
    #pragma unroll
    for (int mf = 0; mf < 4; ++mf) {
      ah[mf] = *(const half8*)&p[aoff[mf]];
      al[mf] = *(const half8*)&p[4096 + aoff[mf]];
    }
    #pragma unroll
    for (int nf = 0; nf < 4; ++nf) {
      bh[nf] = *(const half8*)&p[8192 + boff[nf]];
      bl[nf] = *(const half8*)&p[12288 + boff[nf]];
    }
    #pragma unroll
    for (int mf = 0; mf < 4; ++mf)
      #pragma unroll
      for (int nf = 0; nf < 4; ++nf) {
        acc[mf][nf] = __builtin_amdgcn_mfma_f32_16x16x32_f16(ah[mf], bh[nf], acc[mf][nf], 0, 0, 0);
        acc[mf][nf] = __builtin_amdgcn_mfma_f32_16x16x32_f16(ah[mf], bl[nf], acc[mf][nf], 0, 0, 0);
        acc[mf][nf] = __builtin_amdgcn_mfma_f32_16x16x32_f16(al[mf], bh[nf], acc[mf][nf], 0, 0, 0);
      }
  };

  STAGE(0, 0);
  #pragma unroll 1
  for (int t = 0; t < NT - 1; ++t) {
    STAGE((t + 1) & 1, (t + 1) * 32);
    asm volatile("s_waitcnt vmcnt(8)" ::: "memory");
    __builtin_amdgcn_sched_barrier(0);
    __builtin_amdgcn_s_barrier();
    COMPUTE(t & 1);
    __builtin_amdgcn_s_barrier();
  }
  asm volatile("s_waitcnt vmcnt(0)" ::: "memory");
  __builtin_amdgcn_sched_barrier(0);
  __builtin_amdgcn_s_barrier();
  COMPUTE((NT - 1) & 1);
  __builtin_amdgcn_s_barrier();
}

// ---------------- prep kernels ----------------

__global__ __launch_bounds__(256) void c_kernel(const float* __restrict__ W1,
                                                const float* __restrict__ b1,
                                                const float* __restrict__ hist,
                                                float* __restrict__ c) {
  const int wave = threadIdx.x >> 6, lane = threadIdx.x & 63;
  const int j = blockIdx.x * 4 + wave;
  const float* row = W1 + (size_t)j * 4096;
  float s = 0.f;
  #pragma unroll 2
  for (int kq = lane; kq < 512; kq += 64) {
    const float4 w = *(const float4*)&row[kq * 4];
    const float4 h = *(const float4*)&hist[kq * 4];
    s += w.x * h.x + w.y * h.y + w.z * h.z + w.w * h.w;
  }
  #pragma unroll
  for (int mask = 1; mask < 64; mask <<= 1) s += __shfl_xor(s, mask);
  if (lane == 0) c[j] = s + b1[j];
}

// split through scalar temporaries (vector elements can't bind to refs)
__device__ __forceinline__ half4_t f16hi4(const float4 v) {
  half4_t h;
  h.x = (f16)v.x; h.y = (f16)v.y; h.z = (f16)v.z; h.w = (f16)v.w;
  return h;
}
__device__ __forceinline__ half4_t f16lo4(const float4 v, const half4_t h) {
  half4_t l;
  l.x = (f16)(v.x - (float)h.x);
  l.y = (f16)(v.y - (float)h.y);
  l.z = (f16)(v.z - (float)h.z);
  l.w = (f16)(v.w - (float)h.w);
  return l;
}

// wave per row: A -> Af/Al fp16, ab2[m] = A[m]·b2
__global__ __launch_bounds__(256) void prep_A(const float* __restrict__ A,
                                              const float* __restrict__ b2,
                                              f16* __restrict__ Af,
                                              f16* __restrict__ Al,
                                              float* __restrict__ ab2) {
  const int wv = threadIdx.x >> 6, lane = threadIdx.x & 63;
  const size_t row = (size_t)blockIdx.x * 4 + wv;
  const float* ar = A + row * 2048;
  float dot = 0.f;
  #pragma unroll 2
  for (int c0 = 0; c0 < 2048; c0 += 256) {
    const int col = c0 + lane * 4;
    const float4 v = *(const float4*)&ar[col];
    const float4 bb = *(const float4*)&b2[col];
    dot += v.x * bb.x + v.y * bb.y + v.z * bb.z + v.w * bb.w;
    const half4_t h = f16hi4(v);
    const half4_t l = f16lo4(v, h);
    *(half4_t*)&Af[row * 2048 + col] = h;
    *(half4_t*)&Al[row * 2048 + col] = l;
  }
  #pragma unroll
  for (int mask = 1; mask < 64; mask <<= 1) dot += __shfl_xor(dot, mask);
  if (lane == 0) ab2[row] = dot;
}

__global__ __launch_bounds__(256) void prep_Q(const float* __restrict__ Q,
                                              f16* __restrict__ Qf,
                                              f16* __restrict__ Ql) {
  const int wv = threadIdx.x >> 6, lane = threadIdx.x & 63;
  const size_t row = (size_t)blockIdx.x * 4 + wv;  // grid 32 -> 128 rows
  const float* qr = Q + row * 2048;
  #pragma unroll 2
  for (int c0 = 0; c0 < 2048; c0 += 256) {
    const int col = c0 + lane * 4;
    const float4 v = *(const float4*)&qr[col];
    const half4_t h = f16hi4(v);
    const half4_t l = f16lo4(v, h);
    *(half4_t*)&Qf[row * 2048 + col] = h;
    *(half4_t*)&Ql[row * 2048 + col] = l;
  }
}

// dst[c*ldR + r] = (f16)src[r*C + c]
__global__ __launch_bounds__(256) void transpose_f16(const float* __restrict__ src,
                                                     int R, int C,
                                                     f16* __restrict__ dst) {
  __shared__ float T[64][65];
  const int c0 = blockIdx.x * 64, r0 = blockIdx.y * 64;
  const int t = threadIdx.x;
  {
    const int rl = t >> 4, cl = (t & 15) * 4;
    #pragma unroll
    for (int ii = 0; ii < 4; ++ii) {
      const float4 v = *(const float4*)&src[(size_t)(r0 + rl + ii * 16) * C + c0 + cl];
      T[rl + ii * 16][cl + 0] = v.x; T[rl + ii * 16][cl + 1] = v.y;
      T[rl + ii * 16][cl + 2] = v.z; T[rl + ii * 16][cl + 3] = v.w;
    }
  }
  __syncthreads();
  const int cc = t >> 2, rr0 = (t & 3) * 16;
  f16 u[16];
  #pragma unroll
  for (int k = 0; k < 16; ++k) u[k] = (f16)T[rr0 + k][cc];
  f16* ph = dst + (size_t)(c0 + cc) * R + r0 + rr0;
  #pragma unroll
  for (int k4 = 0; k4 < 4; ++k4)
    *(half4_t*)&ph[k4 * 4] = *(half4_t*)&u[k4 * 4];
}

__global__ __launch_bounds__(256) void to_f16(const float* __restrict__ src,
                                              f16* __restrict__ dst) {
  const size_t i = ((size_t)blockIdx.x * 256 + threadIdx.x) * 4;
  const float4 v = *(const float4*)&src[i];
  *(half4_t*)&dst[i] = f16hi4(v);
}

// fp32 tiled GEMM (B^T layout): C[m][n] = sum_k A[m*lda+k]*B[n*ldb+k]
template <int BM, int TM>
__global__ __launch_bounds__(256) void gemm_bt(const float* __restrict__ A,
                                               const float* __restrict__ B,
                                               float* __restrict__ C,
                                               int K, int lda, int ldb, int ldc) {
  constexpr int BN = 64, BK = 32;
  constexpr int ASTR = BM + 12, BSTR = BN + 4;
  __shared__ float As[BK][ASTR];
  __shared__ float Bs[BK][BSTR];
  const int tid = threadIdx.x;
  const int tx = tid & 15, ty = tid >> 4;
  const int m0 = ty * TM, n0 = tx * 4;
  const size_t bm = (size_t)blockIdx.x * BM, bn = (size_t)blockIdx.y * BN;
  const float* Ab = A + bm * lda;
  const float* Bb = B + bn * ldb;
  float acc[TM][4];
  #pragma unroll
  for (int i = 0; i < TM; ++i)
    #pragma unroll
    for (int j = 0; j < 4; ++j) acc[i][j] = 0.f;
  for (int kt = 0; kt < K; kt += BK) {
    #pragma unroll
    for (int it = 0; it < BM * BK / 4 / 256; ++it) {
      const int idx = it * 256 + tid;
      const int row = idx >> 3, kq = idx & 7;
      const float4 v = *(const float4*)&Ab[(size_t)row * lda + kt + kq * 4];
      As[kq * 4 + 0][row] = v.x; As[kq * 4 + 1][row] = v.y;
      As[kq * 4 + 2][row] = v.z; As[kq * 4 + 3][row] = v.w;
    }
    #pragma unroll
    for (int it = 0; it < BN * BK / 4 / 256; ++it) {
      const int idx = it * 256 + tid;
      const int row = idx >> 3, kq = idx & 7;
      const float4 v = *(const float4*)&Bb[(size_t)row * ldb + kt + kq * 4];
      Bs[kq * 4 + 0][row] = v.x; Bs[kq * 4 + 1][row] = v.y;
      Bs[kq * 4 + 2][row] = v.z; Bs[kq * 4 + 3][row] = v.w;
    }
    __syncthreads();
    #pragma unroll
    for (int k = 0; k < BK; ++k) {
      float av[TM];
      #pragma unroll
      for (int i = 0; i < TM; ++i) av[i] = As[k][m0 + i];
      const float4 b = *(const float4*)&Bs[k][n0];
      const float bv[4] = {b.x, b.y, b.z, b.w};
      #pragma unroll
      for (int i = 0; i < TM; ++i)
        #pragma unroll
        for (int j = 0; j < 4; ++j) acc[i][j] = fmaf(av[i], bv[j], acc[i][j]);
    }
    __syncthreads();
  }
  #pragma unroll
  for (int i = 0; i < TM; ++i) {
    float* crow = C + (bm + m0 + i) * (size_t)ldc + bn + n0;
    #pragma unroll
    for (int j = 0; j < 4; ++j) crow[j] = acc[i][j];
  }
}

// ---------------- S = A@Q^T (split-3 fp16) + fused row softmax -> at f16 ----
__global__ __launch_bounds__(256, 2) void s_attn(const f16* __restrict__ Af,
                                                 const f16* __restrict__ Al,
                                                 const f16* __restrict__ Qf,
                                                 const f16* __restrict__ Ql,
                                                 f16* __restrict__ at) {
  __shared__ f16 SM[32768];  // 64 KB
  const int tid = threadIdx.x, lane = tid & 63, wv = tid >> 6;
  const int wm = (wv >> 1) * 64, wn = (wv & 1) * 64;
  const int f = lane & 15, kk = lane >> 4;
  const size_t bm = (size_t)blockIdx.x * 128;

  f32x4 acc[4][4];
  #pragma unroll
  for (int mf = 0; mf < 4; ++mf)
    #pragma unroll
    for (int nf = 0; nf < 4; ++nf) acc[mf][nf] = 0.f;

  kloop3<64, 2048, 2048>(Af + bm * 2048, Al + bm * 2048, Qf, Ql,
                         SM, acc, lane, wv, wm, wn);

  // fused softmax over full rows (128 cols; wave-pair shares rows)
  float* sred = (float*)SM;        // [128][2] row-max
  float* ssum = sred + 256;        // [128][2] row-sum
  const int rowbase = wm + kk * 4;
  float rmax[4][4];
  #pragma unroll
  for (int mf = 0; mf < 4; ++mf)
    #pragma unroll
    for (int r = 0; r < 4; ++r) {
      float m4 = fmaxf(fmaxf(acc[mf][0][r], acc[mf][1][r]),
                       fmaxf(acc[mf][2][r], acc[mf][3][r]));
      m4 = fmaxf(m4, __shfl_xor(m4, 1));
      m4 = fmaxf(m4, __shfl_xor(m4, 2));
      m4 = fmaxf(m4, __shfl_xor(m4, 4));
      m4 = fmaxf(m4, __shfl_xor(m4, 8));
      rmax[mf][r] = m4;
    }
  if (f == 0) {
    #pragma unroll
    for (int mf = 0; mf < 4; ++mf)
      #pragma unroll
      for (int r = 0; r < 4; ++r)
        sred[(rowbase + mf * 16 + r) * 2 + (wv & 1)] = rmax[mf][r];
  }
  __syncthreads();
  #pragma unroll
  for (int mf = 0; mf < 4; ++mf)
    #pragma unroll
    for (int r = 0; r < 4; ++r) {
      const int row = rowbase + mf * 16 + r;
      rmax[mf][r] = fmaxf(sred[row * 2], sred[row * 2 + 1]);
    }
  float rsum[4][4];
  #pragma unroll
  for (int mf = 0; mf < 4; ++mf)
    #pragma unroll
    for (int r = 0; r < 4; ++r) {
      float s = 0.f;
      #pragma unroll
      for (int nf = 0; nf < 4; ++nf) {
        acc[mf][nf][r] = __expf(acc[mf][nf][r] - rmax[mf][r]);
        s += acc[mf][nf][r];
      }
      s += __shfl_xor(s, 1);
      s += __shfl_xor(s, 2);
      s += __shfl_xor(s, 4);
      s += __shfl_xor(s, 8);
      rsum[mf][r] = s;
    }
  if (f == 0) {
    #pragma unroll
    for (int mf = 0; mf < 4; ++mf)
      #pragma unroll
      for (int r = 0; r < 4; ++r)
        ssum[(rowbase + mf * 16 + r) * 2 + (wv & 1)] = rsum[mf][r];
  }
  __syncthreads();
  #pragma unroll
  for (int mf = 0; mf < 4; ++mf)
    #pragma unroll
    for (int r = 0; r < 4; ++r) {
      const int row = rowbase + mf * 16 + r;
      const float inv = 1.0f / (ssum[row * 2] + ssum[row * 2 + 1]);
      const size_t orow = (bm + row) * 128;
      #pragma unroll
      for (int nf = 0; nf < 4; ++nf)
        at[orow + wn + nf * 16 + f] = (f16)(acc[mf][nf][r] * inv);
    }
}

// ---------------- fused z/h/G/dot ----------------
__global__ __launch_bounds__(256, 2) void fused_zg_mfma(
    const f16* __restrict__ Af, const f16* __restrict__ at,
    const f16* __restrict__ QWt, const f16* __restrict__ W2t,
    const float* __restrict__ cvec, float* __restrict__ partial) {
  __shared__ f16 SM[16384];  // 32 KB
  const int tid = threadIdx.x, lane = tid & 63, wv = tid >> 6;
  const int wm = (wv >> 1) * 64, wn = (wv & 1) * 64;
  const int f = lane & 15, kk = lane >> 4;
  // bijective XCD swizzle: nwg=2048, 8 XCDs, 256 per XCD (x-fast within XCD)
  const int lin = blockIdx.x;
  const int sid = (lin & 7) * 256 + (lin >> 3);
  const int bmI = sid & 127, bnI = sid >> 7;
  const size_t bm = (size_t)bmI * 128;
  const size_t bn = (size_t)bnI * 128;

  f32x4 acc[4][4];
  #pragma unroll
  for (int mf = 0; mf < 4; ++mf)
    #pragma unroll
    for (int nf = 0; nf < 4; ++nf) acc[mf][nf] = 0.f;

  // phase Z: z = at @ QWt, K = 128 (fp16 single)
  kloop1<4, 128, 128>(at + bm * 128, QWt + bn * 128, SM, acc, lane, wv, wm, wn);

  // h = relu(z + c), fp32 regs
  float hreg[4][4][4];
  {
    float ccv[4];
    #pragma unroll
    for (int nf = 0; nf < 4; ++nf) ccv[nf] = cvec[bn + wn + nf * 16 + f];
    #pragma unroll
    for (int mf = 0; mf < 4; ++mf)
      #pragma unroll
      for (int nf = 0; nf < 4; ++nf)
        #pragma unroll
        for (int r = 0; r < 4; ++r) {
          hreg[mf][nf][r] = fmaxf(acc[mf][nf][r] + ccv[nf], 0.f);
          acc[mf][nf][r] = 0.f;
        }
  }

  // phase G: G = Af @ W2t, K = 2048 (fp16 single)
  kloop1<64, 2048, 2048>(Af + bm * 2048, W2t + bn * 2048, SM, acc, lane, wv, wm, wn);

  // epilogue: partial = sum over this block's 128 j of h*G
  float part[4][4];
  #pragma unroll
  for (int mf = 0; mf < 4; ++mf)
    #pragma unroll
    for (int r = 0; r < 4; ++r) {
      float s = 0.f;
      #pragma unroll
      for (int nf = 0; nf < 4; ++nf) s += hreg[mf][nf][r] * acc[mf][nf][r];
      part[mf][r] = s;
    }
  #pragma unroll
  for (int mf = 0; mf < 4; ++mf)
    #pragma unroll
    for (int r = 0; r < 4; ++r) {
      part[mf][r] += __shfl_xor(part[mf][r], 1);
      part[mf][r] += __shfl_xor(part[mf][r], 2);
      part[mf][r] += __shfl_xor(part[mf][r], 4);
      part[mf][r] += __shfl_xor(part[mf][r], 8);
    }
  if (f == 0) {
    const size_t slab = (size_t)(bnI * 2 + (wv & 1)) * 16384;
    #pragma unroll
    for (int mf = 0; mf < 4; ++mf)
      #pragma unroll
      for (int r = 0; r < 4; ++r)
        partial[slab + bm + wm + mf * 16 + kk * 4 + r] = part[mf][r];
  }
}

// ---------------- final reduction + softmax over M ----------------

__global__ __launch_bounds__(256) void k_sem(const float* __restrict__ partial,
                                             const float* __restrict__ ab2,
                                             float* __restrict__ semantic,
                                             float* __restrict__ bstats) {
  const int m = blockIdx.x * 256 + threadIdx.x;
  float s = ab2[m];
  #pragma unroll
  for (int nb = 0; nb < 32; ++nb) s += partial[(size_t)nb * 16384 + m];
  semantic[m] = s;
  float mx = s;
  #pragma unroll
  for (int mask = 1; mask < 64; mask <<= 1) mx = fmaxf(mx, __shfl_xor(mx, mask));
  __shared__ float wmax[4], wsum[4];
  const int wave = threadIdx.x >> 6, lane = threadIdx.x & 63;
  if (lane == 0) wmax[wave] = mx;
  __syncthreads();
  const float bmax = fmaxf(fmaxf(wmax[0], wmax[1]), fmaxf(wmax[2], wmax[3]));
  float e = expf(s - bmax);
  #pragma unroll
  for (int mask = 1; mask < 64; mask <<= 1) e += __shfl_xor(e, mask);
  if (lane == 0) wsum[wave] = e;
  __syncthreads();
  if (threadIdx.x == 0) {
    bstats[blockIdx.x * 2] = bmax;
    bstats[blockIdx.x * 2 + 1] = wsum[0] + wsum[1] + wsum[2] + wsum[3];
  }
}

__global__ void k_combine(const float* __restrict__ bstats, float* __restrict__ gstats) {
  const int t = threadIdx.x;
  const float bm = bstats[t * 2], bs = bstats[t * 2 + 1];
  float gm = bm;
  #pragma unroll
  for (int mask = 1; mask < 64; mask <<= 1) gm = fmaxf(gm, __shfl_xor(gm, mask));
  float gs = bs * expf(bm - gm);
  #pragma unroll
  for (int mask = 1; mask < 64; mask <<= 1) gs += __shfl_xor(gs, mask);
  if (t == 0) { gstats[0] = gm; gstats[1] = gs; }
}

__global__ __launch_bounds__(256) void k_out(const float* __restrict__ semantic,
                                             const float* __restrict__ gstats,
                                             float* __restrict__ out) {
  const int m = blockIdx.x * 256 + threadIdx.x;
  out[m] = expf(semantic[m] - gstats[0]) / gstats[1];
}

// ---------------- launch ----------------

extern "C" void kernel_launch(void* const* d_in, const int* in_sizes, int n_in,
                              void* d_out, int out_size, void* d_ws, size_t ws_size,
                              hipStream_t stream) {
  (void)in_sizes; (void)n_in; (void)out_size; (void)ws_size;
  const float* A    = (const float*)d_in[0];  // [16384][2048]
  const float* Q    = (const float*)d_in[1];  // [128][2048]
  const float* hist = (const float*)d_in[2];  // [2048]
  const float* W1   = (const float*)d_in[3];  // [2048][4096]
  const float* b1   = (const float*)d_in[4];  // [2048]
  const float* W2   = (const float*)d_in[5];  // [2048][2048]
  const float* b2   = (const float*)d_in[6];  // [2048]
  float* out = (float*)d_out;                 // [16384]

  char* ws = (char*)d_ws;
  f16* Af      = (f16*)ws;   ws += (size_t)16384 * 2048 * 2;  // 64 MB
  f16* Al      = (f16*)ws;   ws += (size_t)16384 * 2048 * 2;  // 64 MB
  f16* W2t     = (f16*)ws;   ws += (size_t)2048 * 2048 * 2;   // 8 MB
  f16* Qf      = (f16*)ws;   ws += (size_t)128 * 2048 * 2;
  f16* Ql      = (f16*)ws;   ws += (size_t)128 * 2048 * 2;
  f16* QWt     = (f16*)ws;   ws += (size_t)2048 * 128 * 2;
  f16* at      = (f16*)ws;   ws += (size_t)16384 * 128 * 2;   // 4 MB
  float* qw1t  = (float*)ws; ws += (size_t)2048 * 128 * 4;    // 1 MB
  float* c_vec = (float*)ws; ws += 2048 * 4;
  float* ab2   = (float*)ws; ws += 16384 * 4;
  float* partial  = (float*)ws; ws += (size_t)32 * 16384 * 4; // 2 MB
  float* semantic = (float*)ws; ws += 16384 * 4;
  float* bstats   = (float*)ws; ws += 128 * 4;
  float* gstats   = (float*)ws; ws += 2 * 4;

  // prep
  c_kernel<<<512, 256, 0, stream>>>(W1, b1, hist, c_vec);
  // qw1t[j][n] = sum_k W1q[j][k] * Q[n][k]  (fp32)
  gemm_bt<32, 2><<<dim3(64, 2), 256, 0, stream>>>(W1 + 2048, Q, qw1t,
                                                  2048, 4096, 2048, 128);
  to_f16<<<256, 256, 0, stream>>>(qw1t, QWt);
  transpose_f16<<<dim3(32, 32), 256, 0, stream>>>(W2, 2048, 2048, W2t);
  prep_Q<<<32, 256, 0, stream>>>(Q, Qf, Ql);
  prep_A<<<4096, 256, 0, stream>>>(A, b2, Af, Al, ab2);
  // S = A@Q^T + softmax (split-3 fp16 MFMA)
  s_attn<<<128, 256, 0, stream>>>(Af, Al, Qf, Ql, at);
  // fused z/h/G/dot (fp16 single, XCD-swizzled)
  fused_zg_mfma<<<2048, 256, 0, stream>>>(Af, at, QWt, W2t, c_vec, partial);
  // semantic + softmax over M
  k_sem<<<64, 256, 0, stream>>>(partial, ab2, semantic, bstats);
  k_combine<<<1, 64, 0, stream>>>(bstats, gstats);
  k_out<<<64, 256, 0, stream>>>(semantic, gstats, out);
}

// Round 7
// 381.223 us; speedup vs baseline: 2.3145x; 1.0297x over previous
//
#include <hip/hip_runtime.h>
#include <hip/hip_bf16.h>

// PolicyNet, fp16 MFMA, depth-3 pipelined fused kernel:
//   A -> Af + Al (fp16 + residual), ab2[m] = A[m]·b2;  Q -> Qf + Ql
//   c    = b1 + W1[:, :D] @ hist                  (fp32)
//   QWt  = (f16)(W1[:, D:] @ Q^T)   [j][n], direct f16 GEMM output
//   W2   -> transpose -> W2t f16 [j][k]
//   s_attn: S = A@Q^T via split-3 fp16 MFMA, fused row-softmax -> at f16
//   fused: z = at @ QWt (K=128); h = relu(z+c) fp32 regs
//          G = Af @ W2t (K=2048); partial = sum_j h*G
//          K-loop: 4 LDS sets, depth-3 prefetch, vmcnt(12/8/4/0)
//   semantic = sum partial + ab2 -> softmax over M -> out

typedef _Float16 f16;
typedef __attribute__((ext_vector_type(8))) _Float16 half8;
typedef __attribute__((ext_vector_type(4))) _Float16 half4_t;
typedef __attribute__((ext_vector_type(4))) float f32x4;

#define GLL(gp, lp)                                                              \
  __builtin_amdgcn_global_load_lds(                                              \
      (const __attribute__((address_space(1))) void*)(gp),                       \
      (__attribute__((address_space(3))) void*)(lp), 16, 0, 0)

#define WAITN(n)                                                                 \
  do {                                                                           \
    asm volatile("s_waitcnt vmcnt(" #n ")" ::: "memory");                        \
    __builtin_amdgcn_sched_barrier(0);                                           \
  } while (0)

// ---------------- single-product fp16 K-loop, depth-3 ----------------
// BM=BN=128, BK=32, 4 waves (2m x 2n), wave tile 64x64 (4x4 of 16x16x32).
// LDS: 4 sets x {A 8KB, B 8KB} = 64KB. 4 GLL/wave/step; vmcnt(12) steady.
// Swizzle: 16B-chunk c' = c ^ (line&7); source pre-inverse-swizzled.
template <int NT, int LDA, int LDB>
__device__ __forceinline__ void kloop1(const f16* __restrict__ A,
                                       const f16* __restrict__ B,
                                       f16* __restrict__ SM,
                                       f32x4 (&acc)[4][4],
                                       int lane, int wv, int wm, int wn) {
  static_assert(NT >= 4, "depth-3 pipeline needs NT >= 4");
  const int f = lane & 15, kk = lane >> 4;
  const int cS = (lane & 7) ^ (lane >> 3);
  const int kkS = (cS & 3) * 8;
  const int rS = 2 * (lane >> 3) + (cS >> 2);
  const size_t offA0 = (size_t)(16 * (wv * 2 + 0) + rS) * LDA + kkS;
  const size_t offA1 = (size_t)(16 * (wv * 2 + 1) + rS) * LDA + kkS;
  const size_t offB0 = (size_t)(16 * (wv * 2 + 0) + rS) * LDB + kkS;
  const size_t offB1 = (size_t)(16 * (wv * 2 + 1) + rS) * LDB + kkS;
  const int Ld0 = (wv * 2 + 0) * 512, Ld1 = (wv * 2 + 1) * 512;

  int aoff[4], boff[4];
  #pragma unroll
  for (int mf = 0; mf < 4; ++mf) {
    const int R = wm + mf * 16 + f;
    const int c2 = (((R & 1) << 2) | kk) ^ ((R >> 1) & 7);
    aoff[mf] = (R >> 1) * 64 + c2 * 8;
  }
  #pragma unroll
  for (int nf = 0; nf < 4; ++nf) {
    const int R = wn + nf * 16 + f;
    const int c2 = (((R & 1) << 2) | kk) ^ ((R >> 1) & 7);
    boff[nf] = (R >> 1) * 64 + c2 * 8;
  }

  auto STAGE = [&](int set, int kt) {
    f16* base = SM + set * 8192;
    GLL(A + offA0 + kt, base + Ld0);
    GLL(A + offA1 + kt, base + Ld1);
    GLL(B + offB0 + kt, base + 4096 + Ld0);
    GLL(B + offB1 + kt, base + 4096 + Ld1);
  };
  auto COMPUTE = [&](int set) {
    const f16* p = SM + set * 8192;
    half8 a[4], b[4];
    #pragma unroll
    for (int mf = 0; mf < 4; ++mf) a[mf] = *(const half8*)&p[aoff[mf]];
    #pragma unroll
    for (int nf = 0; nf < 4; ++nf) b[nf] = *(const half8*)&p[4096 + boff[nf]];
    #pragma unroll
    for (int mf = 0; mf < 4; ++mf)
      #pragma unroll
      for (int nf = 0; nf < 4; ++nf)
        acc[mf][nf] = __builtin_amdgcn_mfma_f32_16x16x32_f16(a[mf], b[nf], acc[mf][nf], 0, 0, 0);
  };

  STAGE(0, 0);
  STAGE(1, 32);
  STAGE(2, 64);
  #pragma unroll 1
  for (int t = 0; t < NT - 3; ++t) {
    STAGE((t + 3) & 3, (t + 3) * 32);
    WAITN(12);
    __builtin_amdgcn_s_barrier();
    COMPUTE(t & 3);
    __builtin_amdgcn_s_barrier();
  }
  // peeled tail: t = NT-3, NT-2, NT-1
  WAITN(8);
  __builtin_amdgcn_s_barrier();
  COMPUTE((NT - 3) & 3);
  __builtin_amdgcn_s_barrier();
  WAITN(4);
  __builtin_amdgcn_s_barrier();
  COMPUTE((NT - 2) & 3);
  __builtin_amdgcn_s_barrier();
  WAITN(0);
  __builtin_amdgcn_s_barrier();
  COMPUTE((NT - 1) & 3);
  __builtin_amdgcn_s_barrier();
}

// ---------------- split-3 fp16 K-loop (score path, proven R6) ----------------
template <int NT, int LDA, int LDB>
__device__ __forceinline__ void kloop3(const f16* __restrict__ Ah,
                                       const f16* __restrict__ Al,
                                       const f16* __restrict__ Bh,
                                       const f16* __restrict__ Bl,
                                       f16* __restrict__ SM,
                                       f32x4 (&acc)[4][4],
                                       int lane, int wv, int wm, int wn) {
  const int f = lane & 15, kk = lane >> 4;
  const int cS = (lane & 7) ^ (lane >> 3);
  const int kkS = (cS & 3) * 8;
  const int rS = 2 * (lane >> 3) + (cS >> 2);
  const size_t offA0 = (size_t)(16 * (wv * 2 + 0) + rS) * LDA + kkS;
  const size_t offA1 = (size_t)(16 * (wv * 2 + 1) + rS) * LDA + kkS;
  const size_t offB0 = (size_t)(16 * (wv * 2 + 0) + rS) * LDB + kkS;
  const size_t offB1 = (size_t)(16 * (wv * 2 + 1) + rS) * LDB + kkS;
  const int Ld0 = (wv * 2 + 0) * 512, Ld1 = (wv * 2 + 1) * 512;

  int aoff[4], boff[4];
  #pragma unroll
  for (int mf = 0; mf < 4; ++mf) {
    const int R = wm + mf * 16 + f;
    const int c2 = (((R & 1) << 2) | kk) ^ ((R >> 1) & 7);
    aoff[mf] = (R >> 1) * 64 + c2 * 8;
  }
  #pragma unroll
  for (int nf = 0; nf < 4; ++nf) {
    const int R = wn + nf * 16 + f;
    const int c2 = (((R & 1) << 2) | kk) ^ ((R >> 1) & 7);
    boff[nf] = (R >> 1) * 64 + c2 * 8;
  }

  auto STAGE = [&](int set, int kt) {
    f16* base = SM + set * 16384;
    GLL(Ah + offA0 + kt, base + Ld0);
    GLL(Ah + offA1 + kt, base + Ld1);
    GLL(Al + offA0 + kt, base + 4096 + Ld0);
    GLL(Al + offA1 + kt, base + 4096 + Ld1);
    GLL(Bh + offB0 + kt, base + 8192 + Ld0);
    GLL(Bh + offB1 + kt, base + 8192 + Ld1);
    GLL(Bl + offB0 + kt, base + 12288 + Ld0);
    GLL(Bl + offB1 + kt, base + 12288 + Ld1);
  };
  auto COMPUTE = [&](int set) {
    const f16* p = SM + set * 16384;
    half8 ah[4], al[4], bh[4], bl[4];
    #pragma unroll
    for (int mf = 0; mf < 4; ++mf) {
      ah[mf] = *(const half8*)&p[aoff[mf]];
      al[mf] = *(const half8*)&p[4096 + aoff[mf]];
    }
    #pragma unroll
    for (int nf = 0; nf < 4; ++nf) {
      bh[nf] = *(const half8*)&p[8192 + boff[nf]];
      bl[nf] = *(const half8*)&p[12288 + boff[nf]];
    }
    #pragma unroll
    for (int mf = 0; mf < 4; ++mf)
      #pragma unroll
      for (int nf = 0; nf < 4; ++nf) {
        acc[mf][nf] = __builtin_amdgcn_mfma_f32_16x16x32_f16(ah[mf], bh[nf], acc[mf][nf], 0, 0, 0);
        acc[mf][nf] = __builtin_amdgcn_mfma_f32_16x16x32_f16(ah[mf], bl[nf], acc[mf][nf], 0, 0, 0);
        acc[mf][nf] = __builtin_amdgcn_mfma_f32_16x16x32_f16(al[mf], bh[nf], acc[mf][nf], 0, 0, 0);
      }
  };

  STAGE(0, 0);
  #pragma unroll 1
  for (int t = 0; t < NT - 1; ++t) {
    STAGE((t + 1) & 1, (t + 1) * 32);
    WAITN(8);
    __builtin_amdgcn_s_barrier();
    COMPUTE(t & 1);
    __builtin_amdgcn_s_barrier();
  }
  WAITN(0);
  __builtin_amdgcn_s_barrier();
  COMPUTE((NT - 1) & 1);
  __builtin_amdgcn_s_barrier();
}

// ---------------- prep kernels ----------------

__global__ __launch_bounds__(256) void c_kernel(const float* __restrict__ W1,
                                                const float* __restrict__ b1,
                                                const float* __restrict__ hist,
                                                float* __restrict__ c) {
  const int wave = threadIdx.x >> 6, lane = threadIdx.x & 63;
  const int j = blockIdx.x * 4 + wave;
  const float* row = W1 + (size_t)j * 4096;
  float s = 0.f;
  #pragma unroll 2
  for (int kq = lane; kq < 512; kq += 64) {
    const float4 w = *(const float4*)&row[kq * 4];
    const float4 h = *(const float4*)&hist[kq * 4];
    s += w.x * h.x + w.y * h.y + w.z * h.z + w.w * h.w;
  }
  #pragma unroll
  for (int mask = 1; mask < 64; mask <<= 1) s += __shfl_xor(s, mask);
  if (lane == 0) c[j] = s + b1[j];
}

__device__ __forceinline__ half4_t f16hi4(const float4 v) {
  half4_t h;
  h.x = (f16)v.x; h.y = (f16)v.y; h.z = (f16)v.z; h.w = (f16)v.w;
  return h;
}
__device__ __forceinline__ half4_t f16lo4(const float4 v, const half4_t h) {
  half4_t l;
  l.x = (f16)(v.x - (float)h.x);
  l.y = (f16)(v.y - (float)h.y);
  l.z = (f16)(v.z - (float)h.z);
  l.w = (f16)(v.w - (float)h.w);
  return l;
}

// blocks 0..4095: A rows (4/block) + ab2;  blocks 4096..4127: Q rows (4/block)
__global__ __launch_bounds__(256) void prep_AQ(const float* __restrict__ A,
                                               const float* __restrict__ Q,
                                               const float* __restrict__ b2,
                                               f16* __restrict__ Af,
                                               f16* __restrict__ Al,
                                               f16* __restrict__ Qf,
                                               f16* __restrict__ Ql,
                                               float* __restrict__ ab2) {
  const int wv = threadIdx.x >> 6, lane = threadIdx.x & 63;
  if (blockIdx.x < 4096) {
    const size_t row = (size_t)blockIdx.x * 4 + wv;
    const float* ar = A + row * 2048;
    float dot = 0.f;
    #pragma unroll 2
    for (int c0 = 0; c0 < 2048; c0 += 256) {
      const int col = c0 + lane * 4;
      const float4 v = *(const float4*)&ar[col];
      const float4 bb = *(const float4*)&b2[col];
      dot += v.x * bb.x + v.y * bb.y + v.z * bb.z + v.w * bb.w;
      const half4_t h = f16hi4(v);
      const half4_t l = f16lo4(v, h);
      *(half4_t*)&Af[row * 2048 + col] = h;
      *(half4_t*)&Al[row * 2048 + col] = l;
    }
    #pragma unroll
    for (int mask = 1; mask < 64; mask <<= 1) dot += __shfl_xor(dot, mask);
    if (lane == 0) ab2[row] = dot;
  } else {
    const size_t row = (size_t)(blockIdx.x - 4096) * 4 + wv;
    const float* qr = Q + row * 2048;
    #pragma unroll 2
    for (int c0 = 0; c0 < 2048; c0 += 256) {
      const int col = c0 + lane * 4;
      const float4 v = *(const float4*)&qr[col];
      const half4_t h = f16hi4(v);
      const half4_t l = f16lo4(v, h);
      *(half4_t*)&Qf[row * 2048 + col] = h;
      *(half4_t*)&Ql[row * 2048 + col] = l;
    }
  }
}

// dst[c*ldR + r] = (f16)src[r*C + c]
__global__ __launch_bounds__(256) void transpose_f16(const float* __restrict__ src,
                                                     int R, int C,
                                                     f16* __restrict__ dst) {
  __shared__ float T[64][65];
  const int c0 = blockIdx.x * 64, r0 = blockIdx.y * 64;
  const int t = threadIdx.x;
  {
    const int rl = t >> 4, cl = (t & 15) * 4;
    #pragma unroll
    for (int ii = 0; ii < 4; ++ii) {
      const float4 v = *(const float4*)&src[(size_t)(r0 + rl + ii * 16) * C + c0 + cl];
      T[rl + ii * 16][cl + 0] = v.x; T[rl + ii * 16][cl + 1] = v.y;
      T[rl + ii * 16][cl + 2] = v.z; T[rl + ii * 16][cl + 3] = v.w;
    }
  }
  __syncthreads();
  const int cc = t >> 2, rr0 = (t & 3) * 16;
  f16 u[16];
  #pragma unroll
  for (int k = 0; k < 16; ++k) u[k] = (f16)T[rr0 + k][cc];
  f16* ph = dst + (size_t)(c0 + cc) * R + r0 + rr0;
  #pragma unroll
  for (int k4 = 0; k4 < 4; ++k4)
    *(half4_t*)&ph[k4 * 4] = *(half4_t*)&u[k4 * 4];
}

// fp32 tiled GEMM (B^T layout), f16 output: C[m][n] = (f16) sum_k A[..]B[..]
template <int BM, int TM>
__global__ __launch_bounds__(256) void gemm_bt_f16(const float* __restrict__ A,
                                                   const float* __restrict__ B,
                                                   f16* __restrict__ C,
                                                   int K, int lda, int ldb, int ldc) {
  constexpr int BN = 64, BK = 32;
  constexpr int ASTR = BM + 12, BSTR = BN + 4;
  __shared__ float As[BK][ASTR];
  __shared__ float Bs[BK][BSTR];
  const int tid = threadIdx.x;
  const int tx = tid & 15, ty = tid >> 4;
  const int m0 = ty * TM, n0 = tx * 4;
  const size_t bm = (size_t)blockIdx.x * BM, bn = (size_t)blockIdx.y * BN;
  const float* Ab = A + bm * lda;
  const float* Bb = B + bn * ldb;
  float acc[TM][4];
  #pragma unroll
  for (int i = 0; i < TM; ++i)
    #pragma unroll
    for (int j = 0; j < 4; ++j) acc[i][j] = 0.f;
  for (int kt = 0; kt < K; kt += BK) {
    #pragma unroll
    for (int it = 0; it < BM * BK / 4 / 256; ++it) {
      const int idx = it * 256 + tid;
      const int row = idx >> 3, kq = idx & 7;
      const float4 v = *(const float4*)&Ab[(size_t)row * lda + kt + kq * 4];
      As[kq * 4 + 0][row] = v.x; As[kq * 4 + 1][row] = v.y;
      As[kq * 4 + 2][row] = v.z; As[kq * 4 + 3][row] = v.w;
    }
    #pragma unroll
    for (int it = 0; it < BN * BK / 4 / 256; ++it) {
      const int idx = it * 256 + tid;
      const int row = idx >> 3, kq = idx & 7;
      const float4 v = *(const float4*)&Bb[(size_t)row * ldb + kt + kq * 4];
      Bs[kq * 4 + 0][row] = v.x; Bs[kq * 4 + 1][row] = v.y;
      Bs[kq * 4 + 2][row] = v.z; Bs[kq * 4 + 3][row] = v.w;
    }
    __syncthreads();
    #pragma unroll
    for (int k = 0; k < BK; ++k) {
      float av[TM];
      #pragma unroll
      for (int i = 0; i < TM; ++i) av[i] = As[k][m0 + i];
      const float4 b = *(const float4*)&Bs[k][n0];
      const float bv[4] = {b.x, b.y, b.z, b.w};
      #pragma unroll
      for (int i = 0; i < TM; ++i)
        #pragma unroll
        for (int j = 0; j < 4; ++j) acc[i][j] = fmaf(av[i], bv[j], acc[i][j]);
    }
    __syncthreads();
  }
  #pragma unroll
  for (int i = 0; i < TM; ++i) {
    f16* crow = C + (bm + m0 + i) * (size_t)ldc + bn + n0;
    half4_t h;
    h.x = (f16)acc[i][0]; h.y = (f16)acc[i][1];
    h.z = (f16)acc[i][2]; h.w = (f16)acc[i][3];
    *(half4_t*)crow = h;
  }
}

// ---------------- S = A@Q^T (split-3 fp16) + fused row softmax -> at f16 ----
__global__ __launch_bounds__(256, 2) void s_attn(const f16* __restrict__ Af,
                                                 const f16* __restrict__ Al,
                                                 const f16* __restrict__ Qf,
                                                 const f16* __restrict__ Ql,
                                                 f16* __restrict__ at) {
  __shared__ f16 SM[32768];  // 64 KB
  const int tid = threadIdx.x, lane = tid & 63, wv = tid >> 6;
  const int wm = (wv >> 1) * 64, wn = (wv & 1) * 64;
  const int f = lane & 15, kk = lane >> 4;
  const size_t bm = (size_t)blockIdx.x * 128;

  f32x4 acc[4][4];
  #pragma unroll
  for (int mf = 0; mf < 4; ++mf)
    #pragma unroll
    for (int nf = 0; nf < 4; ++nf) acc[mf][nf] = 0.f;

  kloop3<64, 2048, 2048>(Af + bm * 2048, Al + bm * 2048, Qf, Ql,
                         SM, acc, lane, wv, wm, wn);

  float* sred = (float*)SM;        // [128][2] row-max
  float* ssum = sred + 256;        // [128][2] row-sum
  const int rowbase = wm + kk * 4;
  float rmax[4][4];
  #pragma unroll
  for (int mf = 0; mf < 4; ++mf)
    #pragma unroll
    for (int r = 0; r < 4; ++r) {
      float m4 = fmaxf(fmaxf(acc[mf][0][r], acc[mf][1][r]),
                       fmaxf(acc[mf][2][r], acc[mf][3][r]));
      m4 = fmaxf(m4, __shfl_xor(m4, 1));
      m4 = fmaxf(m4, __shfl_xor(m4, 2));
      m4 = fmaxf(m4, __shfl_xor(m4, 4));
      m4 = fmaxf(m4, __shfl_xor(m4, 8));
      rmax[mf][r] = m4;
    }
  if (f == 0) {
    #pragma unroll
    for (int mf = 0; mf < 4; ++mf)
      #pragma unroll
      for (int r = 0; r < 4; ++r)
        sred[(rowbase + mf * 16 + r) * 2 + (wv & 1)] = rmax[mf][r];
  }
  __syncthreads();
  #pragma unroll
  for (int mf = 0; mf < 4; ++mf)
    #pragma unroll
    for (int r = 0; r < 4; ++r) {
      const int row = rowbase + mf * 16 + r;
      rmax[mf][r] = fmaxf(sred[row * 2], sred[row * 2 + 1]);
    }
  float rsum[4][4];
  #pragma unroll
  for (int mf = 0; mf < 4; ++mf)
    #pragma unroll
    for (int r = 0; r < 4; ++r) {
      float s = 0.f;
      #pragma unroll
      for (int nf = 0; nf < 4; ++nf) {
        acc[mf][nf][r] = __expf(acc[mf][nf][r] - rmax[mf][r]);
        s += acc[mf][nf][r];
      }
      s += __shfl_xor(s, 1);
      s += __shfl_xor(s, 2);
      s += __shfl_xor(s, 4);
      s += __shfl_xor(s, 8);
      rsum[mf][r] = s;
    }
  if (f == 0) {
    #pragma unroll
    for (int mf = 0; mf < 4; ++mf)
      #pragma unroll
      for (int r = 0; r < 4; ++r)
        ssum[(rowbase + mf * 16 + r) * 2 + (wv & 1)] = rsum[mf][r];
  }
  __syncthreads();
  #pragma unroll
  for (int mf = 0; mf < 4; ++mf)
    #pragma unroll
    for (int r = 0; r < 4; ++r) {
      const int row = rowbase + mf * 16 + r;
      const float inv = 1.0f / (ssum[row * 2] + ssum[row * 2 + 1]);
      const size_t orow = (bm + row) * 128;
      #pragma unroll
      for (int nf = 0; nf < 4; ++nf)
        at[orow + wn + nf * 16 + f] = (f16)(acc[mf][nf][r] * inv);
    }
}

// ---------------- fused z/h/G/dot ----------------
__global__ __launch_bounds__(256, 2) void fused_zg_mfma(
    const f16* __restrict__ Af, const f16* __restrict__ at,
    const f16* __restrict__ QWt, const f16* __restrict__ W2t,
    const float* __restrict__ cvec, float* __restrict__ partial) {
  __shared__ f16 SM[32768];  // 64 KB: 4 sets x {A 8KB, B 8KB}
  const int tid = threadIdx.x, lane = tid & 63, wv = tid >> 6;
  const int wm = (wv >> 1) * 64, wn = (wv & 1) * 64;
  const int f = lane & 15, kk = lane >> 4;
  // bijective XCD swizzle: nwg=2048, 8 XCDs, 256 per XCD
  const int lin = blockIdx.x;
  const int sid = (lin & 7) * 256 + (lin >> 3);
  const int bmI = sid & 127, bnI = sid >> 7;
  const size_t bm = (size_t)bmI * 128;
  const size_t bn = (size_t)bnI * 128;

  f32x4 acc[4][4];
  #pragma unroll
  for (int mf = 0; mf < 4; ++mf)
    #pragma unroll
    for (int nf = 0; nf < 4; ++nf) acc[mf][nf] = 0.f;

  // phase Z: z = at @ QWt, K = 128
  kloop1<4, 128, 128>(at + bm * 128, QWt + bn * 128, SM, acc, lane, wv, wm, wn);

  // h = relu(z + c), fp32 regs
  float hreg[4][4][4];
  {
    float ccv[4];
    #pragma unroll
    for (int nf = 0; nf < 4; ++nf) ccv[nf] = cvec[bn + wn + nf * 16 + f];
    #pragma unroll
    for (int mf = 0; mf < 4; ++mf)
      #pragma unroll
      for (int nf = 0; nf < 4; ++nf)
        #pragma unroll
        for (int r = 0; r < 4; ++r) {
          hreg[mf][nf][r] = fmaxf(acc[mf][nf][r] + ccv[nf], 0.f);
          acc[mf][nf][r] = 0.f;
        }
  }

  // phase G: G = Af @ W2t, K = 2048
  kloop1<64, 2048, 2048>(Af + bm * 2048, W2t + bn * 2048, SM, acc, lane, wv, wm, wn);

  // epilogue: partial = sum over this block's 128 j of h*G
  float part[4][4];
  #pragma unroll
  for (int mf = 0; mf < 4; ++mf)
    #pragma unroll
    for (int r = 0; r < 4; ++r) {
      float s = 0.f;
      #pragma unroll
      for (int nf = 0; nf < 4; ++nf) s += hreg[mf][nf][r] * acc[mf][nf][r];
      part[mf][r] = s;
    }
  #pragma unroll
  for (int mf = 0; mf < 4; ++mf)
    #pragma unroll
    for (int r = 0; r < 4; ++r) {
      part[mf][r] += __shfl_xor(part[mf][r], 1);
      part[mf][r] += __shfl_xor(part[mf][r], 2);
      part[mf][r] += __shfl_xor(part[mf][r], 4);
      part[mf][r] += __shfl_xor(part[mf][r], 8);
    }
  if (f == 0) {
    const size_t slab = (size_t)(bnI * 2 + (wv & 1)) * 16384;
    #pragma unroll
    for (int mf = 0; mf < 4; ++mf)
      #pragma unroll
      for (int r = 0; r < 4; ++r)
        partial[slab + bm + wm + mf * 16 + kk * 4 + r] = part[mf][r];
  }
}

// ---------------- final reduction + softmax over M ----------------

__global__ __launch_bounds__(256) void k_sem(const float* __restrict__ partial,
                                             const float* __restrict__ ab2,
                                             float* __restrict__ semantic,
                                             float* __restrict__ bstats) {
  const int m = blockIdx.x * 256 + threadIdx.x;
  float s = ab2[m];
  #pragma unroll
  for (int nb = 0; nb < 32; ++nb) s += partial[(size_t)nb * 16384 + m];
  semantic[m] = s;
  float mx = s;
  #pragma unroll
  for (int mask = 1; mask < 64; mask <<= 1) mx = fmaxf(mx, __shfl_xor(mx, mask));
  __shared__ float wmax[4], wsum[4];
  const int wave = threadIdx.x >> 6, lane = threadIdx.x & 63;
  if (lane == 0) wmax[wave] = mx;
  __syncthreads();
  const float bmax = fmaxf(fmaxf(wmax[0], wmax[1]), fmaxf(wmax[2], wmax[3]));
  float e = expf(s - bmax);
  #pragma unroll
  for (int mask = 1; mask < 64; mask <<= 1) e += __shfl_xor(e, mask);
  if (lane == 0) wsum[wave] = e;
  __syncthreads();
  if (threadIdx.x == 0) {
    bstats[blockIdx.x * 2] = bmax;
    bstats[blockIdx.x * 2 + 1] = wsum[0] + wsum[1] + wsum[2] + wsum[3];
  }
}

// global combine (wave 0) + normalize, merged
__global__ __launch_bounds__(256) void k_out(const float* __restrict__ semantic,
                                             const float* __restrict__ bstats,
                                             float* __restrict__ out) {
  __shared__ float g0s, g1s;
  const int tid = threadIdx.x;
  if (tid < 64) {
    const float bm = bstats[tid * 2], bs = bstats[tid * 2 + 1];
    float gm = bm;
    #pragma unroll
    for (int mask = 1; mask < 64; mask <<= 1) gm = fmaxf(gm, __shfl_xor(gm, mask));
    float gs = bs * expf(bm - gm);
    #pragma unroll
    for (int mask = 1; mask < 64; mask <<= 1) gs += __shfl_xor(gs, mask);
    if (tid == 0) { g0s = gm; g1s = gs; }
  }
  __syncthreads();
  const int m = blockIdx.x * 256 + tid;
  out[m] = expf(semantic[m] - g0s) / g1s;
}

// ---------------- launch ----------------

extern "C" void kernel_launch(void* const* d_in, const int* in_sizes, int n_in,
                              void* d_out, int out_size, void* d_ws, size_t ws_size,
                              hipStream_t stream) {
  (void)in_sizes; (void)n_in; (void)out_size; (void)ws_size;
  const float* A    = (const float*)d_in[0];  // [16384][2048]
  const float* Q    = (const float*)d_in[1];  // [128][2048]
  const float* hist = (const float*)d_in[2];  // [2048]
  const float* W1   = (const float*)d_in[3];  // [2048][4096]
  const float* b1   = (const float*)d_in[4];  // [2048]
  const float* W2   = (const float*)d_in[5];  // [2048][2048]
  const float* b2   = (const float*)d_in[6];  // [2048]
  float* out = (float*)d_out;                 // [16384]

  char* ws = (char*)d_ws;
  f16* Af      = (f16*)ws;   ws += (size_t)16384 * 2048 * 2;  // 64 MB
  f16* Al      = (f16*)ws;   ws += (size_t)16384 * 2048 * 2;  // 64 MB
  f16* W2t     = (f16*)ws;   ws += (size_t)2048 * 2048 * 2;   // 8 MB
  f16* Qf      = (f16*)ws;   ws += (size_t)128 * 2048 * 2;
  f16* Ql      = (f16*)ws;   ws += (size_t)128 * 2048 * 2;
  f16* QWt     = (f16*)ws;   ws += (size_t)2048 * 128 * 2;
  f16* at      = (f16*)ws;   ws += (size_t)16384 * 128 * 2;   // 4 MB
  float* c_vec = (float*)ws; ws += 2048 * 4;
  float* ab2   = (float*)ws; ws += 16384 * 4;
  float* partial  = (float*)ws; ws += (size_t)32 * 16384 * 4; // 2 MB
  float* semantic = (float*)ws; ws += 16384 * 4;
  float* bstats   = (float*)ws; ws += 128 * 4;

  // prep
  c_kernel<<<512, 256, 0, stream>>>(W1, b1, hist, c_vec);
  // QWt[j][n] = (f16) sum_k W1q[j][k] * Q[n][k]
  gemm_bt_f16<32, 2><<<dim3(64, 2), 256, 0, stream>>>(W1 + 2048, Q, QWt,
                                                      2048, 4096, 2048, 128);
  transpose_f16<<<dim3(32, 32), 256, 0, stream>>>(W2, 2048, 2048, W2t);
  prep_AQ<<<4128, 256, 0, stream>>>(A, Q, b2, Af, Al, Qf, Ql, ab2);
  // S = A@Q^T + softmax (split-3 fp16 MFMA)
  s_attn<<<128, 256, 0, stream>>>(Af, Al, Qf, Ql, at);
  // fused z/h/G/dot (fp16 single, depth-3 pipeline, XCD-swizzled)
  fused_zg_mfma<<<2048, 256, 0, stream>>>(Af, at, QWt, W2t, c_vec, partial);
  // semantic + softmax over M
  k_sem<<<64, 256, 0, stream>>>(partial, ab2, semantic, bstats);
  k_out<<<64, 256, 0, stream>>>(semantic, bstats, out);
}

// Round 8
// 380.192 us; speedup vs baseline: 2.3207x; 1.0027x over previous
//
#include <hip/hip_runtime.h>
#include <hip/hip_bf16.h>

// PolicyNet, fp16 MFMA, 256x256 fused tile (8 waves, 96KB dynamic LDS, depth-2):
//   A -> Af + Al (fp16 + residual), ab2[m] = A[m]·b2;  Q -> Qf + Ql
//   c    = b1 + W1[:, :D] @ hist                  (fp32)
//   QWt  = (f16)(W1[:, D:] @ Q^T)   [j][n]
//   W2   -> transpose -> W2t f16 [j][k]
//   s_attn: S = A@Q^T via split-3 fp16 MFMA, fused row-softmax -> at f16
//   fused (BM=BN=256): z = at @ QWt (K=128); h = relu(z+c) packed f16 regs
//          G = Af @ W2t (K=2048); partial = sum_j h*G
//   semantic = sum partial + ab2 -> softmax over M -> out

typedef _Float16 f16;
typedef __attribute__((ext_vector_type(8))) _Float16 half8;
typedef __attribute__((ext_vector_type(4))) _Float16 half4_t;
typedef __attribute__((ext_vector_type(4))) float f32x4;

#define GLL(gp, lp)                                                              \
  __builtin_amdgcn_global_load_lds(                                              \
      (const __attribute__((address_space(1))) void*)(gp),                       \
      (__attribute__((address_space(3))) void*)(lp), 16, 0, 0)

#define WAITN(n)                                                                 \
  do {                                                                           \
    asm volatile("s_waitcnt vmcnt(" #n ")" ::: "memory");                        \
    __builtin_amdgcn_sched_barrier(0);                                           \
  } while (0)

// ---------------- 256x256 single-product fp16 K-loop, 8 waves, depth-2 -------
// BK=32. LDS: 3 sets x {A 16KB, B 16KB} = 96KB dynamic. 4 GLL/thread/STAGE.
// Tile = 256 rows x 32 halves; 128B line = 2 rows; swizzle chunk c' = c^(line&7),
// source pre-inverse-swizzled (both-sides involution).
// Wave grid 2m x 4n; wave tile 128m x 64n -> acc[8][4] frags of 16x16x32.
template <int NT, int LDA, int LDB>
__device__ __forceinline__ void kloop256(const f16* __restrict__ A,
                                         const f16* __restrict__ B,
                                         f16* __restrict__ SM,
                                         f32x4 (&acc)[8][4],
                                         int lane, int wv, int wm, int wn) {
  static_assert(NT >= 4, "pipeline needs NT >= 4");
  const int f = lane & 15, kk = lane >> 4;
  const int cS = (lane & 7) ^ (lane >> 3);
  const int kkS = (cS & 3) * 8;
  const int rS = 2 * (lane >> 3) + (cS >> 2);
  const size_t offA0 = (size_t)(16 * (wv * 2 + 0) + rS) * LDA + kkS;
  const size_t offA1 = (size_t)(16 * (wv * 2 + 1) + rS) * LDA + kkS;
  const size_t offB0 = (size_t)(16 * (wv * 2 + 0) + rS) * LDB + kkS;
  const size_t offB1 = (size_t)(16 * (wv * 2 + 1) + rS) * LDB + kkS;
  const int Ld0 = (wv * 2 + 0) * 512, Ld1 = (wv * 2 + 1) * 512;

  int aoff[8], boff[4];
  #pragma unroll
  for (int mf = 0; mf < 8; ++mf) {
    const int R = wm + mf * 16 + f;
    const int c2 = (((R & 1) << 2) | kk) ^ ((R >> 1) & 7);
    aoff[mf] = (R >> 1) * 64 + c2 * 8;
  }
  #pragma unroll
  for (int nf = 0; nf < 4; ++nf) {
    const int R = wn + nf * 16 + f;
    const int c2 = (((R & 1) << 2) | kk) ^ ((R >> 1) & 7);
    boff[nf] = (R >> 1) * 64 + c2 * 8;
  }

  auto STAGE = [&](int set, int kt) {
    f16* base = SM + set * 16384;
    GLL(A + offA0 + kt, base + Ld0);
    GLL(A + offA1 + kt, base + Ld1);
    GLL(B + offB0 + kt, base + 8192 + Ld0);
    GLL(B + offB1 + kt, base + 8192 + Ld1);
  };
  auto COMPUTE = [&](int set) {
    const f16* p = SM + set * 16384;
    half8 a[8], b[4];
    #pragma unroll
    for (int mf = 0; mf < 8; ++mf) a[mf] = *(const half8*)&p[aoff[mf]];
    #pragma unroll
    for (int nf = 0; nf < 4; ++nf) b[nf] = *(const half8*)&p[8192 + boff[nf]];
    #pragma unroll
    for (int mf = 0; mf < 8; ++mf)
      #pragma unroll
      for (int nf = 0; nf < 4; ++nf)
        acc[mf][nf] = __builtin_amdgcn_mfma_f32_16x16x32_f16(a[mf], b[nf], acc[mf][nf], 0, 0, 0);
  };

  STAGE(0, 0);
  STAGE(1, 32);
  int cs = 0;
  #pragma unroll 1
  for (int t = 0; t < NT - 2; ++t) {
    int ss = cs + 2; if (ss >= 3) ss -= 3;
    STAGE(ss, (t + 2) * 32);
    WAITN(8);
    __builtin_amdgcn_s_barrier();
    COMPUTE(cs);
    __builtin_amdgcn_s_barrier();
    ++cs; if (cs == 3) cs = 0;
  }
  WAITN(4);
  __builtin_amdgcn_s_barrier();
  COMPUTE(cs);
  __builtin_amdgcn_s_barrier();
  ++cs; if (cs == 3) cs = 0;
  WAITN(0);
  __builtin_amdgcn_s_barrier();
  COMPUTE(cs);
  __builtin_amdgcn_s_barrier();
}

// ---------------- split-3 fp16 K-loop (score path, 4 waves, proven) ---------
template <int NT, int LDA, int LDB>
__device__ __forceinline__ void kloop3(const f16* __restrict__ Ah,
                                       const f16* __restrict__ Al,
                                       const f16* __restrict__ Bh,
                                       const f16* __restrict__ Bl,
                                       f16* __restrict__ SM,
                                       f32x4 (&acc)[4][4],
                                       int lane, int wv, int wm, int wn) {
  const int f = lane & 15, kk = lane >> 4;
  const int cS = (lane & 7) ^ (lane >> 3);
  const int kkS = (cS & 3) * 8;
  const int rS = 2 * (lane >> 3) + (cS >> 2);
  const size_t offA0 = (size_t)(16 * (wv * 2 + 0) + rS) * LDA + kkS;
  const size_t offA1 = (size_t)(16 * (wv * 2 + 1) + rS) * LDA + kkS;
  const size_t offB0 = (size_t)(16 * (wv * 2 + 0) + rS) * LDB + kkS;
  const size_t offB1 = (size_t)(16 * (wv * 2 + 1) + rS) * LDB + kkS;
  const int Ld0 = (wv * 2 + 0) * 512, Ld1 = (wv * 2 + 1) * 512;

  int aoff[4], boff[4];
  #pragma unroll
  for (int mf = 0; mf < 4; ++mf) {
    const int R = wm + mf * 16 + f;
    const int c2 = (((R & 1) << 2) | kk) ^ ((R >> 1) & 7);
    aoff[mf] = (R >> 1) * 64 + c2 * 8;
  }
  #pragma unroll
  for (int nf = 0; nf < 4; ++nf) {
    const int R = wn + nf * 16 + f;
    const int c2 = (((R & 1) << 2) | kk) ^ ((R >> 1) & 7);
    boff[nf] = (R >> 1) * 64 + c2 * 8;
  }

  auto STAGE = [&](int set, int kt) {
    f16* base = SM + set * 16384;
    GLL(Ah + offA0 + kt, base + Ld0);
    GLL(Ah + offA1 + kt, base + Ld1);
    GLL(Al + offA0 + kt, base + 4096 + Ld0);
    GLL(Al + offA1 + kt, base + 4096 + Ld1);
    GLL(Bh + offB0 + kt, base + 8192 + Ld0);
    GLL(Bh + offB1 + kt, base + 8192 + Ld1);
    GLL(Bl + offB0 + kt, base + 12288 + Ld0);
    GLL(Bl + offB1 + kt, base + 12288 + Ld1);
  };
  auto COMPUTE = [&](int set) {
    const f16* p = SM + set * 16384;
    half8 ah[4], al[4], bh[4], bl[4];
    #pragma unroll
    for (int mf = 0; mf < 4; ++mf) {
      ah[mf] = *(const half8*)&p[aoff[mf]];
      al[mf] = *(const half8*)&p[4096 + aoff[mf]];
    }
    #pragma unroll
    for (int nf = 0; nf < 4; ++nf) {
      bh[nf] = *(const half8*)&p[8192 + boff[nf]];
      bl[nf] = *(const half8*)&p[12288 + boff[nf]];
    }
    #pragma unroll
    for (int mf = 0; mf < 4; ++mf)
      #pragma unroll
      for (int nf = 0; nf < 4; ++nf) {
        acc[mf][nf] = __builtin_amdgcn_mfma_f32_16x16x32_f16(ah[mf], bh[nf], acc[mf][nf], 0, 0, 0);
        acc[mf][nf] = __builtin_amdgcn_mfma_f32_16x16x32_f16(ah[mf], bl[nf], acc[mf][nf], 0, 0, 0);
        acc[mf][nf] = __builtin_amdgcn_mfma_f32_16x16x32_f16(al[mf], bh[nf], acc[mf][nf], 0, 0, 0);
      }
  };

  STAGE(0, 0);
  #pragma unroll 1
  for (int t = 0; t < NT - 1; ++t) {
    STAGE((t + 1) & 1, (t + 1) * 32);
    WAITN(8);
    __builtin_amdgcn_s_barrier();
    COMPUTE(t & 1);
    __builtin_amdgcn_s_barrier();
  }
  WAITN(0);
  __builtin_amdgcn_s_barrier();
  COMPUTE((NT - 1) & 1);
  __builtin_amdgcn_s_barrier();
}

// ---------------- prep kernels ----------------

__global__ __launch_bounds__(256) void c_kernel(const float* __restrict__ W1,
                                                const float* __restrict__ b1,
                                                const float* __restrict__ hist,
                                                float* __restrict__ c) {
  const int wave = threadIdx.x >> 6, lane = threadIdx.x & 63;
  const int j = blockIdx.x * 4 + wave;
  const float* row = W1 + (size_t)j * 4096;
  float s = 0.f;
  #pragma unroll 2
  for (int kq = lane; kq < 512; kq += 64) {
    const float4 w = *(const float4*)&row[kq * 4];
    const float4 h = *(const float4*)&hist[kq * 4];
    s += w.x * h.x + w.y * h.y + w.z * h.z + w.w * h.w;
  }
  #pragma unroll
  for (int mask = 1; mask < 64; mask <<= 1) s += __shfl_xor(s, mask);
  if (lane == 0) c[j] = s + b1[j];
}

__device__ __forceinline__ half4_t f16hi4(const float4 v) {
  half4_t h;
  h.x = (f16)v.x; h.y = (f16)v.y; h.z = (f16)v.z; h.w = (f16)v.w;
  return h;
}
__device__ __forceinline__ half4_t f16lo4(const float4 v, const half4_t h) {
  half4_t l;
  l.x = (f16)(v.x - (float)h.x);
  l.y = (f16)(v.y - (float)h.y);
  l.z = (f16)(v.z - (float)h.z);
  l.w = (f16)(v.w - (float)h.w);
  return l;
}

// blocks 0..4095: A rows (4/block) + ab2;  blocks 4096..4127: Q rows (4/block)
__global__ __launch_bounds__(256) void prep_AQ(const float* __restrict__ A,
                                               const float* __restrict__ Q,
                                               const float* __restrict__ b2,
                                               f16* __restrict__ Af,
                                               f16* __restrict__ Al,
                                               f16* __restrict__ Qf,
                                               f16* __restrict__ Ql,
                                               float* __restrict__ ab2) {
  const int wv = threadIdx.x >> 6, lane = threadIdx.x & 63;
  if (blockIdx.x < 4096) {
    const size_t row = (size_t)blockIdx.x * 4 + wv;
    const float* ar = A + row * 2048;
    float dot = 0.f;
    #pragma unroll 2
    for (int c0 = 0; c0 < 2048; c0 += 256) {
      const int col = c0 + lane * 4;
      const float4 v = *(const float4*)&ar[col];
      const float4 bb = *(const float4*)&b2[col];
      dot += v.x * bb.x + v.y * bb.y + v.z * bb.z + v.w * bb.w;
      const half4_t h = f16hi4(v);
      const half4_t l = f16lo4(v, h);
      *(half4_t*)&Af[row * 2048 + col] = h;
      *(half4_t*)&Al[row * 2048 + col] = l;
    }
    #pragma unroll
    for (int mask = 1; mask < 64; mask <<= 1) dot += __shfl_xor(dot, mask);
    if (lane == 0) ab2[row] = dot;
  } else {
    const size_t row = (size_t)(blockIdx.x - 4096) * 4 + wv;
    const float* qr = Q + row * 2048;
    #pragma unroll 2
    for (int c0 = 0; c0 < 2048; c0 += 256) {
      const int col = c0 + lane * 4;
      const float4 v = *(const float4*)&qr[col];
      const half4_t h = f16hi4(v);
      const half4_t l = f16lo4(v, h);
      *(half4_t*)&Qf[row * 2048 + col] = h;
      *(half4_t*)&Ql[row * 2048 + col] = l;
    }
  }
}

// dst[c*ldR + r] = (f16)src[r*C + c]
__global__ __launch_bounds__(256) void transpose_f16(const float* __restrict__ src,
                                                     int R, int C,
                                                     f16* __restrict__ dst) {
  __shared__ float T[64][65];
  const int c0 = blockIdx.x * 64, r0 = blockIdx.y * 64;
  const int t = threadIdx.x;
  {
    const int rl = t >> 4, cl = (t & 15) * 4;
    #pragma unroll
    for (int ii = 0; ii < 4; ++ii) {
      const float4 v = *(const float4*)&src[(size_t)(r0 + rl + ii * 16) * C + c0 + cl];
      T[rl + ii * 16][cl + 0] = v.x; T[rl + ii * 16][cl + 1] = v.y;
      T[rl + ii * 16][cl + 2] = v.z; T[rl + ii * 16][cl + 3] = v.w;
    }
  }
  __syncthreads();
  const int cc = t >> 2, rr0 = (t & 3) * 16;
  f16 u[16];
  #pragma unroll
  for (int k = 0; k < 16; ++k) u[k] = (f16)T[rr0 + k][cc];
  f16* ph = dst + (size_t)(c0 + cc) * R + r0 + rr0;
  #pragma unroll
  for (int k4 = 0; k4 < 4; ++k4)
    *(half4_t*)&ph[k4 * 4] = *(half4_t*)&u[k4 * 4];
}

// fp32 tiled GEMM (B^T layout), f16 output
template <int BM, int TM>
__global__ __launch_bounds__(256) void gemm_bt_f16(const float* __restrict__ A,
                                                   const float* __restrict__ B,
                                                   f16* __restrict__ C,
                                                   int K, int lda, int ldb, int ldc) {
  constexpr int BN = 64, BK = 32;
  constexpr int ASTR = BM + 12, BSTR = BN + 4;
  __shared__ float As[BK][ASTR];
  __shared__ float Bs[BK][BSTR];
  const int tid = threadIdx.x;
  const int tx = tid & 15, ty = tid >> 4;
  const int m0 = ty * TM, n0 = tx * 4;
  const size_t bm = (size_t)blockIdx.x * BM, bn = (size_t)blockIdx.y * BN;
  const float* Ab = A + bm * lda;
  const float* Bb = B + bn * ldb;
  float acc[TM][4];
  #pragma unroll
  for (int i = 0; i < TM; ++i)
    #pragma unroll
    for (int j = 0; j < 4; ++j) acc[i][j] = 0.f;
  for (int kt = 0; kt < K; kt += BK) {
    #pragma unroll
    for (int it = 0; it < BM * BK / 4 / 256; ++it) {
      const int idx = it * 256 + tid;
      const int row = idx >> 3, kq = idx & 7;
      const float4 v = *(const float4*)&Ab[(size_t)row * lda + kt + kq * 4];
      As[kq * 4 + 0][row] = v.x; As[kq * 4 + 1][row] = v.y;
      As[kq * 4 + 2][row] = v.z; As[kq * 4 + 3][row] = v.w;
    }
    #pragma unroll
    for (int it = 0; it < BN * BK / 4 / 256; ++it) {
      const int idx = it * 256 + tid;
      const int row = idx >> 3, kq = idx & 7;
      const float4 v = *(const float4*)&Bb[(size_t)row * ldb + kt + kq * 4];
      Bs[kq * 4 + 0][row] = v.x; Bs[kq * 4 + 1][row] = v.y;
      Bs[kq * 4 + 2][row] = v.z; Bs[kq * 4 + 3][row] = v.w;
    }
    __syncthreads();
    #pragma unroll
    for (int k = 0; k < BK; ++k) {
      float av[TM];
      #pragma unroll
      for (int i = 0; i < TM; ++i) av[i] = As[k][m0 + i];
      const float4 b = *(const float4*)&Bs[k][n0];
      const float bv[4] = {b.x, b.y, b.z, b.w};
      #pragma unroll
      for (int i = 0; i < TM; ++i)
        #pragma unroll
        for (int j = 0; j < 4; ++j) acc[i][j] = fmaf(av[i], bv[j], acc[i][j]);
    }
    __syncthreads();
  }
  #pragma unroll
  for (int i = 0; i < TM; ++i) {
    f16* crow = C + (bm + m0 + i) * (size_t)ldc + bn + n0;
    half4_t h;
    h.x = (f16)acc[i][0]; h.y = (f16)acc[i][1];
    h.z = (f16)acc[i][2]; h.w = (f16)acc[i][3];
    *(half4_t*)crow = h;
  }
}

// ---------------- S = A@Q^T (split-3 fp16) + fused row softmax -> at f16 ----
__global__ __launch_bounds__(256, 2) void s_attn(const f16* __restrict__ Af,
                                                 const f16* __restrict__ Al,
                                                 const f16* __restrict__ Qf,
                                                 const f16* __restrict__ Ql,
                                                 f16* __restrict__ at) {
  __shared__ f16 SM[32768];  // 64 KB
  const int tid = threadIdx.x, lane = tid & 63, wv = tid >> 6;
  const int wm = (wv >> 1) * 64, wn = (wv & 1) * 64;
  const int f = lane & 15, kk = lane >> 4;
  const size_t bm = (size_t)blockIdx.x * 128;

  f32x4 acc[4][4];
  #pragma unroll
  for (int mf = 0; mf < 4; ++mf)
    #pragma unroll
    for (int nf = 0; nf < 4; ++nf) acc[mf][nf] = 0.f;

  kloop3<64, 2048, 2048>(Af + bm * 2048, Al + bm * 2048, Qf, Ql,
                         SM, acc, lane, wv, wm, wn);

  float* sred = (float*)SM;        // [128][2] row-max
  float* ssum = sred + 256;        // [128][2] row-sum
  const int rowbase = wm + kk * 4;
  float rmax[4][4];
  #pragma unroll
  for (int mf = 0; mf < 4; ++mf)
    #pragma unroll
    for (int r = 0; r < 4; ++r) {
      float m4 = fmaxf(fmaxf(acc[mf][0][r], acc[mf][1][r]),
                       fmaxf(acc[mf][2][r], acc[mf][3][r]));
      m4 = fmaxf(m4, __shfl_xor(m4, 1));
      m4 = fmaxf(m4, __shfl_xor(m4, 2));
      m4 = fmaxf(m4, __shfl_xor(m4, 4));
      m4 = fmaxf(m4, __shfl_xor(m4, 8));
      rmax[mf][r] = m4;
    }
  if (f == 0) {
    #pragma unroll
    for (int mf = 0; mf < 4; ++mf)
      #pragma unroll
      for (int r = 0; r < 4; ++r)
        sred[(rowbase + mf * 16 + r) * 2 + (wv & 1)] = rmax[mf][r];
  }
  __syncthreads();
  #pragma unroll
  for (int mf = 0; mf < 4; ++mf)
    #pragma unroll
    for (int r = 0; r < 4; ++r) {
      const int row = rowbase + mf * 16 + r;
      rmax[mf][r] = fmaxf(sred[row * 2], sred[row * 2 + 1]);
    }
  float rsum[4][4];
  #pragma unroll
  for (int mf = 0; mf < 4; ++mf)
    #pragma unroll
    for (int r = 0; r < 4; ++r) {
      float s = 0.f;
      #pragma unroll
      for (int nf = 0; nf < 4; ++nf) {
        acc[mf][nf][r] = __expf(acc[mf][nf][r] - rmax[mf][r]);
        s += acc[mf][nf][r];
      }
      s += __shfl_xor(s, 1);
      s += __shfl_xor(s, 2);
      s += __shfl_xor(s, 4);
      s += __shfl_xor(s, 8);
      rsum[mf][r] = s;
    }
  if (f == 0) {
    #pragma unroll
    for (int mf = 0; mf < 4; ++mf)
      #pragma unroll
      for (int r = 0; r < 4; ++r)
        ssum[(rowbase + mf * 16 + r) * 2 + (wv & 1)] = rsum[mf][r];
  }
  __syncthreads();
  #pragma unroll
  for (int mf = 0; mf < 4; ++mf)
    #pragma unroll
    for (int r = 0; r < 4; ++r) {
      const int row = rowbase + mf * 16 + r;
      const float inv = 1.0f / (ssum[row * 2] + ssum[row * 2 + 1]);
      const size_t orow = (bm + row) * 128;
      #pragma unroll
      for (int nf = 0; nf < 4; ++nf)
        at[orow + wn + nf * 16 + f] = (f16)(acc[mf][nf][r] * inv);
    }
}

// ---------------- fused z/h/G/dot, 256x256 tile ----------------
__global__ __launch_bounds__(512, 2) void fused_zg_mfma(
    const f16* __restrict__ Af, const f16* __restrict__ at,
    const f16* __restrict__ QWt, const f16* __restrict__ W2t,
    const float* __restrict__ cvec, float* __restrict__ partial) {
  extern __shared__ f16 SM[];  // 96 KB: 3 sets x {A 16KB, B 16KB}
  const int tid = threadIdx.x, lane = tid & 63, wv = tid >> 6;   // wv 0..7
  const int wm = (wv >> 2) * 128, wn = (wv & 3) * 64;
  const int f = lane & 15, kk = lane >> 4;
  // bijective XCD swizzle: nwg=512, 8 XCDs, 64 per XCD
  const int lin = blockIdx.x;
  const int sid = (lin & 7) * 64 + (lin >> 3);
  const int bmI = sid & 63, bnI = sid >> 6;       // 64 m-blocks x 8 n-blocks
  const size_t bm = (size_t)bmI * 256;
  const size_t bn = (size_t)bnI * 256;

  f32x4 acc[8][4];
  #pragma unroll
  for (int mf = 0; mf < 8; ++mf)
    #pragma unroll
    for (int nf = 0; nf < 4; ++nf) acc[mf][nf] = 0.f;

  // phase Z: z = at @ QWt, K = 128
  kloop256<4, 128, 128>(at + bm * 128, QWt + bn * 128, SM, acc, lane, wv, wm, wn);

  // h = relu(z + c), packed f16 (32 VGPR)
  half4_t hreg[8][4];
  {
    float ccv[4];
    #pragma unroll
    for (int nf = 0; nf < 4; ++nf) ccv[nf] = cvec[bn + wn + nf * 16 + f];
    #pragma unroll
    for (int mf = 0; mf < 8; ++mf)
      #pragma unroll
      for (int nf = 0; nf < 4; ++nf) {
        half4_t hv;
        hv.x = (f16)fmaxf(acc[mf][nf][0] + ccv[nf], 0.f);
        hv.y = (f16)fmaxf(acc[mf][nf][1] + ccv[nf], 0.f);
        hv.z = (f16)fmaxf(acc[mf][nf][2] + ccv[nf], 0.f);
        hv.w = (f16)fmaxf(acc[mf][nf][3] + ccv[nf], 0.f);
        hreg[mf][nf] = hv;
        acc[mf][nf] = 0.f;
      }
  }

  // phase G: G = Af @ W2t, K = 2048
  kloop256<64, 2048, 2048>(Af + bm * 2048, W2t + bn * 2048, SM, acc, lane, wv, wm, wn);

  // epilogue: partial = sum over this block's 256 j of h*G
  float part[8][4];
  #pragma unroll
  for (int mf = 0; mf < 8; ++mf)
    #pragma unroll
    for (int r = 0; r < 4; ++r) {
      float s = 0.f;
      #pragma unroll
      for (int nf = 0; nf < 4; ++nf)
        s += (float)hreg[mf][nf][r] * acc[mf][nf][r];
      part[mf][r] = s;
    }
  #pragma unroll
  for (int mf = 0; mf < 8; ++mf)
    #pragma unroll
    for (int r = 0; r < 4; ++r) {
      part[mf][r] += __shfl_xor(part[mf][r], 1);
      part[mf][r] += __shfl_xor(part[mf][r], 2);
      part[mf][r] += __shfl_xor(part[mf][r], 4);
      part[mf][r] += __shfl_xor(part[mf][r], 8);
    }
  if (f == 0) {
    const size_t slab = (size_t)(bnI * 4 + (wv & 3)) * 16384;
    #pragma unroll
    for (int mf = 0; mf < 8; ++mf)
      #pragma unroll
      for (int r = 0; r < 4; ++r)
        partial[slab + bm + wm + mf * 16 + kk * 4 + r] = part[mf][r];
  }
}

// ---------------- final reduction + softmax over M ----------------

__global__ __launch_bounds__(256) void k_sem(const float* __restrict__ partial,
                                             const float* __restrict__ ab2,
                                             float* __restrict__ semantic,
                                             float* __restrict__ bstats) {
  const int m = blockIdx.x * 256 + threadIdx.x;
  float s = ab2[m];
  #pragma unroll
  for (int nb = 0; nb < 32; ++nb) s += partial[(size_t)nb * 16384 + m];
  semantic[m] = s;
  float mx = s;
  #pragma unroll
  for (int mask = 1; mask < 64; mask <<= 1) mx = fmaxf(mx, __shfl_xor(mx, mask));
  __shared__ float wmax[4], wsum[4];
  const int wave = threadIdx.x >> 6, lane = threadIdx.x & 63;
  if (lane == 0) wmax[wave] = mx;
  __syncthreads();
  const float bmax = fmaxf(fmaxf(wmax[0], wmax[1]), fmaxf(wmax[2], wmax[3]));
  float e = expf(s - bmax);
  #pragma unroll
  for (int mask = 1; mask < 64; mask <<= 1) e += __shfl_xor(e, mask);
  if (lane == 0) wsum[wave] = e;
  __syncthreads();
  if (threadIdx.x == 0) {
    bstats[blockIdx.x * 2] = bmax;
    bstats[blockIdx.x * 2 + 1] = wsum[0] + wsum[1] + wsum[2] + wsum[3];
  }
}

__global__ __launch_bounds__(256) void k_out(const float* __restrict__ semantic,
                                             const float* __restrict__ bstats,
                                             float* __restrict__ out) {
  __shared__ float g0s, g1s;
  const int tid = threadIdx.x;
  if (tid < 64) {
    const float bm = bstats[tid * 2], bs = bstats[tid * 2 + 1];
    float gm = bm;
    #pragma unroll
    for (int mask = 1; mask < 64; mask <<= 1) gm = fmaxf(gm, __shfl_xor(gm, mask));
    float gs = bs * expf(bm - gm);
    #pragma unroll
    for (int mask = 1; mask < 64; mask <<= 1) gs += __shfl_xor(gs, mask);
    if (tid == 0) { g0s = gm; g1s = gs; }
  }
  __syncthreads();
  const int m = blockIdx.x * 256 + tid;
  out[m] = expf(semantic[m] - g0s) / g1s;
}

// ---------------- launch ----------------

extern "C" void kernel_launch(void* const* d_in, const int* in_sizes, int n_in,
                              void* d_out, int out_size, void* d_ws, size_t ws_size,
                              hipStream_t stream) {
  (void)in_sizes; (void)n_in; (void)out_size; (void)ws_size;
  const float* A    = (const float*)d_in[0];  // [16384][2048]
  const float* Q    = (const float*)d_in[1];  // [128][2048]
  const float* hist = (const float*)d_in[2];  // [2048]
  const float* W1   = (const float*)d_in[3];  // [2048][4096]
  const float* b1   = (const float*)d_in[4];  // [2048]
  const float* W2   = (const float*)d_in[5];  // [2048][2048]
  const float* b2   = (const float*)d_in[6];  // [2048]
  float* out = (float*)d_out;                 // [16384]

  char* ws = (char*)d_ws;
  f16* Af      = (f16*)ws;   ws += (size_t)16384 * 2048 * 2;  // 64 MB
  f16* Al      = (f16*)ws;   ws += (size_t)16384 * 2048 * 2;  // 64 MB
  f16* W2t     = (f16*)ws;   ws += (size_t)2048 * 2048 * 2;   // 8 MB
  f16* Qf      = (f16*)ws;   ws += (size_t)128 * 2048 * 2;
  f16* Ql      = (f16*)ws;   ws += (size_t)128 * 2048 * 2;
  f16* QWt     = (f16*)ws;   ws += (size_t)2048 * 128 * 2;
  f16* at      = (f16*)ws;   ws += (size_t)16384 * 128 * 2;   // 4 MB
  float* c_vec = (float*)ws; ws += 2048 * 4;
  float* ab2   = (float*)ws; ws += 16384 * 4;
  float* partial  = (float*)ws; ws += (size_t)32 * 16384 * 4; // 2 MB
  float* semantic = (float*)ws; ws += 16384 * 4;
  float* bstats   = (float*)ws; ws += 128 * 4;

  static bool attr_set = false;
  if (!attr_set) {
    hipFuncSetAttribute((const void*)fused_zg_mfma,
                        hipFuncAttributeMaxDynamicSharedMemorySize, 98304);
    attr_set = true;
  }

  // prep
  c_kernel<<<512, 256, 0, stream>>>(W1, b1, hist, c_vec);
  gemm_bt_f16<32, 2><<<dim3(64, 2), 256, 0, stream>>>(W1 + 2048, Q, QWt,
                                                      2048, 4096, 2048, 128);
  transpose_f16<<<dim3(32, 32), 256, 0, stream>>>(W2, 2048, 2048, W2t);
  prep_AQ<<<4128, 256, 0, stream>>>(A, Q, b2, Af, Al, Qf, Ql, ab2);
  // S = A@Q^T + softmax (split-3 fp16 MFMA)
  s_attn<<<128, 256, 0, stream>>>(Af, Al, Qf, Ql, at);
  // fused z/h/G/dot (256x256 tile, 96KB dynamic LDS, XCD-swizzled)
  fused_zg_mfma<<<512, 512, 98304, stream>>>(Af, at, QWt, W2t, c_vec, partial);
  // semantic + softmax over M
  k_sem<<<64, 256, 0, stream>>>(partial, ab2, semantic, bstats);
  k_out<<<64, 256, 0, stream>>>(semantic, bstats, out);
}

// Round 9
// 354.099 us; speedup vs baseline: 2.4917x; 1.0737x over previous
//
#include <hip/hip_runtime.h>
#include <hip/hip_bf16.h>

// PolicyNet, fp16 MFMA:
//   A -> Af fp16, ab2[m] = A[m]·b2;  Q -> Qf fp16
//   c    = b1 + W1[:, :D] @ hist                  (fp32)
//   QWt  = (f16)(W1[:, D:] @ Q^T)   [j][n]
//   W2   -> transpose -> W2t f16 [j][k]
//   s_attn: S = Af@Qf^T (fp16 single MFMA), fused row-softmax -> at f16
//   fused (256x256, 8 waves, 96KB LDS, no spill): z = at @ QWt (K=128);
//          h = relu(z+c) packed f16; G = Af @ W2t (K=2048); partial = sum_j h*G
//   semantic = sum partial + ab2 -> softmax over M -> out

typedef _Float16 f16;
typedef __attribute__((ext_vector_type(8))) _Float16 half8;
typedef __attribute__((ext_vector_type(4))) _Float16 half4_t;
typedef __attribute__((ext_vector_type(4))) float f32x4;

#define GLL(gp, lp)                                                              \
  __builtin_amdgcn_global_load_lds(                                              \
      (const __attribute__((address_space(1))) void*)(gp),                       \
      (__attribute__((address_space(3))) void*)(lp), 16, 0, 0)

#define WAITN(n)                                                                 \
  do {                                                                           \
    asm volatile("s_waitcnt vmcnt(" #n ")" ::: "memory");                        \
    __builtin_amdgcn_sched_barrier(0);                                           \
  } while (0)

// ---------------- 4-wave 128x128 fp16 K-loop, depth-3 (s_attn) ----------------
// BK=32. LDS: 4 sets x {A 8KB, B 8KB} = 64KB. vmcnt(12) steady.
template <int NT, int LDA, int LDB>
__device__ __forceinline__ void kloop1(const f16* __restrict__ A,
                                       const f16* __restrict__ B,
                                       f16* __restrict__ SM,
                                       f32x4 (&acc)[4][4],
                                       int lane, int wv, int wm, int wn) {
  static_assert(NT >= 4, "depth-3 pipeline needs NT >= 4");
  const int f = lane & 15, kk = lane >> 4;
  const int cS = (lane & 7) ^ (lane >> 3);
  const int kkS = (cS & 3) * 8;
  const int rS = 2 * (lane >> 3) + (cS >> 2);
  const size_t offA0 = (size_t)(16 * (wv * 2 + 0) + rS) * LDA + kkS;
  const size_t offA1 = (size_t)(16 * (wv * 2 + 1) + rS) * LDA + kkS;
  const size_t offB0 = (size_t)(16 * (wv * 2 + 0) + rS) * LDB + kkS;
  const size_t offB1 = (size_t)(16 * (wv * 2 + 1) + rS) * LDB + kkS;
  const int Ld0 = (wv * 2 + 0) * 512, Ld1 = (wv * 2 + 1) * 512;

  int aoff[4], boff[4];
  #pragma unroll
  for (int mf = 0; mf < 4; ++mf) {
    const int R = wm + mf * 16 + f;
    const int c2 = (((R & 1) << 2) | kk) ^ ((R >> 1) & 7);
    aoff[mf] = (R >> 1) * 64 + c2 * 8;
  }
  #pragma unroll
  for (int nf = 0; nf < 4; ++nf) {
    const int R = wn + nf * 16 + f;
    const int c2 = (((R & 1) << 2) | kk) ^ ((R >> 1) & 7);
    boff[nf] = (R >> 1) * 64 + c2 * 8;
  }

  auto STAGE = [&](int set, int kt) {
    f16* base = SM + set * 8192;
    GLL(A + offA0 + kt, base + Ld0);
    GLL(A + offA1 + kt, base + Ld1);
    GLL(B + offB0 + kt, base + 4096 + Ld0);
    GLL(B + offB1 + kt, base + 4096 + Ld1);
  };
  auto COMPUTE = [&](int set) {
    const f16* p = SM + set * 8192;
    half8 a[4], b[4];
    #pragma unroll
    for (int mf = 0; mf < 4; ++mf) a[mf] = *(const half8*)&p[aoff[mf]];
    #pragma unroll
    for (int nf = 0; nf < 4; ++nf) b[nf] = *(const half8*)&p[4096 + boff[nf]];
    __builtin_amdgcn_s_setprio(1);
    #pragma unroll
    for (int mf = 0; mf < 4; ++mf)
      #pragma unroll
      for (int nf = 0; nf < 4; ++nf)
        acc[mf][nf] = __builtin_amdgcn_mfma_f32_16x16x32_f16(a[mf], b[nf], acc[mf][nf], 0, 0, 0);
    __builtin_amdgcn_s_setprio(0);
  };

  STAGE(0, 0);
  STAGE(1, 32);
  STAGE(2, 64);
  #pragma unroll 1
  for (int t = 0; t < NT - 3; ++t) {
    STAGE((t + 3) & 3, (t + 3) * 32);
    WAITN(12);
    __builtin_amdgcn_s_barrier();
    COMPUTE(t & 3);
    __builtin_amdgcn_s_barrier();
  }
  WAITN(8);
  __builtin_amdgcn_s_barrier();
  COMPUTE((NT - 3) & 3);
  __builtin_amdgcn_s_barrier();
  WAITN(4);
  __builtin_amdgcn_s_barrier();
  COMPUTE((NT - 2) & 3);
  __builtin_amdgcn_s_barrier();
  WAITN(0);
  __builtin_amdgcn_s_barrier();
  COMPUTE((NT - 1) & 3);
  __builtin_amdgcn_s_barrier();
}

// ---------------- 8-wave 256x256 fp16 K-loop, depth-2 (fused) ----------------
// BK=32. LDS: 3 sets x {A 16KB, B 16KB} = 96KB dynamic. vmcnt(8) steady.
template <int NT, int LDA, int LDB>
__device__ __forceinline__ void kloop256(const f16* __restrict__ A,
                                         const f16* __restrict__ B,
                                         f16* __restrict__ SM,
                                         f32x4 (&acc)[8][4],
                                         int lane, int wv, int wm, int wn) {
  static_assert(NT >= 4, "pipeline needs NT >= 4");
  const int f = lane & 15, kk = lane >> 4;
  const int cS = (lane & 7) ^ (lane >> 3);
  const int kkS = (cS & 3) * 8;
  const int rS = 2 * (lane >> 3) + (cS >> 2);
  const size_t offA0 = (size_t)(16 * (wv * 2 + 0) + rS) * LDA + kkS;
  const size_t offA1 = (size_t)(16 * (wv * 2 + 1) + rS) * LDA + kkS;
  const size_t offB0 = (size_t)(16 * (wv * 2 + 0) + rS) * LDB + kkS;
  const size_t offB1 = (size_t)(16 * (wv * 2 + 1) + rS) * LDB + kkS;
  const int Ld0 = (wv * 2 + 0) * 512, Ld1 = (wv * 2 + 1) * 512;

  int aoff[8], boff[4];
  #pragma unroll
  for (int mf = 0; mf < 8; ++mf) {
    const int R = wm + mf * 16 + f;
    const int c2 = (((R & 1) << 2) | kk) ^ ((R >> 1) & 7);
    aoff[mf] = (R >> 1) * 64 + c2 * 8;
  }
  #pragma unroll
  for (int nf = 0; nf < 4; ++nf) {
    const int R = wn + nf * 16 + f;
    const int c2 = (((R & 1) << 2) | kk) ^ ((R >> 1) & 7);
    boff[nf] = (R >> 1) * 64 + c2 * 8;
  }

  auto STAGE = [&](int set, int kt) {
    f16* base = SM + set * 16384;
    GLL(A + offA0 + kt, base + Ld0);
    GLL(A + offA1 + kt, base + Ld1);
    GLL(B + offB0 + kt, base + 8192 + Ld0);
    GLL(B + offB1 + kt, base + 8192 + Ld1);
  };
  auto COMPUTE = [&](int set) {
    const f16* p = SM + set * 16384;
    half8 a[8], b[4];
    #pragma unroll
    for (int mf = 0; mf < 8; ++mf) a[mf] = *(const half8*)&p[aoff[mf]];
    #pragma unroll
    for (int nf = 0; nf < 4; ++nf) b[nf] = *(const half8*)&p[8192 + boff[nf]];
    __builtin_amdgcn_s_setprio(1);
    #pragma unroll
    for (int mf = 0; mf < 8; ++mf)
      #pragma unroll
      for (int nf = 0; nf < 4; ++nf)
        acc[mf][nf] = __builtin_amdgcn_mfma_f32_16x16x32_f16(a[mf], b[nf], acc[mf][nf], 0, 0, 0);
    __builtin_amdgcn_s_setprio(0);
  };

  STAGE(0, 0);
  STAGE(1, 32);
  int cs = 0;
  #pragma unroll 1
  for (int t = 0; t < NT - 2; ++t) {
    int ss = cs + 2; if (ss >= 3) ss -= 3;
    STAGE(ss, (t + 2) * 32);
    WAITN(8);
    __builtin_amdgcn_s_barrier();
    COMPUTE(cs);
    __builtin_amdgcn_s_barrier();
    ++cs; if (cs == 3) cs = 0;
  }
  WAITN(4);
  __builtin_amdgcn_s_barrier();
  COMPUTE(cs);
  __builtin_amdgcn_s_barrier();
  ++cs; if (cs == 3) cs = 0;
  WAITN(0);
  __builtin_amdgcn_s_barrier();
  COMPUTE(cs);
  __builtin_amdgcn_s_barrier();
}

// ---------------- prep kernels ----------------

__global__ __launch_bounds__(256) void c_kernel(const float* __restrict__ W1,
                                                const float* __restrict__ b1,
                                                const float* __restrict__ hist,
                                                float* __restrict__ c) {
  const int wave = threadIdx.x >> 6, lane = threadIdx.x & 63;
  const int j = blockIdx.x * 4 + wave;
  const float* row = W1 + (size_t)j * 4096;
  float s = 0.f;
  #pragma unroll 2
  for (int kq = lane; kq < 512; kq += 64) {
    const float4 w = *(const float4*)&row[kq * 4];
    const float4 h = *(const float4*)&hist[kq * 4];
    s += w.x * h.x + w.y * h.y + w.z * h.z + w.w * h.w;
  }
  #pragma unroll
  for (int mask = 1; mask < 64; mask <<= 1) s += __shfl_xor(s, mask);
  if (lane == 0) c[j] = s + b1[j];
}

__device__ __forceinline__ half4_t f16hi4(const float4 v) {
  half4_t h;
  h.x = (f16)v.x; h.y = (f16)v.y; h.z = (f16)v.z; h.w = (f16)v.w;
  return h;
}

// blocks 0..4095: A rows (4/block) -> Af + ab2;  blocks 4096..4127: Q -> Qf
__global__ __launch_bounds__(256) void prep_AQ(const float* __restrict__ A,
                                               const float* __restrict__ Q,
                                               const float* __restrict__ b2,
                                               f16* __restrict__ Af,
                                               f16* __restrict__ Qf,
                                               float* __restrict__ ab2) {
  const int wv = threadIdx.x >> 6, lane = threadIdx.x & 63;
  if (blockIdx.x < 4096) {
    const size_t row = (size_t)blockIdx.x * 4 + wv;
    const float* ar = A + row * 2048;
    float dot = 0.f;
    #pragma unroll 2
    for (int c0 = 0; c0 < 2048; c0 += 256) {
      const int col = c0 + lane * 4;
      const float4 v = *(const float4*)&ar[col];
      const float4 bb = *(const float4*)&b2[col];
      dot += v.x * bb.x + v.y * bb.y + v.z * bb.z + v.w * bb.w;
      *(half4_t*)&Af[row * 2048 + col] = f16hi4(v);
    }
    #pragma unroll
    for (int mask = 1; mask < 64; mask <<= 1) dot += __shfl_xor(dot, mask);
    if (lane == 0) ab2[row] = dot;
  } else {
    const size_t row = (size_t)(blockIdx.x - 4096) * 4 + wv;
    const float* qr = Q + row * 2048;
    #pragma unroll 2
    for (int c0 = 0; c0 < 2048; c0 += 256) {
      const int col = c0 + lane * 4;
      const float4 v = *(const float4*)&qr[col];
      *(half4_t*)&Qf[row * 2048 + col] = f16hi4(v);
    }
  }
}

// dst[c*ldR + r] = (f16)src[r*C + c]
__global__ __launch_bounds__(256) void transpose_f16(const float* __restrict__ src,
                                                     int R, int C,
                                                     f16* __restrict__ dst) {
  __shared__ float T[64][65];
  const int c0 = blockIdx.x * 64, r0 = blockIdx.y * 64;
  const int t = threadIdx.x;
  {
    const int rl = t >> 4, cl = (t & 15) * 4;
    #pragma unroll
    for (int ii = 0; ii < 4; ++ii) {
      const float4 v = *(const float4*)&src[(size_t)(r0 + rl + ii * 16) * C + c0 + cl];
      T[rl + ii * 16][cl + 0] = v.x; T[rl + ii * 16][cl + 1] = v.y;
      T[rl + ii * 16][cl + 2] = v.z; T[rl + ii * 16][cl + 3] = v.w;
    }
  }
  __syncthreads();
  const int cc = t >> 2, rr0 = (t & 3) * 16;
  f16 u[16];
  #pragma unroll
  for (int k = 0; k < 16; ++k) u[k] = (f16)T[rr0 + k][cc];
  f16* ph = dst + (size_t)(c0 + cc) * R + r0 + rr0;
  #pragma unroll
  for (int k4 = 0; k4 < 4; ++k4)
    *(half4_t*)&ph[k4 * 4] = *(half4_t*)&u[k4 * 4];
}

// fp32 tiled GEMM (B^T layout), f16 output
template <int BM, int TM>
__global__ __launch_bounds__(256) void gemm_bt_f16(const float* __restrict__ A,
                                                   const float* __restrict__ B,
                                                   f16* __restrict__ C,
                                                   int K, int lda, int ldb, int ldc) {
  constexpr int BN = 64, BK = 32;
  constexpr int ASTR = BM + 12, BSTR = BN + 4;
  __shared__ float As[BK][ASTR];
  __shared__ float Bs[BK][BSTR];
  const int tid = threadIdx.x;
  const int tx = tid & 15, ty = tid >> 4;
  const int m0 = ty * TM, n0 = tx * 4;
  const size_t bm = (size_t)blockIdx.x * BM, bn = (size_t)blockIdx.y * BN;
  const float* Ab = A + bm * lda;
  const float* Bb = B + bn * ldb;
  float acc[TM][4];
  #pragma unroll
  for (int i = 0; i < TM; ++i)
    #pragma unroll
    for (int j = 0; j < 4; ++j) acc[i][j] = 0.f;
  for (int kt = 0; kt < K; kt += BK) {
    #pragma unroll
    for (int it = 0; it < BM * BK / 4 / 256; ++it) {
      const int idx = it * 256 + tid;
      const int row = idx >> 3, kq = idx & 7;
      const float4 v = *(const float4*)&Ab[(size_t)row * lda + kt + kq * 4];
      As[kq * 4 + 0][row] = v.x; As[kq * 4 + 1][row] = v.y;
      As[kq * 4 + 2][row] = v.z; As[kq * 4 + 3][row] = v.w;
    }
    #pragma unroll
    for (int it = 0; it < BN * BK / 4 / 256; ++it) {
      const int idx = it * 256 + tid;
      const int row = idx >> 3, kq = idx & 7;
      const float4 v = *(const float4*)&Bb[(size_t)row * ldb + kt + kq * 4];
      Bs[kq * 4 + 0][row] = v.x; Bs[kq * 4 + 1][row] = v.y;
      Bs[kq * 4 + 2][row] = v.z; Bs[kq * 4 + 3][row] = v.w;
    }
    __syncthreads();
    #pragma unroll
    for (int k = 0; k < BK; ++k) {
      float av[TM];
      #pragma unroll
      for (int i = 0; i < TM; ++i) av[i] = As[k][m0 + i];
      const float4 b = *(const float4*)&Bs[k][n0];
      const float bv[4] = {b.x, b.y, b.z, b.w};
      #pragma unroll
      for (int i = 0; i < TM; ++i)
        #pragma unroll
        for (int j = 0; j < 4; ++j) acc[i][j] = fmaf(av[i], bv[j], acc[i][j]);
    }
    __syncthreads();
  }
  #pragma unroll
  for (int i = 0; i < TM; ++i) {
    f16* crow = C + (bm + m0 + i) * (size_t)ldc + bn + n0;
    half4_t h;
    h.x = (f16)acc[i][0]; h.y = (f16)acc[i][1];
    h.z = (f16)acc[i][2]; h.w = (f16)acc[i][3];
    *(half4_t*)crow = h;
  }
}

// ---------------- S = Af@Qf^T (fp16 single) + fused row softmax -> at f16 ----
__global__ __launch_bounds__(256, 2) void s_attn(const f16* __restrict__ Af,
                                                 const f16* __restrict__ Qf,
                                                 f16* __restrict__ at) {
  __shared__ f16 SM[32768];  // 64 KB
  const int tid = threadIdx.x, lane = tid & 63, wv = tid >> 6;
  const int wm = (wv >> 1) * 64, wn = (wv & 1) * 64;
  const int f = lane & 15, kk = lane >> 4;
  const size_t bm = (size_t)blockIdx.x * 128;

  f32x4 acc[4][4];
  #pragma unroll
  for (int mf = 0; mf < 4; ++mf)
    #pragma unroll
    for (int nf = 0; nf < 4; ++nf) acc[mf][nf] = 0.f;

  kloop1<64, 2048, 2048>(Af + bm * 2048, Qf, SM, acc, lane, wv, wm, wn);

  float* sred = (float*)SM;        // [128][2] row-max
  float* ssum = sred + 256;        // [128][2] row-sum
  const int rowbase = wm + kk * 4;
  float rmax[4][4];
  #pragma unroll
  for (int mf = 0; mf < 4; ++mf)
    #pragma unroll
    for (int r = 0; r < 4; ++r) {
      float m4 = fmaxf(fmaxf(acc[mf][0][r], acc[mf][1][r]),
                       fmaxf(acc[mf][2][r], acc[mf][3][r]));
      m4 = fmaxf(m4, __shfl_xor(m4, 1));
      m4 = fmaxf(m4, __shfl_xor(m4, 2));
      m4 = fmaxf(m4, __shfl_xor(m4, 4));
      m4 = fmaxf(m4, __shfl_xor(m4, 8));
      rmax[mf][r] = m4;
    }
  if (f == 0) {
    #pragma unroll
    for (int mf = 0; mf < 4; ++mf)
      #pragma unroll
      for (int r = 0; r < 4; ++r)
        sred[(rowbase + mf * 16 + r) * 2 + (wv & 1)] = rmax[mf][r];
  }
  __syncthreads();
  #pragma unroll
  for (int mf = 0; mf < 4; ++mf)
    #pragma unroll
    for (int r = 0; r < 4; ++r) {
      const int row = rowbase + mf * 16 + r;
      rmax[mf][r] = fmaxf(sred[row * 2], sred[row * 2 + 1]);
    }
  float rsum[4][4];
  #pragma unroll
  for (int mf = 0; mf < 4; ++mf)
    #pragma unroll
    for (int r = 0; r < 4; ++r) {
      float s = 0.f;
      #pragma unroll
      for (int nf = 0; nf < 4; ++nf) {
        acc[mf][nf][r] = __expf(acc[mf][nf][r] - rmax[mf][r]);
        s += acc[mf][nf][r];
      }
      s += __shfl_xor(s, 1);
      s += __shfl_xor(s, 2);
      s += __shfl_xor(s, 4);
      s += __shfl_xor(s, 8);
      rsum[mf][r] = s;
    }
  if (f == 0) {
    #pragma unroll
    for (int mf = 0; mf < 4; ++mf)
      #pragma unroll
      for (int r = 0; r < 4; ++r)
        ssum[(rowbase + mf * 16 + r) * 2 + (wv & 1)] = rsum[mf][r];
  }
  __syncthreads();
  #pragma unroll
  for (int mf = 0; mf < 4; ++mf)
    #pragma unroll
    for (int r = 0; r < 4; ++r) {
      const int row = rowbase + mf * 16 + r;
      const float inv = 1.0f / (ssum[row * 2] + ssum[row * 2 + 1]);
      const size_t orow = (bm + row) * 128;
      #pragma unroll
      for (int nf = 0; nf < 4; ++nf)
        at[orow + wn + nf * 16 + f] = (f16)(acc[mf][nf][r] * inv);
    }
}

// ---------------- fused z/h/G/dot, 256x256 tile ----------------
__global__ __launch_bounds__(512, 1) void fused_zg_mfma(
    const f16* __restrict__ Af, const f16* __restrict__ at,
    const f16* __restrict__ QWt, const f16* __restrict__ W2t,
    const float* __restrict__ cvec, float* __restrict__ partial) {
  extern __shared__ f16 SM[];  // 96 KB: 3 sets x {A 16KB, B 16KB}
  const int tid = threadIdx.x, lane = tid & 63, wv = tid >> 6;   // wv 0..7
  const int wm = (wv >> 2) * 128, wn = (wv & 3) * 64;
  const int f = lane & 15, kk = lane >> 4;
  // bijective XCD swizzle: nwg=512, 8 XCDs, 64 per XCD
  const int lin = blockIdx.x;
  const int sid = (lin & 7) * 64 + (lin >> 3);
  const int bmI = sid & 63, bnI = sid >> 6;       // 64 m-blocks x 8 n-blocks
  const size_t bm = (size_t)bmI * 256;
  const size_t bn = (size_t)bnI * 256;

  f32x4 acc[8][4];
  #pragma unroll
  for (int mf = 0; mf < 8; ++mf)
    #pragma unroll
    for (int nf = 0; nf < 4; ++nf) acc[mf][nf] = 0.f;

  // phase Z: z = at @ QWt, K = 128
  kloop256<4, 128, 128>(at + bm * 128, QWt + bn * 128, SM, acc, lane, wv, wm, wn);

  // h = relu(z + c), packed f16 (16 VGPR)
  half4_t hreg[8][4];
  {
    float ccv[4];
    #pragma unroll
    for (int nf = 0; nf < 4; ++nf) ccv[nf] = cvec[bn + wn + nf * 16 + f];
    #pragma unroll
    for (int mf = 0; mf < 8; ++mf)
      #pragma unroll
      for (int nf = 0; nf < 4; ++nf) {
        half4_t hv;
        hv.x = (f16)fmaxf(acc[mf][nf][0] + ccv[nf], 0.f);
        hv.y = (f16)fmaxf(acc[mf][nf][1] + ccv[nf], 0.f);
        hv.z = (f16)fmaxf(acc[mf][nf][2] + ccv[nf], 0.f);
        hv.w = (f16)fmaxf(acc[mf][nf][3] + ccv[nf], 0.f);
        hreg[mf][nf] = hv;
        acc[mf][nf] = 0.f;
      }
  }

  // phase G: G = Af @ W2t, K = 2048
  kloop256<64, 2048, 2048>(Af + bm * 2048, W2t + bn * 2048, SM, acc, lane, wv, wm, wn);

  // epilogue: partial = sum over this block's 256 j of h*G
  float part[8][4];
  #pragma unroll
  for (int mf = 0; mf < 8; ++mf)
    #pragma unroll
    for (int r = 0; r < 4; ++r) {
      float s = 0.f;
      #pragma unroll
      for (int nf = 0; nf < 4; ++nf)
        s += (float)hreg[mf][nf][r] * acc[mf][nf][r];
      part[mf][r] = s;
    }
  #pragma unroll
  for (int mf = 0; mf < 8; ++mf)
    #pragma unroll
    for (int r = 0; r < 4; ++r) {
      part[mf][r] += __shfl_xor(part[mf][r], 1);
      part[mf][r] += __shfl_xor(part[mf][r], 2);
      part[mf][r] += __shfl_xor(part[mf][r], 4);
      part[mf][r] += __shfl_xor(part[mf][r], 8);
    }
  if (f == 0) {
    const size_t slab = (size_t)(bnI * 4 + (wv & 3)) * 16384;
    #pragma unroll
    for (int mf = 0; mf < 8; ++mf)
      #pragma unroll
      for (int r = 0; r < 4; ++r)
        partial[slab + bm + wm + mf * 16 + kk * 4 + r] = part[mf][r];
  }
}

// ---------------- final reduction + softmax over M ----------------

__global__ __launch_bounds__(256) void k_sem(const float* __restrict__ partial,
                                             const float* __restrict__ ab2,
                                             float* __restrict__ semantic,
                                             float* __restrict__ bstats) {
  const int m = blockIdx.x * 256 + threadIdx.x;
  float s = ab2[m];
  #pragma unroll
  for (int nb = 0; nb < 32; ++nb) s += partial[(size_t)nb * 16384 + m];
  semantic[m] = s;
  float mx = s;
  #pragma unroll
  for (int mask = 1; mask < 64; mask <<= 1) mx = fmaxf(mx, __shfl_xor(mx, mask));
  __shared__ float wmax[4], wsum[4];
  const int wave = threadIdx.x >> 6, lane = threadIdx.x & 63;
  if (lane == 0) wmax[wave] = mx;
  __syncthreads();
  const float bmax = fmaxf(fmaxf(wmax[0], wmax[1]), fmaxf(wmax[2], wmax[3]));
  float e = expf(s - bmax);
  #pragma unroll
  for (int mask = 1; mask < 64; mask <<= 1) e += __shfl_xor(e, mask);
  if (lane == 0) wsum[wave] = e;
  __syncthreads();
  if (threadIdx.x == 0) {
    bstats[blockIdx.x * 2] = bmax;
    bstats[blockIdx.x * 2 + 1] = wsum[0] + wsum[1] + wsum[2] + wsum[3];
  }
}

__global__ __launch_bounds__(256) void k_out(const float* __restrict__ semantic,
                                             const float* __restrict__ bstats,
                                             float* __restrict__ out) {
  __shared__ float g0s, g1s;
  const int tid = threadIdx.x;
  if (tid < 64) {
    const float bm = bstats[tid * 2], bs = bstats[tid * 2 + 1];
    float gm = bm;
    #pragma unroll
    for (int mask = 1; mask < 64; mask <<= 1) gm = fmaxf(gm, __shfl_xor(gm, mask));
    float gs = bs * expf(bm - gm);
    #pragma unroll
    for (int mask = 1; mask < 64; mask <<= 1) gs += __shfl_xor(gs, mask);
    if (tid == 0) { g0s = gm; g1s = gs; }
  }
  __syncthreads();
  const int m = blockIdx.x * 256 + tid;
  out[m] = expf(semantic[m] - g0s) / g1s;
}

// ---------------- launch ----------------

extern "C" void kernel_launch(void* const* d_in, const int* in_sizes, int n_in,
                              void* d_out, int out_size, void* d_ws, size_t ws_size,
                              hipStream_t stream) {
  (void)in_sizes; (void)n_in; (void)out_size; (void)ws_size;
  const float* A    = (const float*)d_in[0];  // [16384][2048]
  const float* Q    = (const float*)d_in[1];  // [128][2048]
  const float* hist = (const float*)d_in[2];  // [2048]
  const float* W1   = (const float*)d_in[3];  // [2048][4096]
  const float* b1   = (const float*)d_in[4];  // [2048]
  const float* W2   = (const float*)d_in[5];  // [2048][2048]
  const float* b2   = (const float*)d_in[6];  // [2048]
  float* out = (float*)d_out;                 // [16384]

  char* ws = (char*)d_ws;
  f16* Af      = (f16*)ws;   ws += (size_t)16384 * 2048 * 2;  // 64 MB
  f16* W2t     = (f16*)ws;   ws += (size_t)2048 * 2048 * 2;   // 8 MB
  f16* Qf      = (f16*)ws;   ws += (size_t)128 * 2048 * 2;
  f16* QWt     = (f16*)ws;   ws += (size_t)2048 * 128 * 2;
  f16* at      = (f16*)ws;   ws += (size_t)16384 * 128 * 2;   // 4 MB
  float* c_vec = (float*)ws; ws += 2048 * 4;
  float* ab2   = (float*)ws; ws += 16384 * 4;
  float* partial  = (float*)ws; ws += (size_t)32 * 16384 * 4; // 2 MB
  float* semantic = (float*)ws; ws += 16384 * 4;
  float* bstats   = (float*)ws; ws += 128 * 4;

  hipFuncSetAttribute((const void*)fused_zg_mfma,
                      hipFuncAttributeMaxDynamicSharedMemorySize, 98304);

  // prep
  c_kernel<<<512, 256, 0, stream>>>(W1, b1, hist, c_vec);
  gemm_bt_f16<32, 2><<<dim3(64, 2), 256, 0, stream>>>(W1 + 2048, Q, QWt,
                                                      2048, 4096, 2048, 128);
  transpose_f16<<<dim3(32, 32), 256, 0, stream>>>(W2, 2048, 2048, W2t);
  prep_AQ<<<4128, 256, 0, stream>>>(A, Q, b2, Af, Qf, ab2);
  // S = Af@Qf^T + softmax (fp16 single MFMA)
  s_attn<<<128, 256, 0, stream>>>(Af, Qf, at);
  // fused z/h/G/dot (256x256 tile, 96KB dynamic LDS, no VGPR cap -> no spill)
  fused_zg_mfma<<<512, 512, 98304, stream>>>(Af, at, QWt, W2t, c_vec, partial);
  // semantic + softmax over M
  k_sem<<<64, 256, 0, stream>>>(partial, ab2, semantic, bstats);
  k_out<<<64, 256, 0, stream>>>(semantic, bstats, out);
}

// Round 10
// 325.175 us; speedup vs baseline: 2.7134x; 1.0889x over previous
//
#include <hip/hip_runtime.h>
#include <hip/hip_bf16.h>

// PolicyNet, fp16 MFMA:
//   A -> Af fp16, ab2[m] = A[m]·b2;  Q -> Qf fp16
//   c    = b1 + W1[:, :D] @ hist                  (fp32)
//   QWt  = (f16)(W1[:, D:] @ Q^T)   [j][n]
//   W2   -> transpose -> W2t f16 [j][k]
//   s_attn: S = Af@Qf^T (fp16 single MFMA), fused row-softmax -> at f16
//   h_kernel: H = relu(at @ QWt + c) f16 [16384][2048]   (128² tile, K=128)
//   fused_g (256², G-only, no spill): G = Af @ W2t (K=2048);
//       epilogue loads H frags, partial = sum_j H*G
//   semantic = sum partial + ab2 -> softmax over M -> out

typedef _Float16 f16;
typedef __attribute__((ext_vector_type(8))) _Float16 half8;
typedef __attribute__((ext_vector_type(4))) _Float16 half4_t;
typedef __attribute__((ext_vector_type(4))) float f32x4;

#define GLL(gp, lp)                                                              \
  __builtin_amdgcn_global_load_lds(                                              \
      (const __attribute__((address_space(1))) void*)(gp),                       \
      (__attribute__((address_space(3))) void*)(lp), 16, 0, 0)

#define WAITN(n)                                                                 \
  do {                                                                           \
    asm volatile("s_waitcnt vmcnt(" #n ")" ::: "memory");                        \
    __builtin_amdgcn_sched_barrier(0);                                           \
  } while (0)

// ---------------- 4-wave 128x128 fp16 K-loop, depth-3 ----------------
// BK=32. LDS: 4 sets x {A 8KB, B 8KB} = 64KB. vmcnt(12) steady.
template <int NT, int LDA, int LDB>
__device__ __forceinline__ void kloop1(const f16* __restrict__ A,
                                       const f16* __restrict__ B,
                                       f16* __restrict__ SM,
                                       f32x4 (&acc)[4][4],
                                       int lane, int wv, int wm, int wn) {
  static_assert(NT >= 4, "depth-3 pipeline needs NT >= 4");
  const int f = lane & 15, kk = lane >> 4;
  const int cS = (lane & 7) ^ (lane >> 3);
  const int kkS = (cS & 3) * 8;
  const int rS = 2 * (lane >> 3) + (cS >> 2);
  const size_t offA0 = (size_t)(16 * (wv * 2 + 0) + rS) * LDA + kkS;
  const size_t offA1 = (size_t)(16 * (wv * 2 + 1) + rS) * LDA + kkS;
  const size_t offB0 = (size_t)(16 * (wv * 2 + 0) + rS) * LDB + kkS;
  const size_t offB1 = (size_t)(16 * (wv * 2 + 1) + rS) * LDB + kkS;
  const int Ld0 = (wv * 2 + 0) * 512, Ld1 = (wv * 2 + 1) * 512;

  int aoff[4], boff[4];
  #pragma unroll
  for (int mf = 0; mf < 4; ++mf) {
    const int R = wm + mf * 16 + f;
    const int c2 = (((R & 1) << 2) | kk) ^ ((R >> 1) & 7);
    aoff[mf] = (R >> 1) * 64 + c2 * 8;
  }
  #pragma unroll
  for (int nf = 0; nf < 4; ++nf) {
    const int R = wn + nf * 16 + f;
    const int c2 = (((R & 1) << 2) | kk) ^ ((R >> 1) & 7);
    boff[nf] = (R >> 1) * 64 + c2 * 8;
  }

  auto STAGE = [&](int set, int kt) {
    f16* base = SM + set * 8192;
    GLL(A + offA0 + kt, base + Ld0);
    GLL(A + offA1 + kt, base + Ld1);
    GLL(B + offB0 + kt, base + 4096 + Ld0);
    GLL(B + offB1 + kt, base + 4096 + Ld1);
  };
  auto COMPUTE = [&](int set) {
    const f16* p = SM + set * 8192;
    half8 a[4], b[4];
    #pragma unroll
    for (int mf = 0; mf < 4; ++mf) a[mf] = *(const half8*)&p[aoff[mf]];
    #pragma unroll
    for (int nf = 0; nf < 4; ++nf) b[nf] = *(const half8*)&p[4096 + boff[nf]];
    __builtin_amdgcn_s_setprio(1);
    #pragma unroll
    for (int mf = 0; mf < 4; ++mf)
      #pragma unroll
      for (int nf = 0; nf < 4; ++nf)
        acc[mf][nf] = __builtin_amdgcn_mfma_f32_16x16x32_f16(a[mf], b[nf], acc[mf][nf], 0, 0, 0);
    __builtin_amdgcn_s_setprio(0);
  };

  STAGE(0, 0);
  STAGE(1, 32);
  STAGE(2, 64);
  #pragma unroll 1
  for (int t = 0; t < NT - 3; ++t) {
    STAGE((t + 3) & 3, (t + 3) * 32);
    WAITN(12);
    __builtin_amdgcn_s_barrier();
    COMPUTE(t & 3);
    __builtin_amdgcn_s_barrier();
  }
  WAITN(8);
  __builtin_amdgcn_s_barrier();
  COMPUTE((NT - 3) & 3);
  __builtin_amdgcn_s_barrier();
  WAITN(4);
  __builtin_amdgcn_s_barrier();
  COMPUTE((NT - 2) & 3);
  __builtin_amdgcn_s_barrier();
  WAITN(0);
  __builtin_amdgcn_s_barrier();
  COMPUTE((NT - 1) & 3);
  __builtin_amdgcn_s_barrier();
}

// ---------------- 8-wave 256x256 fp16 K-loop, depth-2 ----------------
// BK=32. LDS: 3 sets x {A 16KB, B 16KB} = 96KB dynamic. vmcnt(8) steady.
template <int NT, int LDA, int LDB>
__device__ __forceinline__ void kloop256(const f16* __restrict__ A,
                                         const f16* __restrict__ B,
                                         f16* __restrict__ SM,
                                         f32x4 (&acc)[8][4],
                                         int lane, int wv, int wm, int wn) {
  static_assert(NT >= 4, "pipeline needs NT >= 4");
  const int f = lane & 15, kk = lane >> 4;
  const int cS = (lane & 7) ^ (lane >> 3);
  const int kkS = (cS & 3) * 8;
  const int rS = 2 * (lane >> 3) + (cS >> 2);
  const size_t offA0 = (size_t)(16 * (wv * 2 + 0) + rS) * LDA + kkS;
  const size_t offA1 = (size_t)(16 * (wv * 2 + 1) + rS) * LDA + kkS;
  const size_t offB0 = (size_t)(16 * (wv * 2 + 0) + rS) * LDB + kkS;
  const size_t offB1 = (size_t)(16 * (wv * 2 + 1) + rS) * LDB + kkS;
  const int Ld0 = (wv * 2 + 0) * 512, Ld1 = (wv * 2 + 1) * 512;

  int aoff[8], boff[4];
  #pragma unroll
  for (int mf = 0; mf < 8; ++mf) {
    const int R = wm + mf * 16 + f;
    const int c2 = (((R & 1) << 2) | kk) ^ ((R >> 1) & 7);
    aoff[mf] = (R >> 1) * 64 + c2 * 8;
  }
  #pragma unroll
  for (int nf = 0; nf < 4; ++nf) {
    const int R = wn + nf * 16 + f;
    const int c2 = (((R & 1) << 2) | kk) ^ ((R >> 1) & 7);
    boff[nf] = (R >> 1) * 64 + c2 * 8;
  }

  auto STAGE = [&](int set, int kt) {
    f16* base = SM + set * 16384;
    GLL(A + offA0 + kt, base + Ld0);
    GLL(A + offA1 + kt, base + Ld1);
    GLL(B + offB0 + kt, base + 8192 + Ld0);
    GLL(B + offB1 + kt, base + 8192 + Ld1);
  };
  auto COMPUTE = [&](int set) {
    const f16* p = SM + set * 16384;
    half8 a[8], b[4];
    #pragma unroll
    for (int mf = 0; mf < 8; ++mf) a[mf] = *(const half8*)&p[aoff[mf]];
    #pragma unroll
    for (int nf = 0; nf < 4; ++nf) b[nf] = *(const half8*)&p[8192 + boff[nf]];
    __builtin_amdgcn_s_setprio(1);
    #pragma unroll
    for (int mf = 0; mf < 8; ++mf)
      #pragma unroll
      for (int nf = 0; nf < 4; ++nf)
        acc[mf][nf] = __builtin_amdgcn_mfma_f32_16x16x32_f16(a[mf], b[nf], acc[mf][nf], 0, 0, 0);
    __builtin_amdgcn_s_setprio(0);
  };

  STAGE(0, 0);
  STAGE(1, 32);
  int cs = 0;
  #pragma unroll 1
  for (int t = 0; t < NT - 2; ++t) {
    int ss = cs + 2; if (ss >= 3) ss -= 3;
    STAGE(ss, (t + 2) * 32);
    WAITN(8);
    __builtin_amdgcn_s_barrier();
    COMPUTE(cs);
    __builtin_amdgcn_s_barrier();
    ++cs; if (cs == 3) cs = 0;
  }
  WAITN(4);
  __builtin_amdgcn_s_barrier();
  COMPUTE(cs);
  __builtin_amdgcn_s_barrier();
  ++cs; if (cs == 3) cs = 0;
  WAITN(0);
  __builtin_amdgcn_s_barrier();
  COMPUTE(cs);
  __builtin_amdgcn_s_barrier();
}

// ---------------- prep kernels ----------------

__global__ __launch_bounds__(256) void c_kernel(const float* __restrict__ W1,
                                                const float* __restrict__ b1,
                                                const float* __restrict__ hist,
                                                float* __restrict__ c) {
  const int wave = threadIdx.x >> 6, lane = threadIdx.x & 63;
  const int j = blockIdx.x * 4 + wave;
  const float* row = W1 + (size_t)j * 4096;
  float s = 0.f;
  #pragma unroll 2
  for (int kq = lane; kq < 512; kq += 64) {
    const float4 w = *(const float4*)&row[kq * 4];
    const float4 h = *(const float4*)&hist[kq * 4];
    s += w.x * h.x + w.y * h.y + w.z * h.z + w.w * h.w;
  }
  #pragma unroll
  for (int mask = 1; mask < 64; mask <<= 1) s += __shfl_xor(s, mask);
  if (lane == 0) c[j] = s + b1[j];
}

__device__ __forceinline__ half4_t f16hi4(const float4 v) {
  half4_t h;
  h.x = (f16)v.x; h.y = (f16)v.y; h.z = (f16)v.z; h.w = (f16)v.w;
  return h;
}

// blocks 0..4095: A rows (4/block) -> Af + ab2;  blocks 4096..4127: Q -> Qf
__global__ __launch_bounds__(256) void prep_AQ(const float* __restrict__ A,
                                               const float* __restrict__ Q,
                                               const float* __restrict__ b2,
                                               f16* __restrict__ Af,
                                               f16* __restrict__ Qf,
                                               float* __restrict__ ab2) {
  const int wv = threadIdx.x >> 6, lane = threadIdx.x & 63;
  if (blockIdx.x < 4096) {
    const size_t row = (size_t)blockIdx.x * 4 + wv;
    const float* ar = A + row * 2048;
    float dot = 0.f;
    #pragma unroll 2
    for (int c0 = 0; c0 < 2048; c0 += 256) {
      const int col = c0 + lane * 4;
      const float4 v = *(const float4*)&ar[col];
      const float4 bb = *(const float4*)&b2[col];
      dot += v.x * bb.x + v.y * bb.y + v.z * bb.z + v.w * bb.w;
      *(half4_t*)&Af[row * 2048 + col] = f16hi4(v);
    }
    #pragma unroll
    for (int mask = 1; mask < 64; mask <<= 1) dot += __shfl_xor(dot, mask);
    if (lane == 0) ab2[row] = dot;
  } else {
    const size_t row = (size_t)(blockIdx.x - 4096) * 4 + wv;
    const float* qr = Q + row * 2048;
    #pragma unroll 2
    for (int c0 = 0; c0 < 2048; c0 += 256) {
      const int col = c0 + lane * 4;
      const float4 v = *(const float4*)&qr[col];
      *(half4_t*)&Qf[row * 2048 + col] = f16hi4(v);
    }
  }
}

// dst[c*ldR + r] = (f16)src[r*C + c]
__global__ __launch_bounds__(256) void transpose_f16(const float* __restrict__ src,
                                                     int R, int C,
                                                     f16* __restrict__ dst) {
  __shared__ float T[64][65];
  const int c0 = blockIdx.x * 64, r0 = blockIdx.y * 64;
  const int t = threadIdx.x;
  {
    const int rl = t >> 4, cl = (t & 15) * 4;
    #pragma unroll
    for (int ii = 0; ii < 4; ++ii) {
      const float4 v = *(const float4*)&src[(size_t)(r0 + rl + ii * 16) * C + c0 + cl];
      T[rl + ii * 16][cl + 0] = v.x; T[rl + ii * 16][cl + 1] = v.y;
      T[rl + ii * 16][cl + 2] = v.z; T[rl + ii * 16][cl + 3] = v.w;
    }
  }
  __syncthreads();
  const int cc = t >> 2, rr0 = (t & 3) * 16;
  f16 u[16];
  #pragma unroll
  for (int k = 0; k < 16; ++k) u[k] = (f16)T[rr0 + k][cc];
  f16* ph = dst + (size_t)(c0 + cc) * R + r0 + rr0;
  #pragma unroll
  for (int k4 = 0; k4 < 4; ++k4)
    *(half4_t*)&ph[k4 * 4] = *(half4_t*)&u[k4 * 4];
}

// fp32 tiled GEMM (B^T layout), f16 output
template <int BM, int TM>
__global__ __launch_bounds__(256) void gemm_bt_f16(const float* __restrict__ A,
                                                   const float* __restrict__ B,
                                                   f16* __restrict__ C,
                                                   int K, int lda, int ldb, int ldc) {
  constexpr int BN = 64, BK = 32;
  constexpr int ASTR = BM + 12, BSTR = BN + 4;
  __shared__ float As[BK][ASTR];
  __shared__ float Bs[BK][BSTR];
  const int tid = threadIdx.x;
  const int tx = tid & 15, ty = tid >> 4;
  const int m0 = ty * TM, n0 = tx * 4;
  const size_t bm = (size_t)blockIdx.x * BM, bn = (size_t)blockIdx.y * BN;
  const float* Ab = A + bm * lda;
  const float* Bb = B + bn * ldb;
  float acc[TM][4];
  #pragma unroll
  for (int i = 0; i < TM; ++i)
    #pragma unroll
    for (int j = 0; j < 4; ++j) acc[i][j] = 0.f;
  for (int kt = 0; kt < K; kt += BK) {
    #pragma unroll
    for (int it = 0; it < BM * BK / 4 / 256; ++it) {
      const int idx = it * 256 + tid;
      const int row = idx >> 3, kq = idx & 7;
      const float4 v = *(const float4*)&Ab[(size_t)row * lda + kt + kq * 4];
      As[kq * 4 + 0][row] = v.x; As[kq * 4 + 1][row] = v.y;
      As[kq * 4 + 2][row] = v.z; As[kq * 4 + 3][row] = v.w;
    }
    #pragma unroll
    for (int it = 0; it < BN * BK / 4 / 256; ++it) {
      const int idx = it * 256 + tid;
      const int row = idx >> 3, kq = idx & 7;
      const float4 v = *(const float4*)&Bb[(size_t)row * ldb + kt + kq * 4];
      Bs[kq * 4 + 0][row] = v.x; Bs[kq * 4 + 1][row] = v.y;
      Bs[kq * 4 + 2][row] = v.z; Bs[kq * 4 + 3][row] = v.w;
    }
    __syncthreads();
    #pragma unroll
    for (int k = 0; k < BK; ++k) {
      float av[TM];
      #pragma unroll
      for (int i = 0; i < TM; ++i) av[i] = As[k][m0 + i];
      const float4 b = *(const float4*)&Bs[k][n0];
      const float bv[4] = {b.x, b.y, b.z, b.w};
      #pragma unroll
      for (int i = 0; i < TM; ++i)
        #pragma unroll
        for (int j = 0; j < 4; ++j) acc[i][j] = fmaf(av[i], bv[j], acc[i][j]);
    }
    __syncthreads();
  }
  #pragma unroll
  for (int i = 0; i < TM; ++i) {
    f16* crow = C + (bm + m0 + i) * (size_t)ldc + bn + n0;
    half4_t h;
    h.x = (f16)acc[i][0]; h.y = (f16)acc[i][1];
    h.z = (f16)acc[i][2]; h.w = (f16)acc[i][3];
    *(half4_t*)crow = h;
  }
}

// ---------------- S = Af@Qf^T (fp16 single) + fused row softmax -> at f16 ----
__global__ __launch_bounds__(256, 2) void s_attn(const f16* __restrict__ Af,
                                                 const f16* __restrict__ Qf,
                                                 f16* __restrict__ at) {
  __shared__ f16 SM[32768];  // 64 KB
  const int tid = threadIdx.x, lane = tid & 63, wv = tid >> 6;
  const int wm = (wv >> 1) * 64, wn = (wv & 1) * 64;
  const int f = lane & 15, kk = lane >> 4;
  const size_t bm = (size_t)blockIdx.x * 128;

  f32x4 acc[4][4];
  #pragma unroll
  for (int mf = 0; mf < 4; ++mf)
    #pragma unroll
    for (int nf = 0; nf < 4; ++nf) acc[mf][nf] = 0.f;

  kloop1<64, 2048, 2048>(Af + bm * 2048, Qf, SM, acc, lane, wv, wm, wn);

  float* sred = (float*)SM;        // [128][2] row-max
  float* ssum = sred + 256;        // [128][2] row-sum
  const int rowbase = wm + kk * 4;
  float rmax[4][4];
  #pragma unroll
  for (int mf = 0; mf < 4; ++mf)
    #pragma unroll
    for (int r = 0; r < 4; ++r) {
      float m4 = fmaxf(fmaxf(acc[mf][0][r], acc[mf][1][r]),
                       fmaxf(acc[mf][2][r], acc[mf][3][r]));
      m4 = fmaxf(m4, __shfl_xor(m4, 1));
      m4 = fmaxf(m4, __shfl_xor(m4, 2));
      m4 = fmaxf(m4, __shfl_xor(m4, 4));
      m4 = fmaxf(m4, __shfl_xor(m4, 8));
      rmax[mf][r] = m4;
    }
  if (f == 0) {
    #pragma unroll
    for (int mf = 0; mf < 4; ++mf)
      #pragma unroll
      for (int r = 0; r < 4; ++r)
        sred[(rowbase + mf * 16 + r) * 2 + (wv & 1)] = rmax[mf][r];
  }
  __syncthreads();
  #pragma unroll
  for (int mf = 0; mf < 4; ++mf)
    #pragma unroll
    for (int r = 0; r < 4; ++r) {
      const int row = rowbase + mf * 16 + r;
      rmax[mf][r] = fmaxf(sred[row * 2], sred[row * 2 + 1]);
    }
  float rsum[4][4];
  #pragma unroll
  for (int mf = 0; mf < 4; ++mf)
    #pragma unroll
    for (int r = 0; r < 4; ++r) {
      float s = 0.f;
      #pragma unroll
      for (int nf = 0; nf < 4; ++nf) {
        acc[mf][nf][r] = __expf(acc[mf][nf][r] - rmax[mf][r]);
        s += acc[mf][nf][r];
      }
      s += __shfl_xor(s, 1);
      s += __shfl_xor(s, 2);
      s += __shfl_xor(s, 4);
      s += __shfl_xor(s, 8);
      rsum[mf][r] = s;
    }
  if (f == 0) {
    #pragma unroll
    for (int mf = 0; mf < 4; ++mf)
      #pragma unroll
      for (int r = 0; r < 4; ++r)
        ssum[(rowbase + mf * 16 + r) * 2 + (wv & 1)] = rsum[mf][r];
  }
  __syncthreads();
  #pragma unroll
  for (int mf = 0; mf < 4; ++mf)
    #pragma unroll
    for (int r = 0; r < 4; ++r) {
      const int row = rowbase + mf * 16 + r;
      const float inv = 1.0f / (ssum[row * 2] + ssum[row * 2 + 1]);
      const size_t orow = (bm + row) * 128;
      #pragma unroll
      for (int nf = 0; nf < 4; ++nf)
        at[orow + wn + nf * 16 + f] = (f16)(acc[mf][nf][r] * inv);
    }
}

// ---------------- H = relu(at @ QWt + c), 128x128 tile, K=128 ----------------
__global__ __launch_bounds__(256, 2) void h_kernel(const f16* __restrict__ at,
                                                   const f16* __restrict__ QWt,
                                                   const float* __restrict__ cvec,
                                                   f16* __restrict__ H) {
  __shared__ f16 SM[32768];  // 64 KB (4 sets x 16KB)
  const int tid = threadIdx.x, lane = tid & 63, wv = tid >> 6;
  const int wm = (wv >> 1) * 64, wn = (wv & 1) * 64;
  const int f = lane & 15, kk = lane >> 4;
  const size_t bm = (size_t)(blockIdx.x & 127) * 128;
  const size_t bn = (size_t)(blockIdx.x >> 7) * 128;

  f32x4 acc[4][4];
  #pragma unroll
  for (int mf = 0; mf < 4; ++mf)
    #pragma unroll
    for (int nf = 0; nf < 4; ++nf) acc[mf][nf] = 0.f;

  kloop1<4, 128, 128>(at + bm * 128, QWt + bn * 128, SM, acc, lane, wv, wm, wn);

  float ccv[4];
  #pragma unroll
  for (int nf = 0; nf < 4; ++nf) ccv[nf] = cvec[bn + wn + nf * 16 + f];
  #pragma unroll
  for (int mf = 0; mf < 4; ++mf)
    #pragma unroll
    for (int r = 0; r < 4; ++r) {
      const size_t row = bm + wm + mf * 16 + kk * 4 + r;
      #pragma unroll
      for (int nf = 0; nf < 4; ++nf)
        H[row * 2048 + bn + wn + nf * 16 + f] =
            (f16)fmaxf(acc[mf][nf][r] + ccv[nf], 0.f);
    }
}

// ---------------- fused G: G = Af @ W2t (256² tile) + dot with H ----------------
__global__ __launch_bounds__(512, 1) void fused_g(
    const f16* __restrict__ Af, const f16* __restrict__ H,
    const f16* __restrict__ W2t, float* __restrict__ partial) {
  extern __shared__ f16 SM[];  // 96 KB: 3 sets x {A 16KB, B 16KB}
  const int tid = threadIdx.x, lane = tid & 63, wv = tid >> 6;   // wv 0..7
  const int wm = (wv >> 2) * 128, wn = (wv & 3) * 64;
  const int f = lane & 15, kk = lane >> 4;
  // bijective XCD swizzle: nwg=512, 8 XCDs, 64 per XCD
  const int lin = blockIdx.x;
  const int sid = (lin & 7) * 64 + (lin >> 3);
  const int bmI = sid & 63, bnI = sid >> 6;       // 64 m-blocks x 8 n-blocks
  const size_t bm = (size_t)bmI * 256;
  const size_t bn = (size_t)bnI * 256;

  f32x4 acc[8][4];
  #pragma unroll
  for (int mf = 0; mf < 8; ++mf)
    #pragma unroll
    for (int nf = 0; nf < 4; ++nf) acc[mf][nf] = 0.f;

  kloop256<64, 2048, 2048>(Af + bm * 2048, W2t + bn * 2048, SM, acc, lane, wv, wm, wn);

  // epilogue: load H frags from global, dot, reduce over 16-lane groups
  float part[8][4];
  #pragma unroll
  for (int mf = 0; mf < 8; ++mf)
    #pragma unroll
    for (int r = 0; r < 4; ++r) {
      const size_t hrow = (bm + wm + mf * 16 + kk * 4 + r) * 2048 + bn + wn + f;
      float s = 0.f;
      #pragma unroll
      for (int nf = 0; nf < 4; ++nf)
        s += (float)H[hrow + nf * 16] * acc[mf][nf][r];
      part[mf][r] = s;
    }
  #pragma unroll
  for (int mf = 0; mf < 8; ++mf)
    #pragma unroll
    for (int r = 0; r < 4; ++r) {
      part[mf][r] += __shfl_xor(part[mf][r], 1);
      part[mf][r] += __shfl_xor(part[mf][r], 2);
      part[mf][r] += __shfl_xor(part[mf][r], 4);
      part[mf][r] += __shfl_xor(part[mf][r], 8);
    }
  if (f == 0) {
    const size_t slab = (size_t)(bnI * 4 + (wv & 3)) * 16384;
    #pragma unroll
    for (int mf = 0; mf < 8; ++mf)
      #pragma unroll
      for (int r = 0; r < 4; ++r)
        partial[slab + bm + wm + mf * 16 + kk * 4 + r] = part[mf][r];
  }
}

// ---------------- final reduction + softmax over M ----------------

__global__ __launch_bounds__(256) void k_sem(const float* __restrict__ partial,
                                             const float* __restrict__ ab2,
                                             float* __restrict__ semantic,
                                             float* __restrict__ bstats) {
  const int m = blockIdx.x * 256 + threadIdx.x;
  float s = ab2[m];
  #pragma unroll
  for (int nb = 0; nb < 32; ++nb) s += partial[(size_t)nb * 16384 + m];
  semantic[m] = s;
  float mx = s;
  #pragma unroll
  for (int mask = 1; mask < 64; mask <<= 1) mx = fmaxf(mx, __shfl_xor(mx, mask));
  __shared__ float wmax[4], wsum[4];
  const int wave = threadIdx.x >> 6, lane = threadIdx.x & 63;
  if (lane == 0) wmax[wave] = mx;
  __syncthreads();
  const float bmax = fmaxf(fmaxf(wmax[0], wmax[1]), fmaxf(wmax[2], wmax[3]));
  float e = expf(s - bmax);
  #pragma unroll
  for (int mask = 1; mask < 64; mask <<= 1) e += __shfl_xor(e, mask);
  if (lane == 0) wsum[wave] = e;
  __syncthreads();
  if (threadIdx.x == 0) {
    bstats[blockIdx.x * 2] = bmax;
    bstats[blockIdx.x * 2 + 1] = wsum[0] + wsum[1] + wsum[2] + wsum[3];
  }
}

__global__ __launch_bounds__(256) void k_out(const float* __restrict__ semantic,
                                             const float* __restrict__ bstats,
                                             float* __restrict__ out) {
  __shared__ float g0s, g1s;
  const int tid = threadIdx.x;
  if (tid < 64) {
    const float bm = bstats[tid * 2], bs = bstats[tid * 2 + 1];
    float gm = bm;
    #pragma unroll
    for (int mask = 1; mask < 64; mask <<= 1) gm = fmaxf(gm, __shfl_xor(gm, mask));
    float gs = bs * expf(bm - gm);
    #pragma unroll
    for (int mask = 1; mask < 64; mask <<= 1) gs += __shfl_xor(gs, mask);
    if (tid == 0) { g0s = gm; g1s = gs; }
  }
  __syncthreads();
  const int m = blockIdx.x * 256 + tid;
  out[m] = expf(semantic[m] - g0s) / g1s;
}

// ---------------- launch ----------------

extern "C" void kernel_launch(void* const* d_in, const int* in_sizes, int n_in,
                              void* d_out, int out_size, void* d_ws, size_t ws_size,
                              hipStream_t stream) {
  (void)in_sizes; (void)n_in; (void)out_size; (void)ws_size;
  const float* A    = (const float*)d_in[0];  // [16384][2048]
  const float* Q    = (const float*)d_in[1];  // [128][2048]
  const float* hist = (const float*)d_in[2];  // [2048]
  const float* W1   = (const float*)d_in[3];  // [2048][4096]
  const float* b1   = (const float*)d_in[4];  // [2048]
  const float* W2   = (const float*)d_in[5];  // [2048][2048]
  const float* b2   = (const float*)d_in[6];  // [2048]
  float* out = (float*)d_out;                 // [16384]

  char* ws = (char*)d_ws;
  f16* Af      = (f16*)ws;   ws += (size_t)16384 * 2048 * 2;  // 64 MB
  f16* Hbuf    = (f16*)ws;   ws += (size_t)16384 * 2048 * 2;  // 64 MB
  f16* W2t     = (f16*)ws;   ws += (size_t)2048 * 2048 * 2;   // 8 MB
  f16* Qf      = (f16*)ws;   ws += (size_t)128 * 2048 * 2;
  f16* QWt     = (f16*)ws;   ws += (size_t)2048 * 128 * 2;
  f16* at      = (f16*)ws;   ws += (size_t)16384 * 128 * 2;   // 4 MB
  float* c_vec = (float*)ws; ws += 2048 * 4;
  float* ab2   = (float*)ws; ws += 16384 * 4;
  float* partial  = (float*)ws; ws += (size_t)32 * 16384 * 4; // 2 MB
  float* semantic = (float*)ws; ws += 16384 * 4;
  float* bstats   = (float*)ws; ws += 128 * 4;

  hipFuncSetAttribute((const void*)fused_g,
                      hipFuncAttributeMaxDynamicSharedMemorySize, 98304);

  // prep
  c_kernel<<<512, 256, 0, stream>>>(W1, b1, hist, c_vec);
  gemm_bt_f16<32, 2><<<dim3(64, 2), 256, 0, stream>>>(W1 + 2048, Q, QWt,
                                                      2048, 4096, 2048, 128);
  transpose_f16<<<dim3(32, 32), 256, 0, stream>>>(W2, 2048, 2048, W2t);
  prep_AQ<<<4128, 256, 0, stream>>>(A, Q, b2, Af, Qf, ab2);
  // S = Af@Qf^T + softmax (fp16 single MFMA)
  s_attn<<<128, 256, 0, stream>>>(Af, Qf, at);
  // H = relu(at@QWt + c)
  h_kernel<<<2048, 256, 0, stream>>>(at, QWt, c_vec, Hbuf);
  // G = Af@W2t + dot with H (256² tile, no spill)
  fused_g<<<512, 512, 98304, stream>>>(Af, Hbuf, W2t, partial);
  // semantic + softmax over M
  k_sem<<<64, 256, 0, stream>>>(partial, ab2, semantic, bstats);
  k_out<<<64, 256, 0, stream>>>(semantic, bstats, out);
}

// Round 11
// 272.369 us; speedup vs baseline: 3.2394x; 1.1939x over previous
//
#include <hip/hip_runtime.h>
#include <hip/hip_bf16.h>

// PolicyNet, fp16 MFMA:
//   A -> Af fp16, ab2[m] = A[m]·b2;  Q -> Qf fp16
//   c    = b1 + W1[:, :D] @ hist                  (fp32)
//   QWt  = (f16)(W1[:, D:] @ Q^T)  via split-K fp32 gemm + combine
//   W2   -> transpose -> W2t f16 [j][k]
//   s_attn: S = Af@Qf^T (fp16 single MFMA), fused row-softmax -> at f16
//   h_kernel: H = relu(at @ QWt + c) f16 [16384][2048]
//   fused_g (256², 4-set/128KB LDS, single barrier/step): G = Af @ W2t;
//       epilogue loads H frags, partial = sum_j H*G
//   semantic = sum partial + ab2 -> softmax over M -> out

typedef _Float16 f16;
typedef __attribute__((ext_vector_type(8))) _Float16 half8;
typedef __attribute__((ext_vector_type(4))) _Float16 half4_t;
typedef __attribute__((ext_vector_type(4))) float f32x4;

#define GLL(gp, lp)                                                              \
  __builtin_amdgcn_global_load_lds(                                              \
      (const __attribute__((address_space(1))) void*)(gp),                       \
      (__attribute__((address_space(3))) void*)(lp), 16, 0, 0)

#define WAITN(n)                                                                 \
  do {                                                                           \
    asm volatile("s_waitcnt vmcnt(" #n ")" ::: "memory");                        \
    __builtin_amdgcn_sched_barrier(0);                                           \
  } while (0)

// ---------------- 4-wave 128x128 fp16 K-loop, depth-3 ----------------
// BK=32. LDS: 4 sets x {A 8KB, B 8KB} = 64KB. vmcnt(12) steady.
template <int NT, int LDA, int LDB>
__device__ __forceinline__ void kloop1(const f16* __restrict__ A,
                                       const f16* __restrict__ B,
                                       f16* __restrict__ SM,
                                       f32x4 (&acc)[4][4],
                                       int lane, int wv, int wm, int wn) {
  static_assert(NT >= 4, "depth-3 pipeline needs NT >= 4");
  const int f = lane & 15, kk = lane >> 4;
  const int cS = (lane & 7) ^ (lane >> 3);
  const int kkS = (cS & 3) * 8;
  const int rS = 2 * (lane >> 3) + (cS >> 2);
  const size_t offA0 = (size_t)(16 * (wv * 2 + 0) + rS) * LDA + kkS;
  const size_t offA1 = (size_t)(16 * (wv * 2 + 1) + rS) * LDA + kkS;
  const size_t offB0 = (size_t)(16 * (wv * 2 + 0) + rS) * LDB + kkS;
  const size_t offB1 = (size_t)(16 * (wv * 2 + 1) + rS) * LDB + kkS;
  const int Ld0 = (wv * 2 + 0) * 512, Ld1 = (wv * 2 + 1) * 512;

  int aoff[4], boff[4];
  #pragma unroll
  for (int mf = 0; mf < 4; ++mf) {
    const int R = wm + mf * 16 + f;
    const int c2 = (((R & 1) << 2) | kk) ^ ((R >> 1) & 7);
    aoff[mf] = (R >> 1) * 64 + c2 * 8;
  }
  #pragma unroll
  for (int nf = 0; nf < 4; ++nf) {
    const int R = wn + nf * 16 + f;
    const int c2 = (((R & 1) << 2) | kk) ^ ((R >> 1) & 7);
    boff[nf] = (R >> 1) * 64 + c2 * 8;
  }

  auto STAGE = [&](int set, int kt) {
    f16* base = SM + set * 8192;
    GLL(A + offA0 + kt, base + Ld0);
    GLL(A + offA1 + kt, base + Ld1);
    GLL(B + offB0 + kt, base + 4096 + Ld0);
    GLL(B + offB1 + kt, base + 4096 + Ld1);
  };
  auto COMPUTE = [&](int set) {
    const f16* p = SM + set * 8192;
    half8 a[4], b[4];
    #pragma unroll
    for (int mf = 0; mf < 4; ++mf) a[mf] = *(const half8*)&p[aoff[mf]];
    #pragma unroll
    for (int nf = 0; nf < 4; ++nf) b[nf] = *(const half8*)&p[4096 + boff[nf]];
    __builtin_amdgcn_s_setprio(1);
    #pragma unroll
    for (int mf = 0; mf < 4; ++mf)
      #pragma unroll
      for (int nf = 0; nf < 4; ++nf)
        acc[mf][nf] = __builtin_amdgcn_mfma_f32_16x16x32_f16(a[mf], b[nf], acc[mf][nf], 0, 0, 0);
    __builtin_amdgcn_s_setprio(0);
  };

  STAGE(0, 0);
  STAGE(1, 32);
  STAGE(2, 64);
  #pragma unroll 1
  for (int t = 0; t < NT - 3; ++t) {
    STAGE((t + 3) & 3, (t + 3) * 32);
    WAITN(12);
    __builtin_amdgcn_s_barrier();
    COMPUTE(t & 3);
    __builtin_amdgcn_s_barrier();
  }
  WAITN(8);
  __builtin_amdgcn_s_barrier();
  COMPUTE((NT - 3) & 3);
  __builtin_amdgcn_s_barrier();
  WAITN(4);
  __builtin_amdgcn_s_barrier();
  COMPUTE((NT - 2) & 3);
  __builtin_amdgcn_s_barrier();
  WAITN(0);
  __builtin_amdgcn_s_barrier();
  COMPUTE((NT - 1) & 3);
  __builtin_amdgcn_s_barrier();
}

// ---------------- 8-wave 256x256 fp16 K-loop, 4 sets, 1 barrier/step ---------
// BK=32. LDS: 4 sets x {A 16KB, B 16KB} = 128KB dynamic. depth-2, vmcnt(8).
// Set s staged at iter t was last read at iter t-2; barrier@t-1 separates
// (each wave reaches it only after finishing COMPUTE@t-2) -> trailing barrier
// per step is unnecessary with a 4-deep rotation.
template <int NT, int LDA, int LDB>
__device__ __forceinline__ void kloop256(const f16* __restrict__ A,
                                         const f16* __restrict__ B,
                                         f16* __restrict__ SM,
                                         f32x4 (&acc)[8][4],
                                         int lane, int wv, int wm, int wn) {
  static_assert(NT >= 3, "pipeline needs NT >= 3");
  const int f = lane & 15, kk = lane >> 4;
  const int cS = (lane & 7) ^ (lane >> 3);
  const int kkS = (cS & 3) * 8;
  const int rS = 2 * (lane >> 3) + (cS >> 2);
  const size_t offA0 = (size_t)(16 * (wv * 2 + 0) + rS) * LDA + kkS;
  const size_t offA1 = (size_t)(16 * (wv * 2 + 1) + rS) * LDA + kkS;
  const size_t offB0 = (size_t)(16 * (wv * 2 + 0) + rS) * LDB + kkS;
  const size_t offB1 = (size_t)(16 * (wv * 2 + 1) + rS) * LDB + kkS;
  const int Ld0 = (wv * 2 + 0) * 512, Ld1 = (wv * 2 + 1) * 512;

  int aoff[8], boff[4];
  #pragma unroll
  for (int mf = 0; mf < 8; ++mf) {
    const int R = wm + mf * 16 + f;
    const int c2 = (((R & 1) << 2) | kk) ^ ((R >> 1) & 7);
    aoff[mf] = (R >> 1) * 64 + c2 * 8;
  }
  #pragma unroll
  for (int nf = 0; nf < 4; ++nf) {
    const int R = wn + nf * 16 + f;
    const int c2 = (((R & 1) << 2) | kk) ^ ((R >> 1) & 7);
    boff[nf] = (R >> 1) * 64 + c2 * 8;
  }

  auto STAGE = [&](int set, int kt) {
    f16* base = SM + set * 16384;
    GLL(A + offA0 + kt, base + Ld0);
    GLL(A + offA1 + kt, base + Ld1);
    GLL(B + offB0 + kt, base + 8192 + Ld0);
    GLL(B + offB1 + kt, base + 8192 + Ld1);
  };
  auto COMPUTE = [&](int set) {
    const f16* p = SM + set * 16384;
    half8 a[8], b[4];
    #pragma unroll
    for (int mf = 0; mf < 8; ++mf) a[mf] = *(const half8*)&p[aoff[mf]];
    #pragma unroll
    for (int nf = 0; nf < 4; ++nf) b[nf] = *(const half8*)&p[8192 + boff[nf]];
    __builtin_amdgcn_s_setprio(1);
    #pragma unroll
    for (int mf = 0; mf < 8; ++mf)
      #pragma unroll
      for (int nf = 0; nf < 4; ++nf)
        acc[mf][nf] = __builtin_amdgcn_mfma_f32_16x16x32_f16(a[mf], b[nf], acc[mf][nf], 0, 0, 0);
    __builtin_amdgcn_s_setprio(0);
  };

  STAGE(0, 0);
  STAGE(1, 32);
  #pragma unroll 1
  for (int t = 0; t < NT - 2; ++t) {
    STAGE((t + 2) & 3, (t + 2) * 32);
    WAITN(8);
    __builtin_amdgcn_s_barrier();
    COMPUTE(t & 3);
  }
  WAITN(4);
  __builtin_amdgcn_s_barrier();
  COMPUTE((NT - 2) & 3);
  WAITN(0);
  __builtin_amdgcn_s_barrier();
  COMPUTE((NT - 1) & 3);
}

// ---------------- prep kernels ----------------

__global__ __launch_bounds__(256) void c_kernel(const float* __restrict__ W1,
                                                const float* __restrict__ b1,
                                                const float* __restrict__ hist,
                                                float* __restrict__ c) {
  const int wave = threadIdx.x >> 6, lane = threadIdx.x & 63;
  const int j = blockIdx.x * 4 + wave;
  const float* row = W1 + (size_t)j * 4096;
  float s = 0.f;
  #pragma unroll 2
  for (int kq = lane; kq < 512; kq += 64) {
    const float4 w = *(const float4*)&row[kq * 4];
    const float4 h = *(const float4*)&hist[kq * 4];
    s += w.x * h.x + w.y * h.y + w.z * h.z + w.w * h.w;
  }
  #pragma unroll
  for (int mask = 1; mask < 64; mask <<= 1) s += __shfl_xor(s, mask);
  if (lane == 0) c[j] = s + b1[j];
}

__device__ __forceinline__ half4_t f16hi4(const float4 v) {
  half4_t h;
  h.x = (f16)v.x; h.y = (f16)v.y; h.z = (f16)v.z; h.w = (f16)v.w;
  return h;
}

// blocks 0..4095: A rows (4/block) -> Af + ab2;  blocks 4096..4127: Q -> Qf
__global__ __launch_bounds__(256) void prep_AQ(const float* __restrict__ A,
                                               const float* __restrict__ Q,
                                               const float* __restrict__ b2,
                                               f16* __restrict__ Af,
                                               f16* __restrict__ Qf,
                                               float* __restrict__ ab2) {
  const int wv = threadIdx.x >> 6, lane = threadIdx.x & 63;
  if (blockIdx.x < 4096) {
    const size_t row = (size_t)blockIdx.x * 4 + wv;
    const float* ar = A + row * 2048;
    float dot = 0.f;
    #pragma unroll 2
    for (int c0 = 0; c0 < 2048; c0 += 256) {
      const int col = c0 + lane * 4;
      const float4 v = *(const float4*)&ar[col];
      const float4 bb = *(const float4*)&b2[col];
      dot += v.x * bb.x + v.y * bb.y + v.z * bb.z + v.w * bb.w;
      *(half4_t*)&Af[row * 2048 + col] = f16hi4(v);
    }
    #pragma unroll
    for (int mask = 1; mask < 64; mask <<= 1) dot += __shfl_xor(dot, mask);
    if (lane == 0) ab2[row] = dot;
  } else {
    const size_t row = (size_t)(blockIdx.x - 4096) * 4 + wv;
    const float* qr = Q + row * 2048;
    #pragma unroll 2
    for (int c0 = 0; c0 < 2048; c0 += 256) {
      const int col = c0 + lane * 4;
      const float4 v = *(const float4*)&qr[col];
      *(half4_t*)&Qf[row * 2048 + col] = f16hi4(v);
    }
  }
}

// dst[c*ldR + r] = (f16)src[r*C + c]
__global__ __launch_bounds__(256) void transpose_f16(const float* __restrict__ src,
                                                     int R, int C,
                                                     f16* __restrict__ dst) {
  __shared__ float T[64][65];
  const int c0 = blockIdx.x * 64, r0 = blockIdx.y * 64;
  const int t = threadIdx.x;
  {
    const int rl = t >> 4, cl = (t & 15) * 4;
    #pragma unroll
    for (int ii = 0; ii < 4; ++ii) {
      const float4 v = *(const float4*)&src[(size_t)(r0 + rl + ii * 16) * C + c0 + cl];
      T[rl + ii * 16][cl + 0] = v.x; T[rl + ii * 16][cl + 1] = v.y;
      T[rl + ii * 16][cl + 2] = v.z; T[rl + ii * 16][cl + 3] = v.w;
    }
  }
  __syncthreads();
  const int cc = t >> 2, rr0 = (t & 3) * 16;
  f16 u[16];
  #pragma unroll
  for (int k = 0; k < 16; ++k) u[k] = (f16)T[rr0 + k][cc];
  f16* ph = dst + (size_t)(c0 + cc) * R + r0 + rr0;
  #pragma unroll
  for (int k4 = 0; k4 < 4; ++k4)
    *(half4_t*)&ph[k4 * 4] = *(half4_t*)&u[k4 * 4];
}

// fp32 tiled GEMM (B^T layout), split-K fp32 partial output
// Cpart[z][m][n] = sum_{k in slab z} A[m*lda+k]*B[n*ldb+k]
template <int BM, int TM>
__global__ __launch_bounds__(256) void gemm_bt_sk(const float* __restrict__ A,
                                                  const float* __restrict__ B,
                                                  float* __restrict__ Cpart,
                                                  int Kslab, int lda, int ldb,
                                                  int ldc, int M) {
  constexpr int BN = 64, BK = 32;
  constexpr int ASTR = BM + 12, BSTR = BN + 4;
  __shared__ float As[BK][ASTR];
  __shared__ float Bs[BK][BSTR];
  const int tid = threadIdx.x;
  const int tx = tid & 15, ty = tid >> 4;
  const int m0 = ty * TM, n0 = tx * 4;
  const size_t bm = (size_t)blockIdx.x * BM, bn = (size_t)blockIdx.y * BN;
  const int kb = blockIdx.z * Kslab;
  const float* Ab = A + bm * lda;
  const float* Bb = B + bn * ldb;
  float acc[TM][4];
  #pragma unroll
  for (int i = 0; i < TM; ++i)
    #pragma unroll
    for (int j = 0; j < 4; ++j) acc[i][j] = 0.f;
  for (int kt = kb; kt < kb + Kslab; kt += BK) {
    #pragma unroll
    for (int it = 0; it < BM * BK / 4 / 256; ++it) {
      const int idx = it * 256 + tid;
      const int row = idx >> 3, kq = idx & 7;
      const float4 v = *(const float4*)&Ab[(size_t)row * lda + kt + kq * 4];
      As[kq * 4 + 0][row] = v.x; As[kq * 4 + 1][row] = v.y;
      As[kq * 4 + 2][row] = v.z; As[kq * 4 + 3][row] = v.w;
    }
    #pragma unroll
    for (int it = 0; it < BN * BK / 4 / 256; ++it) {
      const int idx = it * 256 + tid;
      const int row = idx >> 3, kq = idx & 7;
      const float4 v = *(const float4*)&Bb[(size_t)row * ldb + kt + kq * 4];
      Bs[kq * 4 + 0][row] = v.x; Bs[kq * 4 + 1][row] = v.y;
      Bs[kq * 4 + 2][row] = v.z; Bs[kq * 4 + 3][row] = v.w;
    }
    __syncthreads();
    #pragma unroll
    for (int k = 0; k < BK; ++k) {
      float av[TM];
      #pragma unroll
      for (int i = 0; i < TM; ++i) av[i] = As[k][m0 + i];
      const float4 b = *(const float4*)&Bs[k][n0];
      const float bv[4] = {b.x, b.y, b.z, b.w};
      #pragma unroll
      for (int i = 0; i < TM; ++i)
        #pragma unroll
        for (int j = 0; j < 4; ++j) acc[i][j] = fmaf(av[i], bv[j], acc[i][j]);
    }
    __syncthreads();
  }
  float* base = Cpart + (size_t)blockIdx.z * M * ldc;
  #pragma unroll
  for (int i = 0; i < TM; ++i) {
    float* crow = base + (bm + m0 + i) * (size_t)ldc + bn + n0;
    #pragma unroll
    for (int j = 0; j < 4; ++j) crow[j] = acc[i][j];
  }
}

// QWt[i] = (f16) sum_z part[z][i], 2048*128 elems, float4 per thread
__global__ __launch_bounds__(256) void qwt_combine(const float* __restrict__ part,
                                                   f16* __restrict__ QWt) {
  const size_t i = ((size_t)blockIdx.x * 256 + threadIdx.x) * 4;
  float4 s = make_float4(0.f, 0.f, 0.f, 0.f);
  #pragma unroll
  for (int z = 0; z < 8; ++z) {
    const float4 v = *(const float4*)&part[(size_t)z * 262144 + i];
    s.x += v.x; s.y += v.y; s.z += v.z; s.w += v.w;
  }
  *(half4_t*)&QWt[i] = f16hi4(s);
}

// ---------------- S = Af@Qf^T (fp16 single) + fused row softmax -> at f16 ----
__global__ __launch_bounds__(256, 2) void s_attn(const f16* __restrict__ Af,
                                                 const f16* __restrict__ Qf,
                                                 f16* __restrict__ at) {
  __shared__ f16 SM[32768];  // 64 KB
  const int tid = threadIdx.x, lane = tid & 63, wv = tid >> 6;
  const int wm = (wv >> 1) * 64, wn = (wv & 1) * 64;
  const int f = lane & 15, kk = lane >> 4;
  const size_t bm = (size_t)blockIdx.x * 128;

  f32x4 acc[4][4];
  #pragma unroll
  for (int mf = 0; mf < 4; ++mf)
    #pragma unroll
    for (int nf = 0; nf < 4; ++nf) acc[mf][nf] = 0.f;

  kloop1<64, 2048, 2048>(Af + bm * 2048, Qf, SM, acc, lane, wv, wm, wn);

  float* sred = (float*)SM;        // [128][2] row-max
  float* ssum = sred + 256;        // [128][2] row-sum
  const int rowbase = wm + kk * 4;
  float rmax[4][4];
  #pragma unroll
  for (int mf = 0; mf < 4; ++mf)
    #pragma unroll
    for (int r = 0; r < 4; ++r) {
      float m4 = fmaxf(fmaxf(acc[mf][0][r], acc[mf][1][r]),
                       fmaxf(acc[mf][2][r], acc[mf][3][r]));
      m4 = fmaxf(m4, __shfl_xor(m4, 1));
      m4 = fmaxf(m4, __shfl_xor(m4, 2));
      m4 = fmaxf(m4, __shfl_xor(m4, 4));
      m4 = fmaxf(m4, __shfl_xor(m4, 8));
      rmax[mf][r] = m4;
    }
  if (f == 0) {
    #pragma unroll
    for (int mf = 0; mf < 4; ++mf)
      #pragma unroll
      for (int r = 0; r < 4; ++r)
        sred[(rowbase + mf * 16 + r) * 2 + (wv & 1)] = rmax[mf][r];
  }
  __syncthreads();
  #pragma unroll
  for (int mf = 0; mf < 4; ++mf)
    #pragma unroll
    for (int r = 0; r < 4; ++r) {
      const int row = rowbase + mf * 16 + r;
      rmax[mf][r] = fmaxf(sred[row * 2], sred[row * 2 + 1]);
    }
  float rsum[4][4];
  #pragma unroll
  for (int mf = 0; mf < 4; ++mf)
    #pragma unroll
    for (int r = 0; r < 4; ++r) {
      float s = 0.f;
      #pragma unroll
      for (int nf = 0; nf < 4; ++nf) {
        acc[mf][nf][r] = __expf(acc[mf][nf][r] - rmax[mf][r]);
        s += acc[mf][nf][r];
      }
      s += __shfl_xor(s, 1);
      s += __shfl_xor(s, 2);
      s += __shfl_xor(s, 4);
      s += __shfl_xor(s, 8);
      rsum[mf][r] = s;
    }
  if (f == 0) {
    #pragma unroll
    for (int mf = 0; mf < 4; ++mf)
      #pragma unroll
      for (int r = 0; r < 4; ++r)
        ssum[(rowbase + mf * 16 + r) * 2 + (wv & 1)] = rsum[mf][r];
  }
  __syncthreads();
  #pragma unroll
  for (int mf = 0; mf < 4; ++mf)
    #pragma unroll
    for (int r = 0; r < 4; ++r) {
      const int row = rowbase + mf * 16 + r;
      const float inv = 1.0f / (ssum[row * 2] + ssum[row * 2 + 1]);
      const size_t orow = (bm + row) * 128;
      #pragma unroll
      for (int nf = 0; nf < 4; ++nf)
        at[orow + wn + nf * 16 + f] = (f16)(acc[mf][nf][r] * inv);
    }
}

// ---------------- H = relu(at @ QWt + c), 128x128 tile, K=128 ----------------
__global__ __launch_bounds__(256, 2) void h_kernel(const f16* __restrict__ at,
                                                   const f16* __restrict__ QWt,
                                                   const float* __restrict__ cvec,
                                                   f16* __restrict__ H) {
  __shared__ f16 SM[32768];  // 64 KB (4 sets x 16KB)
  const int tid = threadIdx.x, lane = tid & 63, wv = tid >> 6;
  const int wm = (wv >> 1) * 64, wn = (wv & 1) * 64;
  const int f = lane & 15, kk = lane >> 4;
  const size_t bm = (size_t)(blockIdx.x & 127) * 128;
  const size_t bn = (size_t)(blockIdx.x >> 7) * 128;

  f32x4 acc[4][4];
  #pragma unroll
  for (int mf = 0; mf < 4; ++mf)
    #pragma unroll
    for (int nf = 0; nf < 4; ++nf) acc[mf][nf] = 0.f;

  kloop1<4, 128, 128>(at + bm * 128, QWt + bn * 128, SM, acc, lane, wv, wm, wn);

  float ccv[4];
  #pragma unroll
  for (int nf = 0; nf < 4; ++nf) ccv[nf] = cvec[bn + wn + nf * 16 + f];
  #pragma unroll
  for (int mf = 0; mf < 4; ++mf)
    #pragma unroll
    for (int r = 0; r < 4; ++r) {
      const size_t row = bm + wm + mf * 16 + kk * 4 + r;
      #pragma unroll
      for (int nf = 0; nf < 4; ++nf)
        H[row * 2048 + bn + wn + nf * 16 + f] =
            (f16)fmaxf(acc[mf][nf][r] + ccv[nf], 0.f);
    }
}

// ---------------- fused G: G = Af @ W2t (256² tile) + dot with H ----------------
__global__ __launch_bounds__(512, 1) void fused_g(
    const f16* __restrict__ Af, const f16* __restrict__ H,
    const f16* __restrict__ W2t, float* __restrict__ partial) {
  extern __shared__ f16 SM[];  // 128 KB: 4 sets x {A 16KB, B 16KB}
  const int tid = threadIdx.x, lane = tid & 63, wv = tid >> 6;   // wv 0..7
  const int wm = (wv >> 2) * 128, wn = (wv & 3) * 64;
  const int f = lane & 15, kk = lane >> 4;
  // bijective XCD swizzle: nwg=512, 8 XCDs, 64 per XCD
  const int lin = blockIdx.x;
  const int sid = (lin & 7) * 64 + (lin >> 3);
  const int bmI = sid & 63, bnI = sid >> 6;       // 64 m-blocks x 8 n-blocks
  const size_t bm = (size_t)bmI * 256;
  const size_t bn = (size_t)bnI * 256;

  f32x4 acc[8][4];
  #pragma unroll
  for (int mf = 0; mf < 8; ++mf)
    #pragma unroll
    for (int nf = 0; nf < 4; ++nf) acc[mf][nf] = 0.f;

  kloop256<64, 2048, 2048>(Af + bm * 2048, W2t + bn * 2048, SM, acc, lane, wv, wm, wn);

  // epilogue: load H frags from global, dot, reduce over 16-lane groups
  float part[8][4];
  #pragma unroll
  for (int mf = 0; mf < 8; ++mf)
    #pragma unroll
    for (int r = 0; r < 4; ++r) {
      const size_t hrow = (bm + wm + mf * 16 + kk * 4 + r) * 2048 + bn + wn + f;
      float s = 0.f;
      #pragma unroll
      for (int nf = 0; nf < 4; ++nf)
        s += (float)H[hrow + nf * 16] * acc[mf][nf][r];
      part[mf][r] = s;
    }
  #pragma unroll
  for (int mf = 0; mf < 8; ++mf)
    #pragma unroll
    for (int r = 0; r < 4; ++r) {
      part[mf][r] += __shfl_xor(part[mf][r], 1);
      part[mf][r] += __shfl_xor(part[mf][r], 2);
      part[mf][r] += __shfl_xor(part[mf][r], 4);
      part[mf][r] += __shfl_xor(part[mf][r], 8);
    }
  if (f == 0) {
    const size_t slab = (size_t)(bnI * 4 + (wv & 3)) * 16384;
    #pragma unroll
    for (int mf = 0; mf < 8; ++mf)
      #pragma unroll
      for (int r = 0; r < 4; ++r)
        partial[slab + bm + wm + mf * 16 + kk * 4 + r] = part[mf][r];
  }
}

// ---------------- final reduction + softmax over M ----------------

__global__ __launch_bounds__(256) void k_sem(const float* __restrict__ partial,
                                             const float* __restrict__ ab2,
                                             float* __restrict__ semantic,
                                             float* __restrict__ bstats) {
  const int m = blockIdx.x * 256 + threadIdx.x;
  float s = ab2[m];
  #pragma unroll
  for (int nb = 0; nb < 32; ++nb) s += partial[(size_t)nb * 16384 + m];
  semantic[m] = s;
  float mx = s;
  #pragma unroll
  for (int mask = 1; mask < 64; mask <<= 1) mx = fmaxf(mx, __shfl_xor(mx, mask));
  __shared__ float wmax[4], wsum[4];
  const int wave = threadIdx.x >> 6, lane = threadIdx.x & 63;
  if (lane == 0) wmax[wave] = mx;
  __syncthreads();
  const float bmax = fmaxf(fmaxf(wmax[0], wmax[1]), fmaxf(wmax[2], wmax[3]));
  float e = expf(s - bmax);
  #pragma unroll
  for (int mask = 1; mask < 64; mask <<= 1) e += __shfl_xor(e, mask);
  if (lane == 0) wsum[wave] = e;
  __syncthreads();
  if (threadIdx.x == 0) {
    bstats[blockIdx.x * 2] = bmax;
    bstats[blockIdx.x * 2 + 1] = wsum[0] + wsum[1] + wsum[2] + wsum[3];
  }
}

__global__ __launch_bounds__(256) void k_out(const float* __restrict__ semantic,
                                             const float* __restrict__ bstats,
                                             float* __restrict__ out) {
  __shared__ float g0s, g1s;
  const int tid = threadIdx.x;
  if (tid < 64) {
    const float bm = bstats[tid * 2], bs = bstats[tid * 2 + 1];
    float gm = bm;
    #pragma unroll
    for (int mask = 1; mask < 64; mask <<= 1) gm = fmaxf(gm, __shfl_xor(gm, mask));
    float gs = bs * expf(bm - gm);
    #pragma unroll
    for (int mask = 1; mask < 64; mask <<= 1) gs += __shfl_xor(gs, mask);
    if (tid == 0) { g0s = gm; g1s = gs; }
  }
  __syncthreads();
  const int m = blockIdx.x * 256 + tid;
  out[m] = expf(semantic[m] - g0s) / g1s;
}

// ---------------- launch ----------------

extern "C" void kernel_launch(void* const* d_in, const int* in_sizes, int n_in,
                              void* d_out, int out_size, void* d_ws, size_t ws_size,
                              hipStream_t stream) {
  (void)in_sizes; (void)n_in; (void)out_size; (void)ws_size;
  const float* A    = (const float*)d_in[0];  // [16384][2048]
  const float* Q    = (const float*)d_in[1];  // [128][2048]
  const float* hist = (const float*)d_in[2];  // [2048]
  const float* W1   = (const float*)d_in[3];  // [2048][4096]
  const float* b1   = (const float*)d_in[4];  // [2048]
  const float* W2   = (const float*)d_in[5];  // [2048][2048]
  const float* b2   = (const float*)d_in[6];  // [2048]
  float* out = (float*)d_out;                 // [16384]

  char* ws = (char*)d_ws;
  f16* Af      = (f16*)ws;   ws += (size_t)16384 * 2048 * 2;  // 64 MB
  f16* Hbuf    = (f16*)ws;   ws += (size_t)16384 * 2048 * 2;  // 64 MB
  f16* W2t     = (f16*)ws;   ws += (size_t)2048 * 2048 * 2;   // 8 MB
  f16* Qf      = (f16*)ws;   ws += (size_t)128 * 2048 * 2;
  f16* QWt     = (f16*)ws;   ws += (size_t)2048 * 128 * 2;
  f16* at      = (f16*)ws;   ws += (size_t)16384 * 128 * 2;   // 4 MB
  float* qwt_part = (float*)ws; ws += (size_t)8 * 2048 * 128 * 4;  // 8 MB
  float* c_vec = (float*)ws; ws += 2048 * 4;
  float* ab2   = (float*)ws; ws += 16384 * 4;
  float* partial  = (float*)ws; ws += (size_t)32 * 16384 * 4; // 2 MB
  float* semantic = (float*)ws; ws += 16384 * 4;
  float* bstats   = (float*)ws; ws += 128 * 4;

  hipFuncSetAttribute((const void*)fused_g,
                      hipFuncAttributeMaxDynamicSharedMemorySize, 131072);

  // prep
  c_kernel<<<512, 256, 0, stream>>>(W1, b1, hist, c_vec);
  // qwt_part[z][j][n] = sum_{k in slab z} W1q[j][k] * Q[n][k]   (split-K 8)
  gemm_bt_sk<32, 2><<<dim3(64, 2, 8), 256, 0, stream>>>(W1 + 2048, Q, qwt_part,
                                                        256, 4096, 2048, 128, 2048);
  qwt_combine<<<256, 256, 0, stream>>>(qwt_part, QWt);
  transpose_f16<<<dim3(32, 32), 256, 0, stream>>>(W2, 2048, 2048, W2t);
  prep_AQ<<<4128, 256, 0, stream>>>(A, Q, b2, Af, Qf, ab2);
  // S = Af@Qf^T + softmax (fp16 single MFMA)
  s_attn<<<128, 256, 0, stream>>>(Af, Qf, at);
  // H = relu(at@QWt + c)
  h_kernel<<<2048, 256, 0, stream>>>(at, QWt, c_vec, Hbuf);
  // G = Af@W2t + dot with H (256² tile, 4-set LDS, 1 barrier/step)
  fused_g<<<512, 512, 131072, stream>>>(Af, Hbuf, W2t, partial);
  // semantic + softmax over M
  k_sem<<<64, 256, 0, stream>>>(partial, ab2, semantic, bstats);
  k_out<<<64, 256, 0, stream>>>(semantic, bstats, out);
}